// Round 5
// baseline (1067.707 us; speedup 1.0000x reference)
//
#include <hip/hip_runtime.h>
#include <hip/hip_bf16.h>

#define Dd 1024
#define Bb 8192

typedef unsigned short u16;
typedef __attribute__((ext_vector_type(8))) short short8;
typedef __attribute__((ext_vector_type(4))) float f32x4;

static constexpr size_t DD  = (size_t)Dd * Dd;   // 1M
static constexpr size_t BD  = (size_t)Bb * Dd;   // 8M
static constexpr size_t MBy = 1ull << 20;

__device__ __forceinline__ float bf2f(u16 v) {
  union { unsigned u; float f; } c; c.u = ((unsigned)v) << 16; return c.f;
}
__device__ __forceinline__ u16 f2bf(float f) {
  union { float f; unsigned u; } c; c.f = f;
  return (u16)((c.u + 0x7fffu + ((c.u >> 16) & 1u)) >> 16);
}

// ---------------- NT GEMM: C[m][n] = alpha * sum_k A[m][k]*Bt[n][k] (+beta*C) ----------
// MODE 0: 1 MFMA (Ah*Bh) ; MODE 1: 3 MFMA (AhBh+AlBh+AhBl) split ; MODE 2: 2 MFMA (AhBh+AlBl) pair
struct ZP { const u16* Ah; const u16* Al; const u16* Bh; const u16* Bl; void* C; float alpha; float beta; };
struct GArgs { ZP z[8]; int K, lda, ldb; long ldc; int cstride; };

template<int MODE, bool OBF>
__global__ __launch_bounds__(256) void gemm_nt(GArgs a) {
  constexpr bool X2 = (MODE != 0);
  __shared__ __align__(16) u16 smem[X2 ? 32768 : 16384];
  u16* As = smem;
  u16* Bs = smem + 8192;
  const ZP p = a.z[blockIdx.z];
  const int tid  = threadIdx.x;
  const int lane = tid & 63, wv = tid >> 6;

  // XCD-chunked swizzle (per z-slice; bijective when nwg%8==0)  [T1]
  int bx = blockIdx.x, by = blockIdx.y;
  {
    const int gx = gridDim.x;
    const int nwg = gx * gridDim.y;
    if ((nwg & 7) == 0 && nwg >= 16) {
      const int flat = by * gx + bx;
      const int ch = nwg >> 3;
      const int nf = (flat & 7) * ch + (flat >> 3);
      bx = nf % gx; by = nf / gx;
    }
  }

  const long brow = (long)by * 128, bcol = (long)bx * 128;
  const int wm = (wv & 1) * 64, wn = (wv >> 1) * 64;
  const int srow = wv * 8 + (lane >> 3);
  const int scol = (lane & 7) * 8;
  f32x4 acc[4][4];
#pragma unroll
  for (int i = 0; i < 4; ++i)
#pragma unroll
    for (int j = 0; j < 4; ++j) { f32x4 zv = {0.f, 0.f, 0.f, 0.f}; acc[i][j] = zv; }

  for (int kt = 0; kt < a.K; kt += 64) {
    __syncthreads();
#pragma unroll
    for (int i = 0; i < 4; ++i) {
      const int rr = i * 32 + srow;
      const int lb = (i * 32 + wv * 8) * 64;
      const u16* ga = p.Ah + (brow + rr) * (long)a.lda + kt + scol;
      const u16* gb = p.Bh + (bcol + rr) * (long)a.ldb + kt + scol;
      __builtin_amdgcn_global_load_lds((const __attribute__((address_space(1))) void*)ga,
                                       (__attribute__((address_space(3))) void*)(As + lb), 16, 0, 0);
      __builtin_amdgcn_global_load_lds((const __attribute__((address_space(1))) void*)gb,
                                       (__attribute__((address_space(3))) void*)(Bs + lb), 16, 0, 0);
      if constexpr (X2) {
        const u16* ga2 = p.Al + (brow + rr) * (long)a.lda + kt + scol;
        const u16* gb2 = p.Bl + (bcol + rr) * (long)a.ldb + kt + scol;
        __builtin_amdgcn_global_load_lds((const __attribute__((address_space(1))) void*)ga2,
                                         (__attribute__((address_space(3))) void*)(smem + 16384 + lb), 16, 0, 0);
        __builtin_amdgcn_global_load_lds((const __attribute__((address_space(1))) void*)gb2,
                                         (__attribute__((address_space(3))) void*)(smem + 24576 + lb), 16, 0, 0);
      }
    }
    __syncthreads();
#pragma unroll
    for (int kk = 0; kk < 64; kk += 32) {
      const int ko = kk + ((lane >> 4) * 8);
      short8 af[4], bfv[4], al[4], bl[4];
#pragma unroll
      for (int i = 0; i < 4; ++i) {
        af[i]  = *(const short8*)(As + (wm + i * 16 + (lane & 15)) * 64 + ko);
        bfv[i] = *(const short8*)(Bs + (wn + i * 16 + (lane & 15)) * 64 + ko);
        if constexpr (X2) {
          al[i] = *(const short8*)(smem + 16384 + (wm + i * 16 + (lane & 15)) * 64 + ko);
          bl[i] = *(const short8*)(smem + 24576 + (wn + i * 16 + (lane & 15)) * 64 + ko);
        }
      }
#pragma unroll
      for (int i = 0; i < 4; ++i)
#pragma unroll
        for (int j = 0; j < 4; ++j) {
          acc[i][j] = __builtin_amdgcn_mfma_f32_16x16x32_bf16(af[i], bfv[j], acc[i][j], 0, 0, 0);
          if constexpr (MODE == 1) {
            acc[i][j] = __builtin_amdgcn_mfma_f32_16x16x32_bf16(al[i], bfv[j], acc[i][j], 0, 0, 0);
            acc[i][j] = __builtin_amdgcn_mfma_f32_16x16x32_bf16(af[i], bl[j], acc[i][j], 0, 0, 0);
          } else if constexpr (MODE == 2) {
            acc[i][j] = __builtin_amdgcn_mfma_f32_16x16x32_bf16(al[i], bl[j], acc[i][j], 0, 0, 0);
          }
        }
    }
  }
  const long crow = brow + wm + ((lane >> 4) * 4);
  const long ccol = bcol + wn + (lane & 15);
#pragma unroll
  for (int i = 0; i < 4; ++i)
#pragma unroll
    for (int j = 0; j < 4; ++j)
#pragma unroll
      for (int r = 0; r < 4; ++r) {
        const long cidx = (crow + i * 16 + r) * a.ldc + (ccol + j * 16) * (long)a.cstride;
        float v = acc[i][j][r] * p.alpha;
        if constexpr (OBF) {
          ((u16*)p.C)[cidx] = f2bf(v);
        } else {
          float* C = (float*)p.C;
          if (p.beta != 0.0f) v += p.beta * C[cidx];
          C[cidx] = v;
        }
      }
}

// ---------------- elementwise kernels ----------------
// complex d x d planes: [y*2*DD] = re, [y*2*DD + DD] = im ; sum planes: [y*DD]

__global__ void k_buildA(const float* ur, const float* ui, const float* vr, const float* vi,
                         float* Af32, u16* Ahi, u16* Alo, u16* AsumH, u16* AsumL) {
  const int y = blockIdx.y;
  const size_t idx = (size_t)blockIdx.x * 256 + threadIdx.x;
  const size_t r = idx >> 10, c = idx & 1023;
  const float* re = y ? vr : ur; const float* im = y ? vi : ui;
  float are = 0.5f * (re[idx] - re[c * Dd + r]);
  float aim = 0.5f * (im[idx] + im[c * Dd + r]);
  size_t pr = (size_t)y * 2 * DD + idx, pi = pr + DD;
  Af32[pr] = are; Af32[pi] = aim;
  u16 h = f2bf(are); Ahi[pr] = h; Alo[pr] = f2bf(are - bf2f(h));
  h = f2bf(aim); Ahi[pi] = h; Alo[pi] = f2bf(aim - bf2f(h));
  float s = are + aim;
  size_t ps = (size_t)y * DD + idx;
  h = f2bf(s); AsumH[ps] = h; AsumL[ps] = f2bf(s - bf2f(h));
}

// X0 = I + A + A^2 ; A^2 from 3 products/y: re = -T0-T1 ; im = T2 - T2^T
__global__ void k_x0(const float* Af32, const float* T, float* Xf32, u16* Xhi, u16* XThi,
                     u16* XsumH, u16* XTsumH) {
  const int y = blockIdx.y;
  const size_t idx = (size_t)blockIdx.x * 256 + threadIdx.x;
  const size_t r = idx >> 10, c = idx & 1023;
  const size_t t0 = (size_t)y * 3 * DD;
  float a2re = -T[t0 + idx] - T[t0 + DD + idx];
  float a2im =  T[t0 + 2 * DD + idx] - T[t0 + 2 * DD + c * Dd + r];
  size_t pr = (size_t)y * 2 * DD + idx, pi = pr + DD;
  float xre = Af32[pr] + a2re + (r == c ? 1.0f : 0.0f);
  float xim = Af32[pi] + a2im;
  Xf32[pr] = xre; Xf32[pi] = xim;
  Xhi[pr] = f2bf(xre); Xhi[pi] = f2bf(xim);
  size_t tr = c * Dd + r;
  size_t qr = (size_t)y * 2 * DD + tr;
  XThi[qr] = f2bf(xre); XThi[qr + DD] = f2bf(xim);
  float s = xre + xim;
  XsumH[(size_t)y * DD + idx] = f2bf(s);
  XTsumH[(size_t)y * DD + tr] = f2bf(s);
}

// Karatsuba combine -> Wt planes. qre = T1-T2, qim = T3-T1-T2 (read transposed).
// Wt[n][k] = (idc*I - X + Q)[k][n] ; also Wsum^T plane.
__global__ void k_wt(const float* Xf32, const float* T, u16* WThi, u16* WTsumH, float idc) {
  const int y = blockIdx.y;
  const size_t idx = (size_t)blockIdx.x * 256 + threadIdx.x;  // write: n*Dd + k
  const size_t n = idx >> 10, k = idx & 1023;
  const size_t ridx = k * Dd + n;
  const size_t t0 = (size_t)y * 3 * DD;
  float t1 = T[t0 + ridx], t2 = T[t0 + DD + ridx], t3 = T[t0 + 2 * DD + ridx];
  size_t pr = (size_t)y * 2 * DD, pi = pr + DD;
  float wre = (n == k ? idc : 0.0f) - Xf32[pr + ridx] + (t1 - t2);
  float wim = -Xf32[pi + ridx] + (t3 - t1 - t2);
  WThi[pr + idx] = f2bf(wre);
  WThi[pi + idx] = f2bf(wim);
  WTsumH[(size_t)y * DD + idx] = f2bf(wre + wim);
}

// X' from Kara planes: re = T1-T2, im = T3-T1-T2 ; emit bf16 + transposed + sum planes
__global__ void k_xn(const float* T, float* Xf32, u16* Xhi, u16* XThi, u16* XsumH, u16* XTsumH,
                     u16* Xlo, u16* XTlo, u16* XTsumL) {
  const int y = blockIdx.y;
  const size_t idx = (size_t)blockIdx.x * 256 + threadIdx.x;
  const size_t r = idx >> 10, c = idx & 1023;
  const size_t t0 = (size_t)y * 3 * DD;
  float t1 = T[t0 + idx], t2 = T[t0 + DD + idx], t3 = T[t0 + 2 * DD + idx];
  float xre = t1 - t2;
  float xim = t3 - t1 - t2;
  size_t pr = (size_t)y * 2 * DD + idx, pi = pr + DD;
  Xf32[pr] = xre; Xf32[pi] = xim;
  u16 hr = f2bf(xre), hi_ = f2bf(xim);
  Xhi[pr] = hr; Xhi[pi] = hi_;
  size_t tr = c * Dd + r;
  size_t qr = (size_t)y * 2 * DD + tr;
  XThi[qr] = hr; XThi[qr + DD] = hi_;
  float s = xre + xim;
  u16 hs = f2bf(s);
  XsumH[(size_t)y * DD + idx] = hs;
  XTsumH[(size_t)y * DD + tr] = hs;
  if (Xlo) {
    u16 lr = f2bf(xre - bf2f(hr)), li = f2bf(xim - bf2f(hi_));
    Xlo[pr] = lr; Xlo[pi] = li;
    XTlo[qr] = lr; XTlo[qr + DD] = li;
    XTsumL[(size_t)y * DD + tr] = f2bf(s - bf2f(hs));
  }
}

// X_r = X + X@R (Kara planes in T); Cay = 2*X_r - I ; emit all GEMM operands
__global__ void k_finalUV(const float* Xf32, const float* T, const float* logsig,
                          u16* VsHi, u16* VsLo, u16* UHi, u16* ULo, u16* UsHi, u16* VHi,
                          u16* UdifH, u16* UdifL, u16* UssumH, u16* VssumH, u16* VssumL, u16* VdifH) {
  const int y = blockIdx.y;
  const size_t idx = (size_t)blockIdx.x * 256 + threadIdx.x;
  const size_t r = idx >> 10, c = idx & 1023;
  const size_t t0 = (size_t)y * 3 * DD;
  float t1 = T[t0 + idx], t2 = T[t0 + DD + idx], t3 = T[t0 + 2 * DD + idx];
  const size_t pr = (size_t)y * 2 * DD + idx, pi = pr + DD;
  float cre = 2.0f * (Xf32[pr] + (t1 - t2)) - (r == c ? 1.0f : 0.0f);
  float cim = 2.0f * (Xf32[pi] + (t3 - t1 - t2));
  if (y == 0) {  // U: hi/lo (Bt of Minv) ; Udiff hi/lo ; U*s hi ; Ussum hi
    u16 h = f2bf(cre); UHi[idx] = h; ULo[idx] = f2bf(cre - bf2f(h));
    h = f2bf(cim); UHi[DD + idx] = h; ULo[DD + idx] = f2bf(cim - bf2f(h));
    float d = cre - cim; h = f2bf(d); UdifH[idx] = h; UdifL[idx] = f2bf(d - bf2f(h));
    float s = expf(logsig[c]);
    UsHi[idx] = f2bf(cre * s); UsHi[DD + idx] = f2bf(cim * s);
    UssumH[idx] = f2bf((cre + cim) * s);
  } else {       // V: hi (Bt of M) ; Vdiff hi ; V*s_inv hi/lo ; Vssum hi/lo
    VHi[idx] = f2bf(cre); VHi[DD + idx] = f2bf(cim);
    VdifH[idx] = f2bf(cre - cim);
    float si = expf(-logsig[c]);
    float a = cre * si, b = cim * si;
    u16 h = f2bf(a); VsHi[idx] = h; VsLo[idx] = f2bf(a - bf2f(h));
    h = f2bf(b); VsHi[DD + idx] = h; VsLo[DD + idx] = f2bf(b - bf2f(h));
    float ss = (cre + cim) * si; h = f2bf(ss); VssumH[idx] = h; VssumL[idx] = f2bf(ss - bf2f(h));
  }
}

// Minv: re = T0+T1, im = T2-T0+T1 ; M: re = T3+T4, im = T5-T3+T4 (conj-Kara)
__global__ void k_cmb_M(const float* T, u16* MiRe, u16* MiIm, u16* MiT, u16* MRe, u16* MIm) {
  const size_t idx = (size_t)blockIdx.x * 256 + threadIdx.x;
  const size_t r = idx >> 10, c = idx & 1023;
  float g1 = T[idx], g2 = T[DD + idx], g3 = T[2 * DD + idx];
  float mire = g1 + g2;
  float miim = g3 - g1 + g2;
  float h1 = T[3 * DD + idx], h2 = T[4 * DD + idx], h3 = T[5 * DD + idx];
  float mre = h1 + h2;
  float mim = h3 - h1 + h2;
  MiRe[idx] = f2bf(mire); MiIm[idx] = f2bf(miim);
  MRe[idx]  = f2bf(mre);  MIm[idx]  = f2bf(mim);
  size_t tr = c * Dd + r;
  u16 h = f2bf(mire); MiT[tr] = h;          MiT[2 * DD + tr] = f2bf(mire - bf2f(h));
  h = f2bf(miim);     MiT[DD + tr] = h;     MiT[3 * DD + tr] = f2bf(miim - bf2f(h));
}

__global__ void k_split(const float* src, u16* hi, u16* lo, size_t n) {
  const size_t idx = (size_t)blockIdx.x * 256 + threadIdx.x;
  if (idx >= n) return;
  float v = src[idx]; u16 h = f2bf(v); hi[idx] = h;
  if (lo) lo[idx] = f2bf(v - bf2f(h));
}

__global__ void k_pointwise(const u16* HtRe, const u16* HtIm, const u16* XtRe, const u16* XtIm,
                            const float* delta, const float* dt, const float* ld, const float* lf,
                            const float* dts, const float* sre, const float* sim,
                            const float* lwre, const float* lwim, const float* selb,
                            u16* HnRe, u16* HnIm, float imSign) {
  const size_t idx = (size_t)blockIdx.x * 256 + threadIdx.x;  // < BD
  const int b = (int)(idx >> 10); const int c = (int)(idx & 1023);
  float dre = delta[(size_t)b * 2048 + c] + selb[c];
  float dim = delta[(size_t)b * 2048 + 1024 + c] + selb[1024 + c];
  float lamre = -expf(ld[c]) + lwre[c] + dre;
  float lamim = lf[c] + lwim[c] + dim;
  float dtv = dt[b];
  float dtn = dtv / dts[c];
  float zre = lamre * dtn, zim = lamim * dtn;
  float r2 = zre * zre + zim * zim;
  float er = expf(zre); float sn, cs; __sincosf(zim, &sn, &cs);
  float dcre = er * cs, dcim = er * sn;
  float p1re, p1im;
  if (r2 < 1e-8f) {
    p1re = 1.0f + 0.5f * zre + (zre * zre - zim * zim) * (1.0f / 6.0f);
    p1im = 0.5f * zim + (zre * zim) * (1.0f / 3.0f);
  } else {
    float inv = 1.0f / r2;
    float nre = dcre - 1.0f, nim = dcim;
    p1re = (nre * zre + nim * zim) * inv;
    p1im = (nim * zre - nre * zim) * inv;
  }
  float fre = p1re * dtv, fim = p1im * dtv;  // phi1 * dt
  float hre = bf2f(HtRe[idx]), him = bf2f(HtIm[idx]);
  float xre = bf2f(XtRe[idx]) + sre[c], xim = bf2f(XtIm[idx]) + sim[c];
  float ore = hre * dcre - him * dcim + xre * fre - xim * fim;
  float oim = hre * dcim + him * dcre + xre * fim + xim * fre;
  HnRe[idx] = f2bf(ore); HnIm[idx] = f2bf(imSign * oim);
}

__global__ void k_fill(float* p, size_t n, float v) {
  const size_t idx = (size_t)blockIdx.x * 256 + threadIdx.x;
  if (idx < n) p[idx] = v;
}

// ---------------- host ----------------
static void launch_gemm(int mode, bool obf, int M, int N, int K, int lda, int ldb,
                        long ldc, int cstride, int nz, const ZP* z, hipStream_t s) {
  GArgs a; a.K = K; a.lda = lda; a.ldb = ldb; a.ldc = ldc; a.cstride = cstride;
  for (int i = 0; i < 8; ++i) a.z[i] = z[i < nz ? i : 0];
  dim3 g(N / 128, M / 128, nz), blk(256);
  if (mode == 1)      gemm_nt<1, false><<<g, blk, 0, s>>>(a);
  else if (mode == 2) gemm_nt<2, false><<<g, blk, 0, s>>>(a);
  else if (obf)       gemm_nt<0, true ><<<g, blk, 0, s>>>(a);
  else                gemm_nt<0, false><<<g, blk, 0, s>>>(a);
}

extern "C" void kernel_launch(void* const* d_in, const int* in_sizes, int n_in,
                              void* d_out, int out_size, void* d_ws, size_t ws_size,
                              hipStream_t stream) {
  const float* h_prev  = (const float*)d_in[0];
  const float* x_input = (const float*)d_in[1];
  const float* dt      = (const float*)d_in[2];
  const float* ur      = (const float*)d_in[3];
  const float* ui      = (const float*)d_in[4];
  const float* vr      = (const float*)d_in[5];
  const float* vi      = (const float*)d_in[6];
  const float* logsig  = (const float*)d_in[7];
  const float* ld      = (const float*)d_in[8];
  const float* lf      = (const float*)d_in[9];
  const float* dts     = (const float*)d_in[10];
  const float* sre     = (const float*)d_in[11];
  const float* sim     = (const float*)d_in[12];
  const float* lwre    = (const float*)d_in[13];
  const float* lwim    = (const float*)d_in[14];
  const float* sel_w   = (const float*)d_in[15];
  const float* sel_b   = (const float*)d_in[16];
  float* out = (float*)d_out;
  char* ws = (char*)d_ws;

  const bool realOnly = ((size_t)out_size == BD);
  const bool interleaved = ((size_t)out_size == 2 * BD);
  if ((!realOnly && !interleaved) || ws_size < 224 * MBy) {
    k_fill<<<dim3(((size_t)out_size + 255) / 256), dim3(256), 0, stream>>>(out, (size_t)out_size, 1e9f);
    return;
  }

  // persistent region [0,16MB)
  u16* MiRe_b = (u16*)(ws + 0 * MBy);
  u16* MiIm_b = (u16*)(ws + 2 * MBy);
  u16* MRe_b  = (u16*)(ws + 4 * MBy);
  u16* MIm_b  = (u16*)(ws + 6 * MBy);
  u16* G_hi   = (u16*)(ws + 8 * MBy);
  u16* G_lo   = (u16*)(ws + 12 * MBy);
  char* AR = ws + 16 * MBy;  // arena
  // phase A
  float* Af32   = (float*)(AR + 0);        // 16 MB (2y x re/im)
  u16* Ahi      = (u16*)(AR + 16 * MBy);   // 8
  u16* Alo      = (u16*)(AR + 24 * MBy);   // 8
  u16* AsumH    = (u16*)(AR + 32 * MBy);   // 4 (2 planes)
  u16* AsumL    = (u16*)(AR + 36 * MBy);   // 4
  float* Xf32   = (float*)(AR + 40 * MBy); // 16
  u16* Xhi      = (u16*)(AR + 56 * MBy);   // 8
  u16* Xlo      = (u16*)(AR + 64 * MBy);   // 8
  u16* XThi     = (u16*)(AR + 72 * MBy);   // 8
  u16* XTlo     = (u16*)(AR + 80 * MBy);   // 8
  u16* XsumH    = (u16*)(AR + 88 * MBy);   // 4
  u16* XTsumH   = (u16*)(AR + 92 * MBy);   // 4
  u16* XTsumL   = (u16*)(AR + 96 * MBy);   // 4
  u16* WThi     = (u16*)(AR + 100 * MBy);  // 8
  u16* WTsumH   = (u16*)(AR + 108 * MBy);  // 4
  float* T      = (float*)(AR + 112 * MBy);// 24 (6 f32 planes)
  u16* VsHi     = (u16*)(AR + 136 * MBy);  // 4
  u16* VsLo     = (u16*)(AR + 140 * MBy);  // 4
  u16* UHi      = (u16*)(AR + 144 * MBy);  // 4
  u16* ULo      = (u16*)(AR + 148 * MBy);  // 4
  u16* UsHi     = (u16*)(AR + 152 * MBy);  // 4
  u16* VHi      = (u16*)(AR + 156 * MBy);  // 4
  u16* UdifH    = (u16*)(AR + 160 * MBy);  // 2
  u16* UdifL    = (u16*)(AR + 162 * MBy);  // 2
  u16* UssumH   = (u16*)(AR + 164 * MBy);  // 2
  u16* VssumH   = (u16*)(AR + 166 * MBy);  // 2
  u16* VssumL   = (u16*)(AR + 168 * MBy);  // 2
  u16* VdifH    = (u16*)(AR + 170 * MBy);  // 2
  u16* MiT      = (u16*)(AR + 172 * MBy);  // 8 (ReT_hi, ImT_hi, ReT_lo, ImT_lo)
  u16* W_hi     = (u16*)(AR + 180 * MBy);  // 8
  u16* W_lo     = (u16*)(AR + 188 * MBy);  // 8
  float* G_f    = (float*)(AR + 196 * MBy);// 8 -> 204
  // phase B (reuses arena)
  u16* Hb     = (u16*)(AR + 0);
  u16* XbHi   = (u16*)(AR + 16 * MBy);
  u16* XbLo   = (u16*)(AR + 32 * MBy);
  u16* HtRe   = (u16*)(AR + 48 * MBy);
  u16* HtIm   = (u16*)(AR + 64 * MBy);
  u16* XtRe   = (u16*)(AR + 80 * MBy);
  u16* XtIm   = (u16*)(AR + 96 * MBy);
  float* delta= (float*)(AR + 112 * MBy);
  u16* HnRe   = (u16*)(AR + 176 * MBy);
  u16* HnIm   = (u16*)(AR + 192 * MBy);

  dim3 b256(256);
  const dim3 gdd(4096, 2);

  // ---- Phase A: Cayley(U), Cayley(V) via Newton + Karatsuba complex products ----
  k_buildA<<<gdd, b256, 0, stream>>>(ur, ui, vr, vi, Af32, Ahi, Alo, AsumH, AsumL);

  {  // A^2: 3 products per y (symmetry trick)
    ZP z[6];
    for (int y = 0; y < 2; ++y) {
      const u16* are = Ahi + (size_t)y * 2 * DD; const u16* aim = are + DD;
      float* t = T + (size_t)y * 3 * DD;
      z[y*3+0] = {are, nullptr, are, nullptr, t,          1.f, 0.f};
      z[y*3+1] = {aim, nullptr, aim, nullptr, t + DD,     1.f, 0.f};
      z[y*3+2] = {are, nullptr, aim, nullptr, t + 2*DD,   1.f, 0.f};
    }
    launch_gemm(0, false, 1024, 1024, 1024, 1024, 1024, 1024, 1, 6, z, stream);
  }
  k_x0<<<gdd, b256, 0, stream>>>(Af32, T, Xf32, Xhi, XThi, XsumH, XTsumH);

  for (int it = 0; it < 2; ++it) {  // bf16 Newton iterations (Kara: 3 planes per product)
    {  // Q = A@X
      ZP z[6];
      for (int y = 0; y < 2; ++y) {
        const u16* are = Ahi + (size_t)y*2*DD; const u16* aim = are + DD;
        const u16* xtr = XThi + (size_t)y*2*DD; const u16* xti = xtr + DD;
        float* t = T + (size_t)y*3*DD;
        z[y*3+0] = {are, nullptr, xtr, nullptr, t,        1.f, 0.f};
        z[y*3+1] = {aim, nullptr, xti, nullptr, t + DD,   1.f, 0.f};
        z[y*3+2] = {AsumH + (size_t)y*DD, nullptr, XTsumH + (size_t)y*DD, nullptr, t + 2*DD, 1.f, 0.f};
      }
      launch_gemm(0, false, 1024, 1024, 1024, 1024, 1024, 1024, 1, 6, z, stream);
    }
    k_wt<<<gdd, b256, 0, stream>>>(Xf32, T, WThi, WTsumH, 2.0f);
    {  // X' = X@W
      ZP z[6];
      for (int y = 0; y < 2; ++y) {
        const u16* xre = Xhi + (size_t)y*2*DD; const u16* xim = xre + DD;
        const u16* wtr = WThi + (size_t)y*2*DD; const u16* wti = wtr + DD;
        float* t = T + (size_t)y*3*DD;
        z[y*3+0] = {xre, nullptr, wtr, nullptr, t,        1.f, 0.f};
        z[y*3+1] = {xim, nullptr, wti, nullptr, t + DD,   1.f, 0.f};
        z[y*3+2] = {XsumH + (size_t)y*DD, nullptr, WTsumH + (size_t)y*DD, nullptr, t + 2*DD, 1.f, 0.f};
      }
      launch_gemm(0, false, 1024, 1024, 1024, 1024, 1024, 1024, 1, 6, z, stream);
    }
    const bool last = (it == 1);
    k_xn<<<gdd, b256, 0, stream>>>(T, Xf32, Xhi, XThi, XsumH, XTsumH,
                                   last ? Xlo : nullptr, last ? XTlo : nullptr,
                                   last ? XTsumL : nullptr);
  }

  {  // refine step 1: Q = A@X split precision (Kara)
    ZP z[6];
    for (int y = 0; y < 2; ++y) {
      const u16* areh = Ahi + (size_t)y*2*DD; const u16* aimh = areh + DD;
      const u16* arel = Alo + (size_t)y*2*DD; const u16* aiml = arel + DD;
      const u16* xtrh = XThi + (size_t)y*2*DD; const u16* xtih = xtrh + DD;
      const u16* xtrl = XTlo + (size_t)y*2*DD; const u16* xtil = xtrl + DD;
      float* t = T + (size_t)y*3*DD;
      z[y*3+0] = {areh, arel, xtrh, xtrl, t,        1.f, 0.f};
      z[y*3+1] = {aimh, aiml, xtih, xtil, t + DD,   1.f, 0.f};
      z[y*3+2] = {AsumH + (size_t)y*DD, AsumL + (size_t)y*DD,
                  XTsumH + (size_t)y*DD, XTsumL + (size_t)y*DD, t + 2*DD, 1.f, 0.f};
    }
    launch_gemm(1, false, 1024, 1024, 1024, 1024, 1024, 1024, 1, 6, z, stream);
  }
  // R = I - MX ; X_r = X + X@R with the product in plain bf16 (Kara)
  k_wt<<<gdd, b256, 0, stream>>>(Xf32, T, WThi, WTsumH, 1.0f);
  {  // XR = X@R
    ZP z[6];
    for (int y = 0; y < 2; ++y) {
      const u16* xre = Xhi + (size_t)y*2*DD; const u16* xim = xre + DD;
      const u16* rtr = WThi + (size_t)y*2*DD; const u16* rti = rtr + DD;
      float* t = T + (size_t)y*3*DD;
      z[y*3+0] = {xre, nullptr, rtr, nullptr, t,        1.f, 0.f};
      z[y*3+1] = {xim, nullptr, rti, nullptr, t + DD,   1.f, 0.f};
      z[y*3+2] = {XsumH + (size_t)y*DD, nullptr, WTsumH + (size_t)y*DD, nullptr, t + 2*DD, 1.f, 0.f};
    }
    launch_gemm(0, false, 1024, 1024, 1024, 1024, 1024, 1024, 1, 6, z, stream);
  }
  k_finalUV<<<gdd, b256, 0, stream>>>(Xf32, T, logsig, VsHi, VsLo, UHi, ULo, UsHi, VHi,
                                      UdifH, UdifL, UssumH, VssumH, VssumL, VdifH);

  {  // Minv = (V s_inv) @ U^H : conj-Kara, split (3 planes)
    ZP z[3] = {
      {VsHi,      VsLo,      UHi,      ULo,      T,        1.f, 0.f},
      {VsHi + DD, VsLo + DD, UHi + DD, ULo + DD, T + DD,   1.f, 0.f},
      {VssumH,    VssumL,    UdifH,    UdifL,    T + 2*DD, 1.f, 0.f}};
    launch_gemm(1, false, 1024, 1024, 1024, 1024, 1024, 1024, 1, 3, z, stream);
  }
  {  // M = (U s) @ V^H : conj-Kara, plain (3 planes)
    ZP z[3] = {
      {UsHi,      nullptr, VHi,      nullptr, T + 3*DD, 1.f, 0.f},
      {UsHi + DD, nullptr, VHi + DD, nullptr, T + 4*DD, 1.f, 0.f},
      {UssumH,    nullptr, VdifH,    nullptr, T + 5*DD, 1.f, 0.f}};
    launch_gemm(0, false, 1024, 1024, 1024, 1024, 1024, 1024, 1, 3, z, stream);
  }
  k_cmb_M<<<dim3(4096), b256, 0, stream>>>(T, MiRe_b, MiIm_b, MiT, MRe_b, MIm_b);

  // G = W1 @ Re(Mi)^T + W2 @ Im(Mi)^T  (split precision; real, no Kara)
  k_split<<<dim3(16384), b256, 0, stream>>>(sel_w, W_hi, W_lo, (size_t)2048 * 2048);
  {
    ZP z1[1] = {{W_hi, W_lo, MiT, MiT + 2*DD, G_f, 1.f, 0.f}};
    launch_gemm(1, false, 2048, 1024, 1024, 2048, 1024, 1024, 1, 1, z1, stream);
  }
  {
    ZP z1[1] = {{W_hi + 1024, W_lo + 1024, MiT + DD, MiT + 3*DD, G_f, 1.f, 1.f}};
    launch_gemm(1, false, 2048, 1024, 1024, 2048, 1024, 1024, 1, 1, z1, stream);
  }
  k_split<<<dim3(8192), b256, 0, stream>>>(G_f, G_hi, G_lo, (size_t)2048 * 1024);

  // ---- Phase B ----
  k_split<<<dim3(32768), b256, 0, stream>>>(x_input, XbHi, XbLo, BD);
  k_split<<<dim3(32768), b256, 0, stream>>>(h_prev, Hb, nullptr, BD);
  {  // encode: h_tilde / x_tilde (bf16 out)
    ZP z[4] = {
      {Hb,   nullptr, MiRe_b, nullptr, HtRe, 1.f, 0.f},
      {Hb,   nullptr, MiIm_b, nullptr, HtIm, 1.f, 0.f},
      {XbHi, nullptr, MiRe_b, nullptr, XtRe, 1.f, 0.f},
      {XbHi, nullptr, MiIm_b, nullptr, XtIm, 1.f, 0.f}};
    launch_gemm(0, true, 8192, 1024, 1024, 1024, 1024, 1024, 1, 4, z, stream);
  }
  // delta = x @ G^T: split only for dt_n-large cols ([0,512) and [1024,1536))
  {  // split half
    ZP z[2] = {
      {XbHi, XbLo, G_hi,                     G_lo,                     delta,        1.f, 0.f},
      {XbHi, XbLo, G_hi + 1024 * (size_t)Dd, G_lo + 1024 * (size_t)Dd, delta + 1024, 1.f, 0.f}};
    launch_gemm(1, false, 8192, 512, 1024, 1024, 1024, 2048, 1, 2, z, stream);
  }
  {  // plain half
    ZP z[2] = {
      {XbHi, nullptr, G_hi + 512 * (size_t)Dd,  nullptr, delta + 512,  1.f, 0.f},
      {XbHi, nullptr, G_hi + 1536 * (size_t)Dd, nullptr, delta + 1536, 1.f, 0.f}};
    launch_gemm(0, false, 8192, 512, 1024, 1024, 1024, 2048, 1, 2, z, stream);
  }

  if (realOnly) {
    k_pointwise<<<dim3(32768), b256, 0, stream>>>(HtRe, HtIm, XtRe, XtIm, delta, dt, ld, lf, dts,
                                                  sre, sim, lwre, lwim, sel_b, HnRe, HnIm, -1.0f);
    ZP z1[1] = {{HnRe, HnIm, MRe_b, MIm_b, out, 1.f, 0.f}};
    launch_gemm(2, false, 8192, 1024, 1024, 1024, 1024, 1024, 1, 1, z1, stream);
  } else {
    k_pointwise<<<dim3(32768), b256, 0, stream>>>(HtRe, HtIm, XtRe, XtIm, delta, dt, ld, lf, dts,
                                                  sre, sim, lwre, lwim, sel_b, HnRe, HnIm, 1.0f);
    {
      ZP z[2] = {
        {HnRe, nullptr, MRe_b, nullptr, out,     1.f, 0.f},
        {HnRe, nullptr, MIm_b, nullptr, out + 1, 1.f, 0.f}};
      launch_gemm(0, false, 8192, 1024, 1024, 1024, 1024, 2048, 2, 2, z, stream);
    }
    {
      ZP z[2] = {
        {HnIm, nullptr, MIm_b, nullptr, out,     -1.f, 1.f},
        {HnIm, nullptr, MRe_b, nullptr, out + 1,  1.f, 1.f}};
      launch_gemm(0, false, 8192, 1024, 1024, 1024, 1024, 2048, 2, 2, z, stream);
    }
  }
}

// Round 6
// 965.817 us; speedup vs baseline: 1.1055x; 1.1055x over previous
//
#include <hip/hip_runtime.h>
#include <hip/hip_bf16.h>

#define Dd 1024
#define Bb 8192

typedef unsigned short u16;
typedef __attribute__((ext_vector_type(8))) short short8;
typedef __attribute__((ext_vector_type(4))) float f32x4;

static constexpr size_t DD  = (size_t)Dd * Dd;   // 1M
static constexpr size_t BD  = (size_t)Bb * Dd;   // 8M
static constexpr size_t MBy = 1ull << 20;

__device__ __forceinline__ float bf2f(u16 v) {
  union { unsigned u; float f; } c; c.u = ((unsigned)v) << 16; return c.f;
}
__device__ __forceinline__ u16 f2bf(float f) {
  union { float f; unsigned u; } c; c.f = f;
  return (u16)((c.u + 0x7fffu + ((c.u >> 16) & 1u)) >> 16);
}

// ---------------- NT GEMM: C[m][n] = alpha * sum_k A[m][k]*Bt[n][k] (+beta*C) ----------
// MODE 0: 1 MFMA (Ah*Bh) ; MODE 1: 3 MFMA (AhBh+AlBh+AhBl) split ; MODE 2: 2 MFMA (AhBh+AlBl) pair
// K-loop: 2-phase prefetch (double-buffered LDS, stage t+1 during compute t)  [T3-min]
// LDS layout: XOR-swizzled via pre-swizzled GLOBAL source + swizzled ds_read  [T2, rule #21]
struct ZP { const u16* Ah; const u16* Al; const u16* Bh; const u16* Bl; void* C; float alpha; float beta; };
struct GArgs { ZP z[8]; int K, lda, ldb; long ldc; int cstride; };

template<int MODE, bool OBF>
__global__ __launch_bounds__(256) void gemm_nt(GArgs a) {
  constexpr bool X2 = (MODE != 0);
  constexpr int BUFS = X2 ? 32768 : 16384;       // u16 per LDS buffer
  __shared__ __align__(16) u16 smem[2 * BUFS];   // 64 KB (MODE0) / 128 KB (MODE1/2)
  const ZP p = a.z[blockIdx.z];
  const int tid  = threadIdx.x;
  const int lane = tid & 63, wv = tid >> 6;

  // XCD-chunked swizzle (per z-slice; bijective when nwg%8==0)  [T1]
  int bx = blockIdx.x, by = blockIdx.y;
  {
    const int gx = gridDim.x;
    const int nwg = gx * gridDim.y;
    if ((nwg & 7) == 0 && nwg >= 16) {
      const int flat = by * gx + bx;
      const int ch = nwg >> 3;
      const int nf = (flat & 7) * ch + (flat >> 3);
      bx = nf % gx; by = nf / gx;
    }
  }

  const long brow = (long)by * 128, bcol = (long)bx * 128;
  const int wm = (wv & 1) * 64, wn = (wv >> 1) * 64;
  const int srow = wv * 8 + (lane >> 3);
  // swizzled global col chunk: LDS[row][c] will hold global[row][c ^ (row&7)]
  const int sgc  = ((lane & 7) ^ (lane >> 3)) * 8;   // elements

  f32x4 acc[4][4];
#pragma unroll
  for (int i = 0; i < 4; ++i)
#pragma unroll
    for (int j = 0; j < 4; ++j) { f32x4 zv = {0.f, 0.f, 0.f, 0.f}; acc[i][j] = zv; }

  auto STAGE = [&](int kt, int buf) {
    u16* As = smem + buf * BUFS;
    u16* Bs = As + 8192;
#pragma unroll
    for (int i = 0; i < 4; ++i) {
      const int rr = i * 32 + srow;
      const int lb = (i * 32 + wv * 8) * 64;
      const u16* ga = p.Ah + (brow + rr) * (long)a.lda + kt + sgc;
      const u16* gb = p.Bh + (bcol + rr) * (long)a.ldb + kt + sgc;
      __builtin_amdgcn_global_load_lds((const __attribute__((address_space(1))) void*)ga,
                                       (__attribute__((address_space(3))) void*)(As + lb), 16, 0, 0);
      __builtin_amdgcn_global_load_lds((const __attribute__((address_space(1))) void*)gb,
                                       (__attribute__((address_space(3))) void*)(Bs + lb), 16, 0, 0);
      if constexpr (X2) {
        const u16* ga2 = p.Al + (brow + rr) * (long)a.lda + kt + sgc;
        const u16* gb2 = p.Bl + (bcol + rr) * (long)a.ldb + kt + sgc;
        __builtin_amdgcn_global_load_lds((const __attribute__((address_space(1))) void*)ga2,
                                         (__attribute__((address_space(3))) void*)(As + 16384 + lb), 16, 0, 0);
        __builtin_amdgcn_global_load_lds((const __attribute__((address_space(1))) void*)gb2,
                                         (__attribute__((address_space(3))) void*)(As + 24576 + lb), 16, 0, 0);
      }
    }
  };

  auto COMPUTE = [&](int buf) {
    u16* As = smem + buf * BUFS;
    u16* Bs = As + 8192;
#pragma unroll
    for (int kk = 0; kk < 64; kk += 32) {
      const int jf = (kk >> 3) + (lane >> 4);            // col chunk index 0..7
      const int cs = ((jf ^ (lane & 7)) << 3);           // swizzled read offset (elems)
      short8 af[4], bfv[4], al[4], bl[4];
#pragma unroll
      for (int i = 0; i < 4; ++i) {
        af[i]  = *(const short8*)(As + (wm + i * 16 + (lane & 15)) * 64 + cs);
        bfv[i] = *(const short8*)(Bs + (wn + i * 16 + (lane & 15)) * 64 + cs);
        if constexpr (X2) {
          al[i] = *(const short8*)(As + 16384 + (wm + i * 16 + (lane & 15)) * 64 + cs);
          bl[i] = *(const short8*)(As + 24576 + (wn + i * 16 + (lane & 15)) * 64 + cs);
        }
      }
#pragma unroll
      for (int i = 0; i < 4; ++i)
#pragma unroll
        for (int j = 0; j < 4; ++j) {
          acc[i][j] = __builtin_amdgcn_mfma_f32_16x16x32_bf16(af[i], bfv[j], acc[i][j], 0, 0, 0);
          if constexpr (MODE == 1) {
            acc[i][j] = __builtin_amdgcn_mfma_f32_16x16x32_bf16(al[i], bfv[j], acc[i][j], 0, 0, 0);
            acc[i][j] = __builtin_amdgcn_mfma_f32_16x16x32_bf16(af[i], bl[j], acc[i][j], 0, 0, 0);
          } else if constexpr (MODE == 2) {
            acc[i][j] = __builtin_amdgcn_mfma_f32_16x16x32_bf16(al[i], bl[j], acc[i][j], 0, 0, 0);
          }
        }
    }
  };

  const int nkt = a.K >> 6;
  STAGE(0, 0);
  __syncthreads();                 // drain prologue stage
  int cur = 0;
  for (int t = 0; t < nkt - 1; ++t) {
    STAGE((t + 1) * 64, cur ^ 1);  // issue next tile's loads (fly during compute)
    COMPUTE(cur);
    __syncthreads();               // vmcnt(0)+barrier: next buffer ready, old buffer free
    cur ^= 1;
  }
  COMPUTE(cur);

  const long crow = brow + wm + ((lane >> 4) * 4);
  const long ccol = bcol + wn + (lane & 15);
#pragma unroll
  for (int i = 0; i < 4; ++i)
#pragma unroll
    for (int j = 0; j < 4; ++j)
#pragma unroll
      for (int r = 0; r < 4; ++r) {
        const long cidx = (crow + i * 16 + r) * a.ldc + (ccol + j * 16) * (long)a.cstride;
        float v = acc[i][j][r] * p.alpha;
        if constexpr (OBF) {
          ((u16*)p.C)[cidx] = f2bf(v);
        } else {
          float* C = (float*)p.C;
          if (p.beta != 0.0f) v += p.beta * C[cidx];
          C[cidx] = v;
        }
      }
}

// ---------------- elementwise kernels ----------------
// complex d x d planes: [y*2*DD] = re, [y*2*DD + DD] = im ; sum planes: [y*DD]

__global__ void k_buildA(const float* ur, const float* ui, const float* vr, const float* vi,
                         float* Af32, u16* Ahi, u16* Alo, u16* AsumH, u16* AsumL) {
  const int y = blockIdx.y;
  const size_t idx = (size_t)blockIdx.x * 256 + threadIdx.x;
  const size_t r = idx >> 10, c = idx & 1023;
  const float* re = y ? vr : ur; const float* im = y ? vi : ui;
  float are = 0.5f * (re[idx] - re[c * Dd + r]);
  float aim = 0.5f * (im[idx] + im[c * Dd + r]);
  size_t pr = (size_t)y * 2 * DD + idx, pi = pr + DD;
  Af32[pr] = are; Af32[pi] = aim;
  u16 h = f2bf(are); Ahi[pr] = h; Alo[pr] = f2bf(are - bf2f(h));
  h = f2bf(aim); Ahi[pi] = h; Alo[pi] = f2bf(aim - bf2f(h));
  float s = are + aim;
  size_t ps = (size_t)y * DD + idx;
  h = f2bf(s); AsumH[ps] = h; AsumL[ps] = f2bf(s - bf2f(h));
}

// X0 = I + A + A^2 ; A^2 from 3 products/y: re = -T0-T1 ; im = T2 - T2^T
__global__ void k_x0(const float* Af32, const float* T, float* Xf32, u16* Xhi, u16* XThi,
                     u16* XsumH, u16* XTsumH) {
  const int y = blockIdx.y;
  const size_t idx = (size_t)blockIdx.x * 256 + threadIdx.x;
  const size_t r = idx >> 10, c = idx & 1023;
  const size_t t0 = (size_t)y * 3 * DD;
  float a2re = -T[t0 + idx] - T[t0 + DD + idx];
  float a2im =  T[t0 + 2 * DD + idx] - T[t0 + 2 * DD + c * Dd + r];
  size_t pr = (size_t)y * 2 * DD + idx, pi = pr + DD;
  float xre = Af32[pr] + a2re + (r == c ? 1.0f : 0.0f);
  float xim = Af32[pi] + a2im;
  Xf32[pr] = xre; Xf32[pi] = xim;
  Xhi[pr] = f2bf(xre); Xhi[pi] = f2bf(xim);
  size_t tr = c * Dd + r;
  size_t qr = (size_t)y * 2 * DD + tr;
  XThi[qr] = f2bf(xre); XThi[qr + DD] = f2bf(xim);
  float s = xre + xim;
  XsumH[(size_t)y * DD + idx] = f2bf(s);
  XTsumH[(size_t)y * DD + tr] = f2bf(s);
}

// Karatsuba combine -> Wt planes. qre = T1-T2, qim = T3-T1-T2 (read transposed).
// Wt[n][k] = (idc*I - X + Q)[k][n] ; also Wsum^T plane.
__global__ void k_wt(const float* Xf32, const float* T, u16* WThi, u16* WTsumH, float idc) {
  const int y = blockIdx.y;
  const size_t idx = (size_t)blockIdx.x * 256 + threadIdx.x;  // write: n*Dd + k
  const size_t n = idx >> 10, k = idx & 1023;
  const size_t ridx = k * Dd + n;
  const size_t t0 = (size_t)y * 3 * DD;
  float t1 = T[t0 + ridx], t2 = T[t0 + DD + ridx], t3 = T[t0 + 2 * DD + ridx];
  size_t pr = (size_t)y * 2 * DD, pi = pr + DD;
  float wre = (n == k ? idc : 0.0f) - Xf32[pr + ridx] + (t1 - t2);
  float wim = -Xf32[pi + ridx] + (t3 - t1 - t2);
  WThi[pr + idx] = f2bf(wre);
  WThi[pi + idx] = f2bf(wim);
  WTsumH[(size_t)y * DD + idx] = f2bf(wre + wim);
}

// X' from Kara planes: re = T1-T2, im = T3-T1-T2 ; emit bf16 + transposed + sum planes
__global__ void k_xn(const float* T, float* Xf32, u16* Xhi, u16* XThi, u16* XsumH, u16* XTsumH,
                     u16* Xlo, u16* XTlo, u16* XTsumL) {
  const int y = blockIdx.y;
  const size_t idx = (size_t)blockIdx.x * 256 + threadIdx.x;
  const size_t r = idx >> 10, c = idx & 1023;
  const size_t t0 = (size_t)y * 3 * DD;
  float t1 = T[t0 + idx], t2 = T[t0 + DD + idx], t3 = T[t0 + 2 * DD + idx];
  float xre = t1 - t2;
  float xim = t3 - t1 - t2;
  size_t pr = (size_t)y * 2 * DD + idx, pi = pr + DD;
  Xf32[pr] = xre; Xf32[pi] = xim;
  u16 hr = f2bf(xre), hi_ = f2bf(xim);
  Xhi[pr] = hr; Xhi[pi] = hi_;
  size_t tr = c * Dd + r;
  size_t qr = (size_t)y * 2 * DD + tr;
  XThi[qr] = hr; XThi[qr + DD] = hi_;
  float s = xre + xim;
  u16 hs = f2bf(s);
  XsumH[(size_t)y * DD + idx] = hs;
  XTsumH[(size_t)y * DD + tr] = hs;
  if (Xlo) {
    u16 lr = f2bf(xre - bf2f(hr)), li = f2bf(xim - bf2f(hi_));
    Xlo[pr] = lr; Xlo[pi] = li;
    XTlo[qr] = lr; XTlo[qr + DD] = li;
    XTsumL[(size_t)y * DD + tr] = f2bf(s - bf2f(hs));
  }
}

// X_r = X + X@R (Kara planes in T); Cay = 2*X_r - I ; emit all GEMM operands
__global__ void k_finalUV(const float* Xf32, const float* T, const float* logsig,
                          u16* VsHi, u16* VsLo, u16* UHi, u16* ULo, u16* UsHi, u16* VHi,
                          u16* UdifH, u16* UdifL, u16* UssumH, u16* VssumH, u16* VssumL, u16* VdifH) {
  const int y = blockIdx.y;
  const size_t idx = (size_t)blockIdx.x * 256 + threadIdx.x;
  const size_t r = idx >> 10, c = idx & 1023;
  const size_t t0 = (size_t)y * 3 * DD;
  float t1 = T[t0 + idx], t2 = T[t0 + DD + idx], t3 = T[t0 + 2 * DD + idx];
  const size_t pr = (size_t)y * 2 * DD + idx, pi = pr + DD;
  float cre = 2.0f * (Xf32[pr] + (t1 - t2)) - (r == c ? 1.0f : 0.0f);
  float cim = 2.0f * (Xf32[pi] + (t3 - t1 - t2));
  if (y == 0) {  // U: hi/lo (Bt of Minv) ; Udiff hi/lo ; U*s hi ; Ussum hi
    u16 h = f2bf(cre); UHi[idx] = h; ULo[idx] = f2bf(cre - bf2f(h));
    h = f2bf(cim); UHi[DD + idx] = h; ULo[DD + idx] = f2bf(cim - bf2f(h));
    float d = cre - cim; h = f2bf(d); UdifH[idx] = h; UdifL[idx] = f2bf(d - bf2f(h));
    float s = expf(logsig[c]);
    UsHi[idx] = f2bf(cre * s); UsHi[DD + idx] = f2bf(cim * s);
    UssumH[idx] = f2bf((cre + cim) * s);
  } else {       // V: hi (Bt of M) ; Vdiff hi ; V*s_inv hi/lo ; Vssum hi/lo
    VHi[idx] = f2bf(cre); VHi[DD + idx] = f2bf(cim);
    VdifH[idx] = f2bf(cre - cim);
    float si = expf(-logsig[c]);
    float a = cre * si, b = cim * si;
    u16 h = f2bf(a); VsHi[idx] = h; VsLo[idx] = f2bf(a - bf2f(h));
    h = f2bf(b); VsHi[DD + idx] = h; VsLo[DD + idx] = f2bf(b - bf2f(h));
    float ss = (cre + cim) * si; h = f2bf(ss); VssumH[idx] = h; VssumL[idx] = f2bf(ss - bf2f(h));
  }
}

// Minv: re = T0+T1, im = T2-T0+T1 ; M: re = T3+T4, im = T5-T3+T4 (conj-Kara)
__global__ void k_cmb_M(const float* T, u16* MiRe, u16* MiIm, u16* MiT, u16* MRe, u16* MIm) {
  const size_t idx = (size_t)blockIdx.x * 256 + threadIdx.x;
  const size_t r = idx >> 10, c = idx & 1023;
  float g1 = T[idx], g2 = T[DD + idx], g3 = T[2 * DD + idx];
  float mire = g1 + g2;
  float miim = g3 - g1 + g2;
  float h1 = T[3 * DD + idx], h2 = T[4 * DD + idx], h3 = T[5 * DD + idx];
  float mre = h1 + h2;
  float mim = h3 - h1 + h2;
  MiRe[idx] = f2bf(mire); MiIm[idx] = f2bf(miim);
  MRe[idx]  = f2bf(mre);  MIm[idx]  = f2bf(mim);
  size_t tr = c * Dd + r;
  u16 h = f2bf(mire); MiT[tr] = h;          MiT[2 * DD + tr] = f2bf(mire - bf2f(h));
  h = f2bf(miim);     MiT[DD + tr] = h;     MiT[3 * DD + tr] = f2bf(miim - bf2f(h));
}

__global__ void k_split(const float* src, u16* hi, u16* lo, size_t n) {
  const size_t idx = (size_t)blockIdx.x * 256 + threadIdx.x;
  if (idx >= n) return;
  float v = src[idx]; u16 h = f2bf(v); hi[idx] = h;
  if (lo) lo[idx] = f2bf(v - bf2f(h));
}

__global__ void k_pointwise(const u16* HtRe, const u16* HtIm, const u16* XtRe, const u16* XtIm,
                            const float* delta, const float* dt, const float* ld, const float* lf,
                            const float* dts, const float* sre, const float* sim,
                            const float* lwre, const float* lwim, const float* selb,
                            u16* HnRe, u16* HnIm, float imSign) {
  const size_t idx = (size_t)blockIdx.x * 256 + threadIdx.x;  // < BD
  const int b = (int)(idx >> 10); const int c = (int)(idx & 1023);
  float dre = delta[(size_t)b * 2048 + c] + selb[c];
  float dim = delta[(size_t)b * 2048 + 1024 + c] + selb[1024 + c];
  float lamre = -expf(ld[c]) + lwre[c] + dre;
  float lamim = lf[c] + lwim[c] + dim;
  float dtv = dt[b];
  float dtn = dtv / dts[c];
  float zre = lamre * dtn, zim = lamim * dtn;
  float r2 = zre * zre + zim * zim;
  float er = expf(zre); float sn, cs; __sincosf(zim, &sn, &cs);
  float dcre = er * cs, dcim = er * sn;
  float p1re, p1im;
  if (r2 < 1e-8f) {
    p1re = 1.0f + 0.5f * zre + (zre * zre - zim * zim) * (1.0f / 6.0f);
    p1im = 0.5f * zim + (zre * zim) * (1.0f / 3.0f);
  } else {
    float inv = 1.0f / r2;
    float nre = dcre - 1.0f, nim = dcim;
    p1re = (nre * zre + nim * zim) * inv;
    p1im = (nim * zre - nre * zim) * inv;
  }
  float fre = p1re * dtv, fim = p1im * dtv;  // phi1 * dt
  float hre = bf2f(HtRe[idx]), him = bf2f(HtIm[idx]);
  float xre = bf2f(XtRe[idx]) + sre[c], xim = bf2f(XtIm[idx]) + sim[c];
  float ore = hre * dcre - him * dcim + xre * fre - xim * fim;
  float oim = hre * dcim + him * dcre + xre * fim + xim * fre;
  HnRe[idx] = f2bf(ore); HnIm[idx] = f2bf(imSign * oim);
}

__global__ void k_fill(float* p, size_t n, float v) {
  const size_t idx = (size_t)blockIdx.x * 256 + threadIdx.x;
  if (idx < n) p[idx] = v;
}

// ---------------- host ----------------
static void launch_gemm(int mode, bool obf, int M, int N, int K, int lda, int ldb,
                        long ldc, int cstride, int nz, const ZP* z, hipStream_t s) {
  GArgs a; a.K = K; a.lda = lda; a.ldb = ldb; a.ldc = ldc; a.cstride = cstride;
  for (int i = 0; i < 8; ++i) a.z[i] = z[i < nz ? i : 0];
  dim3 g(N / 128, M / 128, nz), blk(256);
  if (mode == 1)      gemm_nt<1, false><<<g, blk, 0, s>>>(a);
  else if (mode == 2) gemm_nt<2, false><<<g, blk, 0, s>>>(a);
  else if (obf)       gemm_nt<0, true ><<<g, blk, 0, s>>>(a);
  else                gemm_nt<0, false><<<g, blk, 0, s>>>(a);
}

extern "C" void kernel_launch(void* const* d_in, const int* in_sizes, int n_in,
                              void* d_out, int out_size, void* d_ws, size_t ws_size,
                              hipStream_t stream) {
  const float* h_prev  = (const float*)d_in[0];
  const float* x_input = (const float*)d_in[1];
  const float* dt      = (const float*)d_in[2];
  const float* ur      = (const float*)d_in[3];
  const float* ui      = (const float*)d_in[4];
  const float* vr      = (const float*)d_in[5];
  const float* vi      = (const float*)d_in[6];
  const float* logsig  = (const float*)d_in[7];
  const float* ld      = (const float*)d_in[8];
  const float* lf      = (const float*)d_in[9];
  const float* dts     = (const float*)d_in[10];
  const float* sre     = (const float*)d_in[11];
  const float* sim     = (const float*)d_in[12];
  const float* lwre    = (const float*)d_in[13];
  const float* lwim    = (const float*)d_in[14];
  const float* sel_w   = (const float*)d_in[15];
  const float* sel_b   = (const float*)d_in[16];
  float* out = (float*)d_out;
  char* ws = (char*)d_ws;

  const bool realOnly = ((size_t)out_size == BD);
  const bool interleaved = ((size_t)out_size == 2 * BD);
  if ((!realOnly && !interleaved) || ws_size < 224 * MBy) {
    k_fill<<<dim3(((size_t)out_size + 255) / 256), dim3(256), 0, stream>>>(out, (size_t)out_size, 1e9f);
    return;
  }

  // persistent region [0,16MB)
  u16* MiRe_b = (u16*)(ws + 0 * MBy);
  u16* MiIm_b = (u16*)(ws + 2 * MBy);
  u16* MRe_b  = (u16*)(ws + 4 * MBy);
  u16* MIm_b  = (u16*)(ws + 6 * MBy);
  u16* G_hi   = (u16*)(ws + 8 * MBy);
  u16* G_lo   = (u16*)(ws + 12 * MBy);
  char* AR = ws + 16 * MBy;  // arena
  // phase A
  float* Af32   = (float*)(AR + 0);        // 16 MB (2y x re/im)
  u16* Ahi      = (u16*)(AR + 16 * MBy);   // 8
  u16* Alo      = (u16*)(AR + 24 * MBy);   // 8
  u16* AsumH    = (u16*)(AR + 32 * MBy);   // 4 (2 planes)
  u16* AsumL    = (u16*)(AR + 36 * MBy);   // 4
  float* Xf32   = (float*)(AR + 40 * MBy); // 16
  u16* Xhi      = (u16*)(AR + 56 * MBy);   // 8
  u16* Xlo      = (u16*)(AR + 64 * MBy);   // 8
  u16* XThi     = (u16*)(AR + 72 * MBy);   // 8
  u16* XTlo     = (u16*)(AR + 80 * MBy);   // 8
  u16* XsumH    = (u16*)(AR + 88 * MBy);   // 4
  u16* XTsumH   = (u16*)(AR + 92 * MBy);   // 4
  u16* XTsumL   = (u16*)(AR + 96 * MBy);   // 4
  u16* WThi     = (u16*)(AR + 100 * MBy);  // 8
  u16* WTsumH   = (u16*)(AR + 108 * MBy);  // 4
  float* T      = (float*)(AR + 112 * MBy);// 24 (6 f32 planes)
  u16* VsHi     = (u16*)(AR + 136 * MBy);  // 4
  u16* VsLo     = (u16*)(AR + 140 * MBy);  // 4
  u16* UHi      = (u16*)(AR + 144 * MBy);  // 4
  u16* ULo      = (u16*)(AR + 148 * MBy);  // 4
  u16* UsHi     = (u16*)(AR + 152 * MBy);  // 4
  u16* VHi      = (u16*)(AR + 156 * MBy);  // 4
  u16* UdifH    = (u16*)(AR + 160 * MBy);  // 2
  u16* UdifL    = (u16*)(AR + 162 * MBy);  // 2
  u16* UssumH   = (u16*)(AR + 164 * MBy);  // 2
  u16* VssumH   = (u16*)(AR + 166 * MBy);  // 2
  u16* VssumL   = (u16*)(AR + 168 * MBy);  // 2
  u16* VdifH    = (u16*)(AR + 170 * MBy);  // 2
  u16* MiT      = (u16*)(AR + 172 * MBy);  // 8 (ReT_hi, ImT_hi, ReT_lo, ImT_lo)
  u16* W_hi     = (u16*)(AR + 180 * MBy);  // 8
  u16* W_lo     = (u16*)(AR + 188 * MBy);  // 8
  float* G_f    = (float*)(AR + 196 * MBy);// 8 -> 204
  // phase B (reuses arena)
  u16* Hb     = (u16*)(AR + 0);
  u16* XbHi   = (u16*)(AR + 16 * MBy);
  u16* XbLo   = (u16*)(AR + 32 * MBy);
  u16* HtRe   = (u16*)(AR + 48 * MBy);
  u16* HtIm   = (u16*)(AR + 64 * MBy);
  u16* XtRe   = (u16*)(AR + 80 * MBy);
  u16* XtIm   = (u16*)(AR + 96 * MBy);
  float* delta= (float*)(AR + 112 * MBy);
  u16* HnRe   = (u16*)(AR + 176 * MBy);
  u16* HnIm   = (u16*)(AR + 192 * MBy);

  dim3 b256(256);
  const dim3 gdd(4096, 2);

  // ---- Phase A: Cayley(U), Cayley(V) via Newton + Karatsuba complex products ----
  k_buildA<<<gdd, b256, 0, stream>>>(ur, ui, vr, vi, Af32, Ahi, Alo, AsumH, AsumL);

  {  // A^2: 3 products per y (symmetry trick)
    ZP z[6];
    for (int y = 0; y < 2; ++y) {
      const u16* are = Ahi + (size_t)y * 2 * DD; const u16* aim = are + DD;
      float* t = T + (size_t)y * 3 * DD;
      z[y*3+0] = {are, nullptr, are, nullptr, t,          1.f, 0.f};
      z[y*3+1] = {aim, nullptr, aim, nullptr, t + DD,     1.f, 0.f};
      z[y*3+2] = {are, nullptr, aim, nullptr, t + 2*DD,   1.f, 0.f};
    }
    launch_gemm(0, false, 1024, 1024, 1024, 1024, 1024, 1024, 1, 6, z, stream);
  }
  k_x0<<<gdd, b256, 0, stream>>>(Af32, T, Xf32, Xhi, XThi, XsumH, XTsumH);

  for (int it = 0; it < 2; ++it) {  // bf16 Newton iterations (Kara: 3 planes per product)
    {  // Q = A@X
      ZP z[6];
      for (int y = 0; y < 2; ++y) {
        const u16* are = Ahi + (size_t)y*2*DD; const u16* aim = are + DD;
        const u16* xtr = XThi + (size_t)y*2*DD; const u16* xti = xtr + DD;
        float* t = T + (size_t)y*3*DD;
        z[y*3+0] = {are, nullptr, xtr, nullptr, t,        1.f, 0.f};
        z[y*3+1] = {aim, nullptr, xti, nullptr, t + DD,   1.f, 0.f};
        z[y*3+2] = {AsumH + (size_t)y*DD, nullptr, XTsumH + (size_t)y*DD, nullptr, t + 2*DD, 1.f, 0.f};
      }
      launch_gemm(0, false, 1024, 1024, 1024, 1024, 1024, 1024, 1, 6, z, stream);
    }
    k_wt<<<gdd, b256, 0, stream>>>(Xf32, T, WThi, WTsumH, 2.0f);
    {  // X' = X@W
      ZP z[6];
      for (int y = 0; y < 2; ++y) {
        const u16* xre = Xhi + (size_t)y*2*DD; const u16* xim = xre + DD;
        const u16* wtr = WThi + (size_t)y*2*DD; const u16* wti = wtr + DD;
        float* t = T + (size_t)y*3*DD;
        z[y*3+0] = {xre, nullptr, wtr, nullptr, t,        1.f, 0.f};
        z[y*3+1] = {xim, nullptr, wti, nullptr, t + DD,   1.f, 0.f};
        z[y*3+2] = {XsumH + (size_t)y*DD, nullptr, WTsumH + (size_t)y*DD, nullptr, t + 2*DD, 1.f, 0.f};
      }
      launch_gemm(0, false, 1024, 1024, 1024, 1024, 1024, 1024, 1, 6, z, stream);
    }
    const bool last = (it == 1);
    k_xn<<<gdd, b256, 0, stream>>>(T, Xf32, Xhi, XThi, XsumH, XTsumH,
                                   last ? Xlo : nullptr, last ? XTlo : nullptr,
                                   last ? XTsumL : nullptr);
  }

  {  // refine step 1: Q = A@X split precision (Kara)
    ZP z[6];
    for (int y = 0; y < 2; ++y) {
      const u16* areh = Ahi + (size_t)y*2*DD; const u16* aimh = areh + DD;
      const u16* arel = Alo + (size_t)y*2*DD; const u16* aiml = arel + DD;
      const u16* xtrh = XThi + (size_t)y*2*DD; const u16* xtih = xtrh + DD;
      const u16* xtrl = XTlo + (size_t)y*2*DD; const u16* xtil = xtrl + DD;
      float* t = T + (size_t)y*3*DD;
      z[y*3+0] = {areh, arel, xtrh, xtrl, t,        1.f, 0.f};
      z[y*3+1] = {aimh, aiml, xtih, xtil, t + DD,   1.f, 0.f};
      z[y*3+2] = {AsumH + (size_t)y*DD, AsumL + (size_t)y*DD,
                  XTsumH + (size_t)y*DD, XTsumL + (size_t)y*DD, t + 2*DD, 1.f, 0.f};
    }
    launch_gemm(1, false, 1024, 1024, 1024, 1024, 1024, 1024, 1, 6, z, stream);
  }
  // R = I - MX ; X_r = X + X@R with the product in plain bf16 (Kara)
  k_wt<<<gdd, b256, 0, stream>>>(Xf32, T, WThi, WTsumH, 1.0f);
  {  // XR = X@R
    ZP z[6];
    for (int y = 0; y < 2; ++y) {
      const u16* xre = Xhi + (size_t)y*2*DD; const u16* xim = xre + DD;
      const u16* rtr = WThi + (size_t)y*2*DD; const u16* rti = rtr + DD;
      float* t = T + (size_t)y*3*DD;
      z[y*3+0] = {xre, nullptr, rtr, nullptr, t,        1.f, 0.f};
      z[y*3+1] = {xim, nullptr, rti, nullptr, t + DD,   1.f, 0.f};
      z[y*3+2] = {XsumH + (size_t)y*DD, nullptr, WTsumH + (size_t)y*DD, nullptr, t + 2*DD, 1.f, 0.f};
    }
    launch_gemm(0, false, 1024, 1024, 1024, 1024, 1024, 1024, 1, 6, z, stream);
  }
  k_finalUV<<<gdd, b256, 0, stream>>>(Xf32, T, logsig, VsHi, VsLo, UHi, ULo, UsHi, VHi,
                                      UdifH, UdifL, UssumH, VssumH, VssumL, VdifH);

  {  // Minv = (V s_inv) @ U^H : conj-Kara, split (3 planes)
    ZP z[3] = {
      {VsHi,      VsLo,      UHi,      ULo,      T,        1.f, 0.f},
      {VsHi + DD, VsLo + DD, UHi + DD, ULo + DD, T + DD,   1.f, 0.f},
      {VssumH,    VssumL,    UdifH,    UdifL,    T + 2*DD, 1.f, 0.f}};
    launch_gemm(1, false, 1024, 1024, 1024, 1024, 1024, 1024, 1, 3, z, stream);
  }
  {  // M = (U s) @ V^H : conj-Kara, plain (3 planes)
    ZP z[3] = {
      {UsHi,      nullptr, VHi,      nullptr, T + 3*DD, 1.f, 0.f},
      {UsHi + DD, nullptr, VHi + DD, nullptr, T + 4*DD, 1.f, 0.f},
      {UssumH,    nullptr, VdifH,    nullptr, T + 5*DD, 1.f, 0.f}};
    launch_gemm(0, false, 1024, 1024, 1024, 1024, 1024, 1024, 1, 3, z, stream);
  }
  k_cmb_M<<<dim3(4096), b256, 0, stream>>>(T, MiRe_b, MiIm_b, MiT, MRe_b, MIm_b);

  // G = W1 @ Re(Mi)^T + W2 @ Im(Mi)^T  (split precision; real, no Kara)
  k_split<<<dim3(16384), b256, 0, stream>>>(sel_w, W_hi, W_lo, (size_t)2048 * 2048);
  {
    ZP z1[1] = {{W_hi, W_lo, MiT, MiT + 2*DD, G_f, 1.f, 0.f}};
    launch_gemm(1, false, 2048, 1024, 1024, 2048, 1024, 1024, 1, 1, z1, stream);
  }
  {
    ZP z1[1] = {{W_hi + 1024, W_lo + 1024, MiT + DD, MiT + 3*DD, G_f, 1.f, 1.f}};
    launch_gemm(1, false, 2048, 1024, 1024, 2048, 1024, 1024, 1, 1, z1, stream);
  }
  k_split<<<dim3(8192), b256, 0, stream>>>(G_f, G_hi, G_lo, (size_t)2048 * 1024);

  // ---- Phase B ----
  k_split<<<dim3(32768), b256, 0, stream>>>(x_input, XbHi, XbLo, BD);
  k_split<<<dim3(32768), b256, 0, stream>>>(h_prev, Hb, nullptr, BD);
  {  // encode: h_tilde / x_tilde (bf16 out)
    ZP z[4] = {
      {Hb,   nullptr, MiRe_b, nullptr, HtRe, 1.f, 0.f},
      {Hb,   nullptr, MiIm_b, nullptr, HtIm, 1.f, 0.f},
      {XbHi, nullptr, MiRe_b, nullptr, XtRe, 1.f, 0.f},
      {XbHi, nullptr, MiIm_b, nullptr, XtIm, 1.f, 0.f}};
    launch_gemm(0, true, 8192, 1024, 1024, 1024, 1024, 1024, 1, 4, z, stream);
  }
  // delta = x @ G^T: split only for dt_n-large cols ([0,512) and [1024,1536))
  {  // split half
    ZP z[2] = {
      {XbHi, XbLo, G_hi,                     G_lo,                     delta,        1.f, 0.f},
      {XbHi, XbLo, G_hi + 1024 * (size_t)Dd, G_lo + 1024 * (size_t)Dd, delta + 1024, 1.f, 0.f}};
    launch_gemm(1, false, 8192, 512, 1024, 1024, 1024, 2048, 1, 2, z, stream);
  }
  {  // plain half
    ZP z[2] = {
      {XbHi, nullptr, G_hi + 512 * (size_t)Dd,  nullptr, delta + 512,  1.f, 0.f},
      {XbHi, nullptr, G_hi + 1536 * (size_t)Dd, nullptr, delta + 1536, 1.f, 0.f}};
    launch_gemm(0, false, 8192, 512, 1024, 1024, 1024, 2048, 1, 2, z, stream);
  }

  if (realOnly) {
    k_pointwise<<<dim3(32768), b256, 0, stream>>>(HtRe, HtIm, XtRe, XtIm, delta, dt, ld, lf, dts,
                                                  sre, sim, lwre, lwim, sel_b, HnRe, HnIm, -1.0f);
    ZP z1[1] = {{HnRe, HnIm, MRe_b, MIm_b, out, 1.f, 0.f}};
    launch_gemm(2, false, 8192, 1024, 1024, 1024, 1024, 1024, 1, 1, z1, stream);
  } else {
    k_pointwise<<<dim3(32768), b256, 0, stream>>>(HtRe, HtIm, XtRe, XtIm, delta, dt, ld, lf, dts,
                                                  sre, sim, lwre, lwim, sel_b, HnRe, HnIm, 1.0f);
    {
      ZP z[2] = {
        {HnRe, nullptr, MRe_b, nullptr, out,     1.f, 0.f},
        {HnRe, nullptr, MIm_b, nullptr, out + 1, 1.f, 0.f}};
      launch_gemm(0, false, 8192, 1024, 1024, 1024, 1024, 2048, 2, 2, z, stream);
    }
    {
      ZP z[2] = {
        {HnIm, nullptr, MIm_b, nullptr, out,     -1.f, 1.f},
        {HnIm, nullptr, MRe_b, nullptr, out + 1,  1.f, 1.f}};
      launch_gemm(0, false, 8192, 1024, 1024, 1024, 1024, 2048, 2, 2, z, stream);
    }
  }
}

// Round 7
// 919.955 us; speedup vs baseline: 1.1606x; 1.0499x over previous
//
#include <hip/hip_runtime.h>
#include <hip/hip_bf16.h>

#define Dd 1024
#define Bb 8192

typedef unsigned short u16;
typedef __attribute__((ext_vector_type(8))) short short8;
typedef __attribute__((ext_vector_type(4))) float f32x4;
typedef __attribute__((ext_vector_type(4))) float float4v;

static constexpr size_t DD  = (size_t)Dd * Dd;   // 1M
static constexpr size_t BD  = (size_t)Bb * Dd;   // 8M
static constexpr size_t MBy = 1ull << 20;

__device__ __forceinline__ float bf2f(u16 v) {
  union { unsigned u; float f; } c; c.u = ((unsigned)v) << 16; return c.f;
}
__device__ __forceinline__ u16 f2bf(float f) {
  union { float f; unsigned u; } c; c.f = f;
  return (u16)((c.u + 0x7fffu + ((c.u >> 16) & 1u)) >> 16);
}

// ---------------- NT GEMM: C[m][n] = alpha * sum_k A[m][k]*Bt[n][k] (+beta*C) ----------
// MODE 0: 1 MFMA (Ah*Bh) ; MODE 1: 3 MFMA split ; MODE 2: 2 MFMA pair (AhBh+AlBl)
// OUT  0: f32 (+beta) ; 1: bf16 ; 2: bf16 hi/lo pair -> C, C2
// K-loop: 2-phase prefetch (dbuf LDS)  [T3-min] ; T2 swizzle via pre-swizzled global src [rule #21]
struct ZP { const u16* Ah; const u16* Al; const u16* Bh; const u16* Bl; void* C; void* C2; float alpha; float beta; };
struct GArgs { ZP z[8]; int K, lda, ldb; long ldc; int cstride; };

template<int OUT>
__device__ __forceinline__ void c_store(const ZP& p, long cidx, float acc) {
  float v = acc * p.alpha;
  if constexpr (OUT == 1) {
    ((u16*)p.C)[cidx] = f2bf(v);
  } else if constexpr (OUT == 2) {
    u16 h = f2bf(v);
    ((u16*)p.C)[cidx] = h;
    ((u16*)p.C2)[cidx] = f2bf(v - bf2f(h));
  } else {
    float* C = (float*)p.C;
    if (p.beta != 0.0f) v += p.beta * C[cidx];
    C[cidx] = v;
  }
}

template<int MODE, int OUT>
__global__ __launch_bounds__(256) void gemm_nt(GArgs a) {
  constexpr bool X2 = (MODE != 0);
  constexpr int BUFS = X2 ? 32768 : 16384;       // u16 per LDS buffer
  __shared__ __align__(16) u16 smem[2 * BUFS];   // 64 KB / 128 KB
  const ZP p = a.z[blockIdx.z];
  const int tid  = threadIdx.x;
  const int lane = tid & 63, wv = tid >> 6;

  int bx = blockIdx.x, by = blockIdx.y;          // T1 XCD-chunked swizzle
  {
    const int gx = gridDim.x;
    const int nwg = gx * gridDim.y;
    if ((nwg & 7) == 0 && nwg >= 16) {
      const int flat = by * gx + bx;
      const int ch = nwg >> 3;
      const int nf = (flat & 7) * ch + (flat >> 3);
      bx = nf % gx; by = nf / gx;
    }
  }

  const long brow = (long)by * 128, bcol = (long)bx * 128;
  const int wm = (wv & 1) * 64, wn = (wv >> 1) * 64;
  const int srow = wv * 8 + (lane >> 3);
  const int sgc  = ((lane & 7) ^ (lane >> 3)) * 8;   // pre-swizzled global col chunk

  f32x4 acc[4][4];
#pragma unroll
  for (int i = 0; i < 4; ++i)
#pragma unroll
    for (int j = 0; j < 4; ++j) { f32x4 zv = {0.f, 0.f, 0.f, 0.f}; acc[i][j] = zv; }

  auto STAGE = [&](int kt, int buf) {
    u16* As = smem + buf * BUFS;
    u16* Bs = As + 8192;
#pragma unroll
    for (int i = 0; i < 4; ++i) {
      const int rr = i * 32 + srow;
      const int lb = (i * 32 + wv * 8) * 64;
      const u16* ga = p.Ah + (brow + rr) * (long)a.lda + kt + sgc;
      const u16* gb = p.Bh + (bcol + rr) * (long)a.ldb + kt + sgc;
      __builtin_amdgcn_global_load_lds((const __attribute__((address_space(1))) void*)ga,
                                       (__attribute__((address_space(3))) void*)(As + lb), 16, 0, 0);
      __builtin_amdgcn_global_load_lds((const __attribute__((address_space(1))) void*)gb,
                                       (__attribute__((address_space(3))) void*)(Bs + lb), 16, 0, 0);
      if constexpr (X2) {
        const u16* ga2 = p.Al + (brow + rr) * (long)a.lda + kt + sgc;
        const u16* gb2 = p.Bl + (bcol + rr) * (long)a.ldb + kt + sgc;
        __builtin_amdgcn_global_load_lds((const __attribute__((address_space(1))) void*)ga2,
                                         (__attribute__((address_space(3))) void*)(As + 16384 + lb), 16, 0, 0);
        __builtin_amdgcn_global_load_lds((const __attribute__((address_space(1))) void*)gb2,
                                         (__attribute__((address_space(3))) void*)(As + 24576 + lb), 16, 0, 0);
      }
    }
  };

  auto COMPUTE = [&](int buf) {
    u16* As = smem + buf * BUFS;
    u16* Bs = As + 8192;
#pragma unroll
    for (int kk = 0; kk < 64; kk += 32) {
      const int jf = (kk >> 3) + (lane >> 4);
      const int cs = ((jf ^ (lane & 7)) << 3);
      short8 af[4], bfv[4], al[4], bl[4];
#pragma unroll
      for (int i = 0; i < 4; ++i) {
        af[i]  = *(const short8*)(As + (wm + i * 16 + (lane & 15)) * 64 + cs);
        bfv[i] = *(const short8*)(Bs + (wn + i * 16 + (lane & 15)) * 64 + cs);
        if constexpr (X2) {
          al[i] = *(const short8*)(As + 16384 + (wm + i * 16 + (lane & 15)) * 64 + cs);
          bl[i] = *(const short8*)(As + 24576 + (wn + i * 16 + (lane & 15)) * 64 + cs);
        }
      }
#pragma unroll
      for (int i = 0; i < 4; ++i)
#pragma unroll
        for (int j = 0; j < 4; ++j) {
          acc[i][j] = __builtin_amdgcn_mfma_f32_16x16x32_bf16(af[i], bfv[j], acc[i][j], 0, 0, 0);
          if constexpr (MODE == 1) {
            acc[i][j] = __builtin_amdgcn_mfma_f32_16x16x32_bf16(al[i], bfv[j], acc[i][j], 0, 0, 0);
            acc[i][j] = __builtin_amdgcn_mfma_f32_16x16x32_bf16(af[i], bl[j], acc[i][j], 0, 0, 0);
          } else if constexpr (MODE == 2) {
            acc[i][j] = __builtin_amdgcn_mfma_f32_16x16x32_bf16(al[i], bl[j], acc[i][j], 0, 0, 0);
          }
        }
    }
  };

  const int nkt = a.K >> 6;
  STAGE(0, 0);
  __syncthreads();
  int cur = 0;
  for (int t = 0; t < nkt - 1; ++t) {
    STAGE((t + 1) * 64, cur ^ 1);
    COMPUTE(cur);
    __syncthreads();
    cur ^= 1;
  }
  COMPUTE(cur);

  const long crow = brow + wm + ((lane >> 4) * 4);
  const long ccol = bcol + wn + (lane & 15);
#pragma unroll
  for (int i = 0; i < 4; ++i)
#pragma unroll
    for (int j = 0; j < 4; ++j)
#pragma unroll
      for (int r = 0; r < 4; ++r) {
        const long cidx = (crow + i * 16 + r) * a.ldc + (ccol + j * 16) * (long)a.cstride;
        c_store<OUT>(p, cidx, acc[i][j][r]);
      }
}

// ---- 256x256-tile MODE0 GEMM (8 waves / 512 thr): halves L2 bytes per FLOP ----
template<int OUT>
__global__ __launch_bounds__(512, 1) void gemm_nt256(GArgs a) {
  constexpr int BUFS = 32768;                    // u16 per buffer (A 16K + B 16K)
  __shared__ __align__(16) u16 smem[2 * BUFS];   // 128 KB
  const ZP p = a.z[blockIdx.z];
  const int tid  = threadIdx.x;
  const int lane = tid & 63, wv = tid >> 6;      // 8 waves
  const int wr = wv >> 2, wc = wv & 3;           // 2 x 4 wave grid; wave tile 128x64

  int bx = blockIdx.x, by = blockIdx.y;          // T1 swizzle
  {
    const int gx = gridDim.x;
    const int nwg = gx * gridDim.y;
    if ((nwg & 7) == 0 && nwg >= 16) {
      const int flat = by * gx + bx;
      const int ch = nwg >> 3;
      const int nf = (flat & 7) * ch + (flat >> 3);
      bx = nf % gx; by = nf / gx;
    }
  }

  const long brow = (long)by * 256, bcol = (long)bx * 256;
  const int sgc = ((tid & 7) ^ ((tid >> 3) & 7)) * 8;  // pre-swizzled global col chunk

  f32x4 acc[8][4];
#pragma unroll
  for (int i = 0; i < 8; ++i)
#pragma unroll
    for (int j = 0; j < 4; ++j) { f32x4 zv = {0.f, 0.f, 0.f, 0.f}; acc[i][j] = zv; }

  auto STAGE = [&](int kt, int buf) {
    u16* As = smem + buf * BUFS;
    u16* Bs = As + 16384;
#pragma unroll
    for (int i = 0; i < 4; ++i) {
      const int rr = i * 64 + (tid >> 3);
      const int lb = i * 4096 + tid * 8;     // linear dest: wave-uniform base + lane*16B
      const u16* ga = p.Ah + (brow + rr) * (long)a.lda + kt + sgc;
      const u16* gb = p.Bh + (bcol + rr) * (long)a.ldb + kt + sgc;
      __builtin_amdgcn_global_load_lds((const __attribute__((address_space(1))) void*)ga,
                                       (__attribute__((address_space(3))) void*)(As + lb), 16, 0, 0);
      __builtin_amdgcn_global_load_lds((const __attribute__((address_space(1))) void*)gb,
                                       (__attribute__((address_space(3))) void*)(Bs + lb), 16, 0, 0);
    }
  };

  auto COMPUTE = [&](int buf) {
    u16* As = smem + buf * BUFS;
    u16* Bs = As + 16384;
#pragma unroll
    for (int kk = 0; kk < 64; kk += 32) {
      const int jf = (kk >> 3) + (lane >> 4);
      const int cs = ((jf ^ (lane & 7)) << 3);
      short8 af[8], bfv[4];
#pragma unroll
      for (int i = 0; i < 8; ++i)
        af[i] = *(const short8*)(As + (wr * 128 + i * 16 + (lane & 15)) * 64 + cs);
#pragma unroll
      for (int j = 0; j < 4; ++j)
        bfv[j] = *(const short8*)(Bs + (wc * 64 + j * 16 + (lane & 15)) * 64 + cs);
#pragma unroll
      for (int i = 0; i < 8; ++i)
#pragma unroll
        for (int j = 0; j < 4; ++j)
          acc[i][j] = __builtin_amdgcn_mfma_f32_16x16x32_bf16(af[i], bfv[j], acc[i][j], 0, 0, 0);
    }
  };

  const int nkt = a.K >> 6;
  STAGE(0, 0);
  __syncthreads();
  int cur = 0;
  for (int t = 0; t < nkt - 1; ++t) {
    STAGE((t + 1) * 64, cur ^ 1);
    COMPUTE(cur);
    __syncthreads();
    cur ^= 1;
  }
  COMPUTE(cur);

  const long crow = brow + wr * 128 + ((lane >> 4) * 4);
  const long ccol = bcol + wc * 64 + (lane & 15);
#pragma unroll
  for (int i = 0; i < 8; ++i)
#pragma unroll
    for (int j = 0; j < 4; ++j)
#pragma unroll
      for (int r = 0; r < 4; ++r) {
        const long cidx = (crow + i * 16 + r) * a.ldc + (ccol + j * 16) * (long)a.cstride;
        c_store<OUT>(p, cidx, acc[i][j][r]);
      }
}

// ---------------- elementwise kernels ----------------
// complex d x d planes: [y*2*DD] = re, [y*2*DD + DD] = im ; sum planes: [y*DD]

__global__ void k_buildA(const float* ur, const float* ui, const float* vr, const float* vi,
                         float* Af32, u16* Ahi, u16* Alo, u16* AsumH, u16* AsumL) {
  const int y = blockIdx.y;
  const size_t idx = (size_t)blockIdx.x * 256 + threadIdx.x;
  const size_t r = idx >> 10, c = idx & 1023;
  const float* re = y ? vr : ur; const float* im = y ? vi : ui;
  float are = 0.5f * (re[idx] - re[c * Dd + r]);
  float aim = 0.5f * (im[idx] + im[c * Dd + r]);
  size_t pr = (size_t)y * 2 * DD + idx, pi = pr + DD;
  Af32[pr] = are; Af32[pi] = aim;
  u16 h = f2bf(are); Ahi[pr] = h; Alo[pr] = f2bf(are - bf2f(h));
  h = f2bf(aim); Ahi[pi] = h; Alo[pi] = f2bf(aim - bf2f(h));
  float s = are + aim;
  size_t ps = (size_t)y * DD + idx;
  h = f2bf(s); AsumH[ps] = h; AsumL[ps] = f2bf(s - bf2f(h));
}

// X0 = I + A + A^2 ; A^2 from 3 products/y: re = -T0-T1 ; im = T2 - T2^T
__global__ void k_x0(const float* Af32, const float* T, float* Xf32, u16* Xhi, u16* XThi,
                     u16* XsumH, u16* XTsumH) {
  const int y = blockIdx.y;
  const size_t idx = (size_t)blockIdx.x * 256 + threadIdx.x;
  const size_t r = idx >> 10, c = idx & 1023;
  const size_t t0 = (size_t)y * 3 * DD;
  float a2re = -T[t0 + idx] - T[t0 + DD + idx];
  float a2im =  T[t0 + 2 * DD + idx] - T[t0 + 2 * DD + c * Dd + r];
  size_t pr = (size_t)y * 2 * DD + idx, pi = pr + DD;
  float xre = Af32[pr] + a2re + (r == c ? 1.0f : 0.0f);
  float xim = Af32[pi] + a2im;
  Xf32[pr] = xre; Xf32[pi] = xim;
  Xhi[pr] = f2bf(xre); Xhi[pi] = f2bf(xim);
  size_t tr = c * Dd + r;
  size_t qr = (size_t)y * 2 * DD + tr;
  XThi[qr] = f2bf(xre); XThi[qr + DD] = f2bf(xim);
  float s = xre + xim;
  XsumH[(size_t)y * DD + idx] = f2bf(s);
  XTsumH[(size_t)y * DD + tr] = f2bf(s);
}

// Kara combine -> Wt planes. qre = T1-T2, qim = T3-T1-T2 (read transposed).
__global__ void k_wt(const float* Xf32, const float* T, u16* WThi, u16* WTsumH, float idc) {
  const int y = blockIdx.y;
  const size_t idx = (size_t)blockIdx.x * 256 + threadIdx.x;  // write: n*Dd + k
  const size_t n = idx >> 10, k = idx & 1023;
  const size_t ridx = k * Dd + n;
  const size_t t0 = (size_t)y * 3 * DD;
  float t1 = T[t0 + ridx], t2 = T[t0 + DD + ridx], t3 = T[t0 + 2 * DD + ridx];
  size_t pr = (size_t)y * 2 * DD, pi = pr + DD;
  float wre = (n == k ? idc : 0.0f) - Xf32[pr + ridx] + (t1 - t2);
  float wim = -Xf32[pi + ridx] + (t3 - t1 - t2);
  WThi[pr + idx] = f2bf(wre);
  WThi[pi + idx] = f2bf(wim);
  WTsumH[(size_t)y * DD + idx] = f2bf(wre + wim);
}

// X' from Kara planes: re = T1-T2, im = T3-T1-T2
__global__ void k_xn(const float* T, float* Xf32, u16* Xhi, u16* XThi, u16* XsumH, u16* XTsumH,
                     u16* Xlo, u16* XTlo, u16* XTsumL) {
  const int y = blockIdx.y;
  const size_t idx = (size_t)blockIdx.x * 256 + threadIdx.x;
  const size_t r = idx >> 10, c = idx & 1023;
  const size_t t0 = (size_t)y * 3 * DD;
  float t1 = T[t0 + idx], t2 = T[t0 + DD + idx], t3 = T[t0 + 2 * DD + idx];
  float xre = t1 - t2;
  float xim = t3 - t1 - t2;
  size_t pr = (size_t)y * 2 * DD + idx, pi = pr + DD;
  Xf32[pr] = xre; Xf32[pi] = xim;
  u16 hr = f2bf(xre), hi_ = f2bf(xim);
  Xhi[pr] = hr; Xhi[pi] = hi_;
  size_t tr = c * Dd + r;
  size_t qr = (size_t)y * 2 * DD + tr;
  XThi[qr] = hr; XThi[qr + DD] = hi_;
  float s = xre + xim;
  u16 hs = f2bf(s);
  XsumH[(size_t)y * DD + idx] = hs;
  XTsumH[(size_t)y * DD + tr] = hs;
  if (Xlo) {
    u16 lr = f2bf(xre - bf2f(hr)), li = f2bf(xim - bf2f(hi_));
    Xlo[pr] = lr; Xlo[pi] = li;
    XTlo[qr] = lr; XTlo[qr + DD] = li;
    XTsumL[(size_t)y * DD + tr] = f2bf(s - bf2f(hs));
  }
}

// X_r = X + X@R ; Cay = 2*X_r - I ; emit GEMM operands
__global__ void k_finalUV(const float* Xf32, const float* T, const float* logsig,
                          u16* VsHi, u16* VsLo, u16* UHi, u16* ULo, u16* UsHi, u16* VHi,
                          u16* UdifH, u16* UdifL, u16* UssumH, u16* VssumH, u16* VssumL, u16* VdifH) {
  const int y = blockIdx.y;
  const size_t idx = (size_t)blockIdx.x * 256 + threadIdx.x;
  const size_t r = idx >> 10, c = idx & 1023;
  const size_t t0 = (size_t)y * 3 * DD;
  float t1 = T[t0 + idx], t2 = T[t0 + DD + idx], t3 = T[t0 + 2 * DD + idx];
  const size_t pr = (size_t)y * 2 * DD + idx, pi = pr + DD;
  float cre = 2.0f * (Xf32[pr] + (t1 - t2)) - (r == c ? 1.0f : 0.0f);
  float cim = 2.0f * (Xf32[pi] + (t3 - t1 - t2));
  if (y == 0) {
    u16 h = f2bf(cre); UHi[idx] = h; ULo[idx] = f2bf(cre - bf2f(h));
    h = f2bf(cim); UHi[DD + idx] = h; ULo[DD + idx] = f2bf(cim - bf2f(h));
    float d = cre - cim; h = f2bf(d); UdifH[idx] = h; UdifL[idx] = f2bf(d - bf2f(h));
    float s = expf(logsig[c]);
    UsHi[idx] = f2bf(cre * s); UsHi[DD + idx] = f2bf(cim * s);
    UssumH[idx] = f2bf((cre + cim) * s);
  } else {
    VHi[idx] = f2bf(cre); VHi[DD + idx] = f2bf(cim);
    VdifH[idx] = f2bf(cre - cim);
    float si = expf(-logsig[c]);
    float a = cre * si, b = cim * si;
    u16 h = f2bf(a); VsHi[idx] = h; VsLo[idx] = f2bf(a - bf2f(h));
    h = f2bf(b); VsHi[DD + idx] = h; VsLo[DD + idx] = f2bf(b - bf2f(h));
    float ss = (cre + cim) * si; h = f2bf(ss); VssumH[idx] = h; VssumL[idx] = f2bf(ss - bf2f(h));
  }
}

// Minv: re=T0+T1, im=T2-T0+T1 ; M: re=T3+T4, im=T5-T3+T4 (conj-Kara).
// Emits MiRe/MiIm/MRe/MIm bf16 + concatenated-K Bt for G: MiTc[n=c][c'] with
// c'<1024 -> MiRe^T, c'>=1024 -> MiIm^T (hi and lo buffers).
__global__ void k_cmb_M(const float* T, u16* MiRe, u16* MiIm, u16* MiTcH, u16* MiTcL,
                        u16* MRe, u16* MIm) {
  const size_t idx = (size_t)blockIdx.x * 256 + threadIdx.x;
  const size_t r = idx >> 10, c = idx & 1023;
  float g1 = T[idx], g2 = T[DD + idx], g3 = T[2 * DD + idx];
  float mire = g1 + g2;
  float miim = g3 - g1 + g2;
  float h1 = T[3 * DD + idx], h2 = T[4 * DD + idx], h3 = T[5 * DD + idx];
  float mre = h1 + h2;
  float mim = h3 - h1 + h2;
  MiRe[idx] = f2bf(mire); MiIm[idx] = f2bf(miim);
  MRe[idx]  = f2bf(mre);  MIm[idx]  = f2bf(mim);
  size_t o = c * 2048 + r;
  u16 h = f2bf(mire); MiTcH[o] = h;         MiTcL[o] = f2bf(mire - bf2f(h));
  h = f2bf(miim);     MiTcH[o + 1024] = h;  MiTcL[o + 1024] = f2bf(miim - bf2f(h));
}

__global__ void k_split(const float* src, u16* hi, u16* lo, size_t n) {
  const size_t idx = (size_t)blockIdx.x * 256 + threadIdx.x;
  if (idx >= n) return;
  float v = src[idx]; u16 h = f2bf(v); hi[idx] = h;
  if (lo) lo[idx] = f2bf(v - bf2f(h));
}

// fused split of x_input (hi/lo) + h_prev (hi), vectorized x4
__global__ void k_splitB(const float* x, const float* hsrc, u16* xh, u16* xl, u16* hb) {
  const size_t i4 = (size_t)blockIdx.x * 256 + threadIdx.x;  // < BD/4
  float4v xv = ((const float4v*)x)[i4];
  float4v hv = ((const float4v*)hsrc)[i4];
  union { u16 u[4]; unsigned long long v; } oh, ol, ob;
#pragma unroll
  for (int j = 0; j < 4; ++j) {
    u16 h = f2bf(xv[j]);
    oh.u[j] = h;
    ol.u[j] = f2bf(xv[j] - bf2f(h));
    ob.u[j] = f2bf(hv[j]);
  }
  ((unsigned long long*)xh)[i4] = oh.v;
  ((unsigned long long*)xl)[i4] = ol.v;
  ((unsigned long long*)hb)[i4] = ob.v;
}

__global__ void k_pointwise(const u16* HtRe, const u16* HtIm, const u16* XtRe, const u16* XtIm,
                            const float* delta, const float* dt, const float* ld, const float* lf,
                            const float* dts, const float* sre, const float* sim,
                            const float* lwre, const float* lwim, const float* selb,
                            u16* HnRe, u16* HnIm, float imSign) {
  const size_t idx = (size_t)blockIdx.x * 256 + threadIdx.x;  // < BD
  const int b = (int)(idx >> 10); const int c = (int)(idx & 1023);
  float dre = delta[(size_t)b * 2048 + c] + selb[c];
  float dim = delta[(size_t)b * 2048 + 1024 + c] + selb[1024 + c];
  float lamre = -expf(ld[c]) + lwre[c] + dre;
  float lamim = lf[c] + lwim[c] + dim;
  float dtv = dt[b];
  float dtn = dtv / dts[c];
  float zre = lamre * dtn, zim = lamim * dtn;
  float r2 = zre * zre + zim * zim;
  float er = expf(zre); float sn, cs; __sincosf(zim, &sn, &cs);
  float dcre = er * cs, dcim = er * sn;
  float p1re, p1im;
  if (r2 < 1e-8f) {
    p1re = 1.0f + 0.5f * zre + (zre * zre - zim * zim) * (1.0f / 6.0f);
    p1im = 0.5f * zim + (zre * zim) * (1.0f / 3.0f);
  } else {
    float inv = 1.0f / r2;
    float nre = dcre - 1.0f, nim = dcim;
    p1re = (nre * zre + nim * zim) * inv;
    p1im = (nim * zre - nre * zim) * inv;
  }
  float fre = p1re * dtv, fim = p1im * dtv;
  float hre = bf2f(HtRe[idx]), him = bf2f(HtIm[idx]);
  float xre = bf2f(XtRe[idx]) + sre[c], xim = bf2f(XtIm[idx]) + sim[c];
  float ore = hre * dcre - him * dcim + xre * fre - xim * fim;
  float oim = hre * dcim + him * dcre + xre * fim + xim * fre;
  HnRe[idx] = f2bf(ore); HnIm[idx] = f2bf(imSign * oim);
}

__global__ void k_fill(float* p, size_t n, float v) {
  const size_t idx = (size_t)blockIdx.x * 256 + threadIdx.x;
  if (idx < n) p[idx] = v;
}

// ---------------- host ----------------
static void launch_gemm(int mode, int out, int M, int N, int K, int lda, int ldb,
                        long ldc, int cstride, int nz, const ZP* z, hipStream_t s) {
  GArgs a; a.K = K; a.lda = lda; a.ldb = ldb; a.ldc = ldc; a.cstride = cstride;
  for (int i = 0; i < 8; ++i) a.z[i] = z[i < nz ? i : 0];
  dim3 g(N / 128, M / 128, nz), blk(256);
  if (mode == 1 && out == 0)      gemm_nt<1, 0><<<g, blk, 0, s>>>(a);
  else if (mode == 1 && out == 2) gemm_nt<1, 2><<<g, blk, 0, s>>>(a);
  else if (mode == 2)             gemm_nt<2, 0><<<g, blk, 0, s>>>(a);
  else if (out == 1)              gemm_nt<0, 1><<<g, blk, 0, s>>>(a);
  else                            gemm_nt<0, 0><<<g, blk, 0, s>>>(a);
}

static void launch_gemm256(int out, int M, int N, int K, int lda, int ldb,
                           long ldc, int cstride, int nz, const ZP* z, hipStream_t s) {
  GArgs a; a.K = K; a.lda = lda; a.ldb = ldb; a.ldc = ldc; a.cstride = cstride;
  for (int i = 0; i < 8; ++i) a.z[i] = z[i < nz ? i : 0];
  dim3 g(N / 256, M / 256, nz), blk(512);
  if (out == 1) gemm_nt256<1><<<g, blk, 0, s>>>(a);
  else          gemm_nt256<0><<<g, blk, 0, s>>>(a);
}

extern "C" void kernel_launch(void* const* d_in, const int* in_sizes, int n_in,
                              void* d_out, int out_size, void* d_ws, size_t ws_size,
                              hipStream_t stream) {
  const float* h_prev  = (const float*)d_in[0];
  const float* x_input = (const float*)d_in[1];
  const float* dt      = (const float*)d_in[2];
  const float* ur      = (const float*)d_in[3];
  const float* ui      = (const float*)d_in[4];
  const float* vr      = (const float*)d_in[5];
  const float* vi      = (const float*)d_in[6];
  const float* logsig  = (const float*)d_in[7];
  const float* ld      = (const float*)d_in[8];
  const float* lf      = (const float*)d_in[9];
  const float* dts     = (const float*)d_in[10];
  const float* sre     = (const float*)d_in[11];
  const float* sim     = (const float*)d_in[12];
  const float* lwre    = (const float*)d_in[13];
  const float* lwim    = (const float*)d_in[14];
  const float* sel_w   = (const float*)d_in[15];
  const float* sel_b   = (const float*)d_in[16];
  float* out = (float*)d_out;
  char* ws = (char*)d_ws;

  const bool realOnly = ((size_t)out_size == BD);
  const bool interleaved = ((size_t)out_size == 2 * BD);
  if ((!realOnly && !interleaved) || ws_size < 224 * MBy) {
    k_fill<<<dim3(((size_t)out_size + 255) / 256), dim3(256), 0, stream>>>(out, (size_t)out_size, 1e9f);
    return;
  }

  // persistent region [0,16MB)
  u16* MiRe_b = (u16*)(ws + 0 * MBy);
  u16* MiIm_b = (u16*)(ws + 2 * MBy);
  u16* MRe_b  = (u16*)(ws + 4 * MBy);
  u16* MIm_b  = (u16*)(ws + 6 * MBy);
  u16* G_hi   = (u16*)(ws + 8 * MBy);
  u16* G_lo   = (u16*)(ws + 12 * MBy);
  char* AR = ws + 16 * MBy;  // arena
  // phase A
  float* Af32   = (float*)(AR + 0);        // 16 MB
  u16* Ahi      = (u16*)(AR + 16 * MBy);   // 8
  u16* Alo      = (u16*)(AR + 24 * MBy);   // 8
  u16* AsumH    = (u16*)(AR + 32 * MBy);   // 4
  u16* AsumL    = (u16*)(AR + 36 * MBy);   // 4
  float* Xf32   = (float*)(AR + 40 * MBy); // 16
  u16* Xhi      = (u16*)(AR + 56 * MBy);   // 8
  u16* Xlo      = (u16*)(AR + 64 * MBy);   // 8
  u16* XThi     = (u16*)(AR + 72 * MBy);   // 8
  u16* XTlo     = (u16*)(AR + 80 * MBy);   // 8
  u16* XsumH    = (u16*)(AR + 88 * MBy);   // 4
  u16* XTsumH   = (u16*)(AR + 92 * MBy);   // 4
  u16* XTsumL   = (u16*)(AR + 96 * MBy);   // 4
  u16* WThi     = (u16*)(AR + 100 * MBy);  // 8
  u16* WTsumH   = (u16*)(AR + 108 * MBy);  // 4
  float* T      = (float*)(AR + 112 * MBy);// 24 (6 f32 planes)
  u16* VsHi     = (u16*)(AR + 136 * MBy);  // 4
  u16* VsLo     = (u16*)(AR + 140 * MBy);  // 4
  u16* UHi      = (u16*)(AR + 144 * MBy);  // 4
  u16* ULo      = (u16*)(AR + 148 * MBy);  // 4
  u16* UsHi     = (u16*)(AR + 152 * MBy);  // 4
  u16* VHi      = (u16*)(AR + 156 * MBy);  // 4
  u16* UdifH    = (u16*)(AR + 160 * MBy);  // 2
  u16* UdifL    = (u16*)(AR + 162 * MBy);  // 2
  u16* UssumH   = (u16*)(AR + 164 * MBy);  // 2
  u16* VssumH   = (u16*)(AR + 166 * MBy);  // 2
  u16* VssumL   = (u16*)(AR + 168 * MBy);  // 2
  u16* VdifH    = (u16*)(AR + 170 * MBy);  // 2
  u16* MiTcH    = (u16*)(AR + 172 * MBy);  // 4 (1024 x 2048 cat-K Bt, hi)
  u16* MiTcL    = (u16*)(AR + 176 * MBy);  // 4
  u16* W_hi     = (u16*)(AR + 180 * MBy);  // 8
  u16* W_lo     = (u16*)(AR + 188 * MBy);  // 8
  // phase B (reuses arena)
  u16* Hb     = (u16*)(AR + 0);
  u16* XbHi   = (u16*)(AR + 16 * MBy);
  u16* XbLo   = (u16*)(AR + 32 * MBy);
  u16* HtRe   = (u16*)(AR + 48 * MBy);
  u16* HtIm   = (u16*)(AR + 64 * MBy);
  u16* XtRe   = (u16*)(AR + 80 * MBy);
  u16* XtIm   = (u16*)(AR + 96 * MBy);
  float* delta= (float*)(AR + 112 * MBy);
  u16* HnRe   = (u16*)(AR + 176 * MBy);
  u16* HnIm   = (u16*)(AR + 192 * MBy);

  dim3 b256(256);
  const dim3 gdd(4096, 2);

  // ---- Phase A: Cayley(U), Cayley(V) via Newton + Karatsuba ----
  k_buildA<<<gdd, b256, 0, stream>>>(ur, ui, vr, vi, Af32, Ahi, Alo, AsumH, AsumL);

  {  // A^2: 3 products per y
    ZP z[6];
    for (int y = 0; y < 2; ++y) {
      const u16* are = Ahi + (size_t)y * 2 * DD; const u16* aim = are + DD;
      float* t = T + (size_t)y * 3 * DD;
      z[y*3+0] = {are, nullptr, are, nullptr, t,          nullptr, 1.f, 0.f};
      z[y*3+1] = {aim, nullptr, aim, nullptr, t + DD,     nullptr, 1.f, 0.f};
      z[y*3+2] = {are, nullptr, aim, nullptr, t + 2*DD,   nullptr, 1.f, 0.f};
    }
    launch_gemm(0, 0, 1024, 1024, 1024, 1024, 1024, 1024, 1, 6, z, stream);
  }
  k_x0<<<gdd, b256, 0, stream>>>(Af32, T, Xf32, Xhi, XThi, XsumH, XTsumH);

  for (int it = 0; it < 2; ++it) {  // bf16 Newton iterations (Kara)
    {  // Q = A@X
      ZP z[6];
      for (int y = 0; y < 2; ++y) {
        const u16* are = Ahi + (size_t)y*2*DD; const u16* aim = are + DD;
        const u16* xtr = XThi + (size_t)y*2*DD; const u16* xti = xtr + DD;
        float* t = T + (size_t)y*3*DD;
        z[y*3+0] = {are, nullptr, xtr, nullptr, t,        nullptr, 1.f, 0.f};
        z[y*3+1] = {aim, nullptr, xti, nullptr, t + DD,   nullptr, 1.f, 0.f};
        z[y*3+2] = {AsumH + (size_t)y*DD, nullptr, XTsumH + (size_t)y*DD, nullptr, t + 2*DD, nullptr, 1.f, 0.f};
      }
      launch_gemm(0, 0, 1024, 1024, 1024, 1024, 1024, 1024, 1, 6, z, stream);
    }
    k_wt<<<gdd, b256, 0, stream>>>(Xf32, T, WThi, WTsumH, 2.0f);
    {  // X' = X@W
      ZP z[6];
      for (int y = 0; y < 2; ++y) {
        const u16* xre = Xhi + (size_t)y*2*DD; const u16* xim = xre + DD;
        const u16* wtr = WThi + (size_t)y*2*DD; const u16* wti = wtr + DD;
        float* t = T + (size_t)y*3*DD;
        z[y*3+0] = {xre, nullptr, wtr, nullptr, t,        nullptr, 1.f, 0.f};
        z[y*3+1] = {xim, nullptr, wti, nullptr, t + DD,   nullptr, 1.f, 0.f};
        z[y*3+2] = {XsumH + (size_t)y*DD, nullptr, WTsumH + (size_t)y*DD, nullptr, t + 2*DD, nullptr, 1.f, 0.f};
      }
      launch_gemm(0, 0, 1024, 1024, 1024, 1024, 1024, 1024, 1, 6, z, stream);
    }
    const bool last = (it == 1);
    k_xn<<<gdd, b256, 0, stream>>>(T, Xf32, Xhi, XThi, XsumH, XTsumH,
                                   last ? Xlo : nullptr, last ? XTlo : nullptr,
                                   last ? XTsumL : nullptr);
  }

  {  // refine: Q = A@X split precision (Kara)
    ZP z[6];
    for (int y = 0; y < 2; ++y) {
      const u16* areh = Ahi + (size_t)y*2*DD; const u16* aimh = areh + DD;
      const u16* arel = Alo + (size_t)y*2*DD; const u16* aiml = arel + DD;
      const u16* xtrh = XThi + (size_t)y*2*DD; const u16* xtih = xtrh + DD;
      const u16* xtrl = XTlo + (size_t)y*2*DD; const u16* xtil = xtrl + DD;
      float* t = T + (size_t)y*3*DD;
      z[y*3+0] = {areh, arel, xtrh, xtrl, t,        nullptr, 1.f, 0.f};
      z[y*3+1] = {aimh, aiml, xtih, xtil, t + DD,   nullptr, 1.f, 0.f};
      z[y*3+2] = {AsumH + (size_t)y*DD, AsumL + (size_t)y*DD,
                  XTsumH + (size_t)y*DD, XTsumL + (size_t)y*DD, t + 2*DD, nullptr, 1.f, 0.f};
    }
    launch_gemm(1, 0, 1024, 1024, 1024, 1024, 1024, 1024, 1, 6, z, stream);
  }
  k_wt<<<gdd, b256, 0, stream>>>(Xf32, T, WThi, WTsumH, 1.0f);
  {  // XR = X@R (plain, Kara)
    ZP z[6];
    for (int y = 0; y < 2; ++y) {
      const u16* xre = Xhi + (size_t)y*2*DD; const u16* xim = xre + DD;
      const u16* rtr = WThi + (size_t)y*2*DD; const u16* rti = rtr + DD;
      float* t = T + (size_t)y*3*DD;
      z[y*3+0] = {xre, nullptr, rtr, nullptr, t,        nullptr, 1.f, 0.f};
      z[y*3+1] = {xim, nullptr, rti, nullptr, t + DD,   nullptr, 1.f, 0.f};
      z[y*3+2] = {XsumH + (size_t)y*DD, nullptr, WTsumH + (size_t)y*DD, nullptr, t + 2*DD, nullptr, 1.f, 0.f};
    }
    launch_gemm(0, 0, 1024, 1024, 1024, 1024, 1024, 1024, 1, 6, z, stream);
  }
  k_finalUV<<<gdd, b256, 0, stream>>>(Xf32, T, logsig, VsHi, VsLo, UHi, ULo, UsHi, VHi,
                                      UdifH, UdifL, UssumH, VssumH, VssumL, VdifH);

  {  // Minv = (V s_inv) @ U^H : conj-Kara, split
    ZP z[3] = {
      {VsHi,      VsLo,      UHi,      ULo,      T,        nullptr, 1.f, 0.f},
      {VsHi + DD, VsLo + DD, UHi + DD, ULo + DD, T + DD,   nullptr, 1.f, 0.f},
      {VssumH,    VssumL,    UdifH,    UdifL,    T + 2*DD, nullptr, 1.f, 0.f}};
    launch_gemm(1, 0, 1024, 1024, 1024, 1024, 1024, 1024, 1, 3, z, stream);
  }
  {  // M = (U s) @ V^H : conj-Kara, plain
    ZP z[3] = {
      {UsHi,      nullptr, VHi,      nullptr, T + 3*DD, nullptr, 1.f, 0.f},
      {UsHi + DD, nullptr, VHi + DD, nullptr, T + 4*DD, nullptr, 1.f, 0.f},
      {UssumH,    nullptr, VdifH,    nullptr, T + 5*DD, nullptr, 1.f, 0.f}};
    launch_gemm(0, 0, 1024, 1024, 1024, 1024, 1024, 1024, 1, 3, z, stream);
  }
  k_cmb_M<<<dim3(4096), b256, 0, stream>>>(T, MiRe_b, MiIm_b, MiTcH, MiTcL, MRe_b, MIm_b);

  // G = [W1|W2] @ [MiRe^T | MiIm^T]  (single K=2048 split GEMM, split-pair output)
  k_split<<<dim3(16384), b256, 0, stream>>>(sel_w, W_hi, W_lo, (size_t)2048 * 2048);
  {
    ZP z1[1] = {{W_hi, W_lo, MiTcH, MiTcL, G_hi, G_lo, 1.f, 0.f}};
    launch_gemm(1, 2, 2048, 1024, 2048, 2048, 2048, 1024, 1, 1, z1, stream);
  }

  // ---- Phase B ----
  k_splitB<<<dim3(8192), b256, 0, stream>>>(x_input, h_prev, XbHi, XbLo, Hb);
  {  // encode: h_tilde / x_tilde (bf16 out) — 256^2 tile
    ZP z[4] = {
      {Hb,   nullptr, MiRe_b, nullptr, HtRe, nullptr, 1.f, 0.f},
      {Hb,   nullptr, MiIm_b, nullptr, HtIm, nullptr, 1.f, 0.f},
      {XbHi, nullptr, MiRe_b, nullptr, XtRe, nullptr, 1.f, 0.f},
      {XbHi, nullptr, MiIm_b, nullptr, XtIm, nullptr, 1.f, 0.f}};
    launch_gemm256(1, 8192, 1024, 1024, 1024, 1024, 1024, 1, 4, z, stream);
  }
  // delta = x @ G^T: split only for dt_n-large cols ([0,512) and [1024,1536))
  {  // split half
    ZP z[2] = {
      {XbHi, XbLo, G_hi,                     G_lo,                     delta,        nullptr, 1.f, 0.f},
      {XbHi, XbLo, G_hi + 1024 * (size_t)Dd, G_lo + 1024 * (size_t)Dd, delta + 1024, nullptr, 1.f, 0.f}};
    launch_gemm(1, 0, 8192, 512, 1024, 1024, 1024, 2048, 1, 2, z, stream);
  }
  {  // plain half
    ZP z[2] = {
      {XbHi, nullptr, G_hi + 512 * (size_t)Dd,  nullptr, delta + 512,  nullptr, 1.f, 0.f},
      {XbHi, nullptr, G_hi + 1536 * (size_t)Dd, nullptr, delta + 1536, nullptr, 1.f, 0.f}};
    launch_gemm(0, 0, 8192, 512, 1024, 1024, 1024, 2048, 1, 2, z, stream);
  }

  if (realOnly) {
    k_pointwise<<<dim3(32768), b256, 0, stream>>>(HtRe, HtIm, XtRe, XtIm, delta, dt, ld, lf, dts,
                                                  sre, sim, lwre, lwim, sel_b, HnRe, HnIm, -1.0f);
    ZP z1[1] = {{HnRe, HnIm, MRe_b, MIm_b, out, nullptr, 1.f, 0.f}};
    launch_gemm(2, 0, 8192, 1024, 1024, 1024, 1024, 1024, 1, 1, z1, stream);
  } else {
    k_pointwise<<<dim3(32768), b256, 0, stream>>>(HtRe, HtIm, XtRe, XtIm, delta, dt, ld, lf, dts,
                                                  sre, sim, lwre, lwim, sel_b, HnRe, HnIm, 1.0f);
    {
      ZP z[2] = {
        {HnRe, nullptr, MRe_b, nullptr, out,     nullptr, 1.f, 0.f},
        {HnRe, nullptr, MIm_b, nullptr, out + 1, nullptr, 1.f, 0.f}};
      launch_gemm(0, 0, 8192, 1024, 1024, 1024, 1024, 2048, 2, 2, z, stream);
    }
    {
      ZP z[2] = {
        {HnIm, nullptr, MIm_b, nullptr, out,     nullptr, -1.f, 1.f},
        {HnIm, nullptr, MRe_b, nullptr, out + 1, nullptr,  1.f, 1.f}};
      launch_gemm(0, 0, 8192, 1024, 1024, 1024, 1024, 2048, 2, 2, z, stream);
    }
  }
}

// Round 8
// 690.657 us; speedup vs baseline: 1.5459x; 1.3320x over previous
//
#include <hip/hip_runtime.h>
#include <hip/hip_bf16.h>

#define Dd 1024
#define Bb 8192

typedef unsigned short u16;
typedef __attribute__((ext_vector_type(8))) short short8;
typedef __attribute__((ext_vector_type(4))) float f32x4;
typedef __attribute__((ext_vector_type(4))) float float4v;

static constexpr size_t DD  = (size_t)Dd * Dd;   // 1M
static constexpr size_t BD  = (size_t)Bb * Dd;   // 8M
static constexpr size_t MBy = 1ull << 20;

__device__ __forceinline__ float bf2f(u16 v) {
  union { unsigned u; float f; } c; c.u = ((unsigned)v) << 16; return c.f;
}
__device__ __forceinline__ u16 f2bf(float f) {
  union { float f; unsigned u; } c; c.f = f;
  return (u16)((c.u + 0x7fffu + ((c.u >> 16) & 1u)) >> 16);
}

union U64 { u16 u[4]; unsigned long long v; };

// ---------------- NT GEMM: C[m][n] = alpha * sum_k A[m][k]*Bt[n][k] (+beta*C) ----------
// MODE 0: 1 MFMA (Ah*Bh) ; MODE 1: 3 MFMA split ; MODE 2: 2 MFMA pair (AhBh+AlBl)
// OUT  0: f32 (+beta) ; 1: bf16 ; 2: bf16 hi/lo pair -> C, C2
struct ZP { const u16* Ah; const u16* Al; const u16* Bh; const u16* Bl; void* C; void* C2; float alpha; float beta; };
struct GArgs { ZP z[8]; int K, lda, ldb; long ldc; int cstride; };

template<int OUT>
__device__ __forceinline__ void c_store(const ZP& p, long cidx, float acc) {
  float v = acc * p.alpha;
  if constexpr (OUT == 1) {
    ((u16*)p.C)[cidx] = f2bf(v);
  } else if constexpr (OUT == 2) {
    u16 h = f2bf(v);
    ((u16*)p.C)[cidx] = h;
    ((u16*)p.C2)[cidx] = f2bf(v - bf2f(h));
  } else {
    float* C = (float*)p.C;
    if (p.beta != 0.0f) v += p.beta * C[cidx];
    C[cidx] = v;
  }
}

template<int MODE, int OUT>
__global__ __launch_bounds__(256) void gemm_nt(GArgs a) {
  constexpr bool X2 = (MODE != 0);
  constexpr int BUFS = X2 ? 32768 : 16384;
  __shared__ __align__(16) u16 smem[2 * BUFS];
  const ZP p = a.z[blockIdx.z];
  const int tid  = threadIdx.x;
  const int lane = tid & 63, wv = tid >> 6;

  int bx = blockIdx.x, by = blockIdx.y;          // T1 XCD-chunked swizzle
  {
    const int gx = gridDim.x;
    const int nwg = gx * gridDim.y;
    if ((nwg & 7) == 0 && nwg >= 16) {
      const int flat = by * gx + bx;
      const int ch = nwg >> 3;
      const int nf = (flat & 7) * ch + (flat >> 3);
      bx = nf % gx; by = nf / gx;
    }
  }

  const long brow = (long)by * 128, bcol = (long)bx * 128;
  const int wm = (wv & 1) * 64, wn = (wv >> 1) * 64;
  const int srow = wv * 8 + (lane >> 3);
  const int sgc  = ((lane & 7) ^ (lane >> 3)) * 8;   // pre-swizzled global col chunk [T2]

  f32x4 acc[4][4];
#pragma unroll
  for (int i = 0; i < 4; ++i)
#pragma unroll
    for (int j = 0; j < 4; ++j) { f32x4 zv = {0.f, 0.f, 0.f, 0.f}; acc[i][j] = zv; }

  auto STAGE = [&](int kt, int buf) {
    u16* As = smem + buf * BUFS;
    u16* Bs = As + 8192;
#pragma unroll
    for (int i = 0; i < 4; ++i) {
      const int rr = i * 32 + srow;
      const int lb = (i * 32 + wv * 8) * 64;
      const u16* ga = p.Ah + (brow + rr) * (long)a.lda + kt + sgc;
      const u16* gb = p.Bh + (bcol + rr) * (long)a.ldb + kt + sgc;
      __builtin_amdgcn_global_load_lds((const __attribute__((address_space(1))) void*)ga,
                                       (__attribute__((address_space(3))) void*)(As + lb), 16, 0, 0);
      __builtin_amdgcn_global_load_lds((const __attribute__((address_space(1))) void*)gb,
                                       (__attribute__((address_space(3))) void*)(Bs + lb), 16, 0, 0);
      if constexpr (X2) {
        const u16* ga2 = p.Al + (brow + rr) * (long)a.lda + kt + sgc;
        const u16* gb2 = p.Bl + (bcol + rr) * (long)a.ldb + kt + sgc;
        __builtin_amdgcn_global_load_lds((const __attribute__((address_space(1))) void*)ga2,
                                         (__attribute__((address_space(3))) void*)(As + 16384 + lb), 16, 0, 0);
        __builtin_amdgcn_global_load_lds((const __attribute__((address_space(1))) void*)gb2,
                                         (__attribute__((address_space(3))) void*)(As + 24576 + lb), 16, 0, 0);
      }
    }
  };

  auto COMPUTE = [&](int buf) {
    u16* As = smem + buf * BUFS;
    u16* Bs = As + 8192;
#pragma unroll
    for (int kk = 0; kk < 64; kk += 32) {
      const int jf = (kk >> 3) + (lane >> 4);
      const int cs = ((jf ^ (lane & 7)) << 3);
      short8 af[4], bfv[4], al[4], bl[4];
#pragma unroll
      for (int i = 0; i < 4; ++i) {
        af[i]  = *(const short8*)(As + (wm + i * 16 + (lane & 15)) * 64 + cs);
        bfv[i] = *(const short8*)(Bs + (wn + i * 16 + (lane & 15)) * 64 + cs);
        if constexpr (X2) {
          al[i] = *(const short8*)(As + 16384 + (wm + i * 16 + (lane & 15)) * 64 + cs);
          bl[i] = *(const short8*)(As + 24576 + (wn + i * 16 + (lane & 15)) * 64 + cs);
        }
      }
#pragma unroll
      for (int i = 0; i < 4; ++i)
#pragma unroll
        for (int j = 0; j < 4; ++j) {
          acc[i][j] = __builtin_amdgcn_mfma_f32_16x16x32_bf16(af[i], bfv[j], acc[i][j], 0, 0, 0);
          if constexpr (MODE == 1) {
            acc[i][j] = __builtin_amdgcn_mfma_f32_16x16x32_bf16(al[i], bfv[j], acc[i][j], 0, 0, 0);
            acc[i][j] = __builtin_amdgcn_mfma_f32_16x16x32_bf16(af[i], bl[j], acc[i][j], 0, 0, 0);
          } else if constexpr (MODE == 2) {
            acc[i][j] = __builtin_amdgcn_mfma_f32_16x16x32_bf16(al[i], bl[j], acc[i][j], 0, 0, 0);
          }
        }
    }
  };

  const int nkt = a.K >> 6;
  STAGE(0, 0);
  __syncthreads();
  int cur = 0;
  for (int t = 0; t < nkt - 1; ++t) {
    STAGE((t + 1) * 64, cur ^ 1);
    COMPUTE(cur);
    __syncthreads();
    cur ^= 1;
  }
  COMPUTE(cur);

  const long crow = brow + wm + ((lane >> 4) * 4);
  const long ccol = bcol + wn + (lane & 15);
#pragma unroll
  for (int i = 0; i < 4; ++i)
#pragma unroll
    for (int j = 0; j < 4; ++j)
#pragma unroll
      for (int r = 0; r < 4; ++r) {
        const long cidx = (crow + i * 16 + r) * a.ldc + (ccol + j * 16) * (long)a.cstride;
        c_store<OUT>(p, cidx, acc[i][j][r]);
      }
}

// ---- 256x256-tile MODE0 GEMM (8 waves / 512 thr) ----
template<int OUT>
__global__ __launch_bounds__(512, 1) void gemm_nt256(GArgs a) {
  constexpr int BUFS = 32768;
  __shared__ __align__(16) u16 smem[2 * BUFS];
  const ZP p = a.z[blockIdx.z];
  const int tid  = threadIdx.x;
  const int lane = tid & 63, wv = tid >> 6;
  const int wr = wv >> 2, wc = wv & 3;

  int bx = blockIdx.x, by = blockIdx.y;
  {
    const int gx = gridDim.x;
    const int nwg = gx * gridDim.y;
    if ((nwg & 7) == 0 && nwg >= 16) {
      const int flat = by * gx + bx;
      const int ch = nwg >> 3;
      const int nf = (flat & 7) * ch + (flat >> 3);
      bx = nf % gx; by = nf / gx;
    }
  }

  const long brow = (long)by * 256, bcol = (long)bx * 256;
  const int sgc = ((tid & 7) ^ ((tid >> 3) & 7)) * 8;

  f32x4 acc[8][4];
#pragma unroll
  for (int i = 0; i < 8; ++i)
#pragma unroll
    for (int j = 0; j < 4; ++j) { f32x4 zv = {0.f, 0.f, 0.f, 0.f}; acc[i][j] = zv; }

  auto STAGE = [&](int kt, int buf) {
    u16* As = smem + buf * BUFS;
    u16* Bs = As + 16384;
#pragma unroll
    for (int i = 0; i < 4; ++i) {
      const int rr = i * 64 + (tid >> 3);
      const int lb = i * 4096 + tid * 8;
      const u16* ga = p.Ah + (brow + rr) * (long)a.lda + kt + sgc;
      const u16* gb = p.Bh + (bcol + rr) * (long)a.ldb + kt + sgc;
      __builtin_amdgcn_global_load_lds((const __attribute__((address_space(1))) void*)ga,
                                       (__attribute__((address_space(3))) void*)(As + lb), 16, 0, 0);
      __builtin_amdgcn_global_load_lds((const __attribute__((address_space(1))) void*)gb,
                                       (__attribute__((address_space(3))) void*)(Bs + lb), 16, 0, 0);
    }
  };

  auto COMPUTE = [&](int buf) {
    u16* As = smem + buf * BUFS;
    u16* Bs = As + 16384;
#pragma unroll
    for (int kk = 0; kk < 64; kk += 32) {
      const int jf = (kk >> 3) + (lane >> 4);
      const int cs = ((jf ^ (lane & 7)) << 3);
      short8 af[8], bfv[4];
#pragma unroll
      for (int i = 0; i < 8; ++i)
        af[i] = *(const short8*)(As + (wr * 128 + i * 16 + (lane & 15)) * 64 + cs);
#pragma unroll
      for (int j = 0; j < 4; ++j)
        bfv[j] = *(const short8*)(Bs + (wc * 64 + j * 16 + (lane & 15)) * 64 + cs);
#pragma unroll
      for (int i = 0; i < 8; ++i)
#pragma unroll
        for (int j = 0; j < 4; ++j)
          acc[i][j] = __builtin_amdgcn_mfma_f32_16x16x32_bf16(af[i], bfv[j], acc[i][j], 0, 0, 0);
    }
  };

  const int nkt = a.K >> 6;
  STAGE(0, 0);
  __syncthreads();
  int cur = 0;
  for (int t = 0; t < nkt - 1; ++t) {
    STAGE((t + 1) * 64, cur ^ 1);
    COMPUTE(cur);
    __syncthreads();
    cur ^= 1;
  }
  COMPUTE(cur);

  const long crow = brow + wr * 128 + ((lane >> 4) * 4);
  const long ccol = bcol + wc * 64 + (lane & 15);
#pragma unroll
  for (int i = 0; i < 8; ++i)
#pragma unroll
    for (int j = 0; j < 4; ++j)
#pragma unroll
      for (int r = 0; r < 4; ++r) {
        const long cidx = (crow + i * 16 + r) * a.ldc + (ccol + j * 16) * (long)a.cstride;
        c_store<OUT>(p, cidx, acc[i][j][r]);
      }
}

// ---------------- elementwise kernels (64x64 LDS-tile, coalesced) ----------------
// complex d x d planes: [y*2*DD] = re, [y*2*DD + DD] = im ; sum planes: [y*DD]
// Tile: block (bx,by[,z=y]); out rows R0=by*64, cols C0=bx*64; 256 thr; thread
// owns rows ty+i*16 (i=0..3), cols tx*4..+3. lds padded [64][65] (<=2-way, free).

#define TLOAD(ldsbuf, srcp) do { \
  _Pragma("unroll") \
  for (int i_ = 0; i_ < 4; ++i_) { \
    int row_ = ty + i_ * 16; \
    float4v v_ = *(const float4v*)((srcp) + (size_t)row_ * Dd + tx * 4); \
    ldsbuf[row_][tx * 4 + 0] = v_[0]; ldsbuf[row_][tx * 4 + 1] = v_[1]; \
    ldsbuf[row_][tx * 4 + 2] = v_[2]; ldsbuf[row_][tx * 4 + 3] = v_[3]; \
  } } while (0)

// A = 0.5(M - M^T)re + i*0.5(M + M^T)im ; emit Af32, Ahi/Alo, Asum hi/lo
__global__ void k_buildA(const float* ur, const float* ui, const float* vr, const float* vi,
                         float* Af32, u16* Ahi, u16* Alo, u16* AsumH, u16* AsumL) {
  __shared__ float ldsA[64][65], ldsB[64][65];
  const int y = blockIdx.z;
  const int tx = threadIdx.x & 15, ty = threadIdx.x >> 4;
  const int R0 = blockIdx.y * 64, C0 = blockIdx.x * 64;
  const float* re = y ? vr : ur; const float* im = y ? vi : ui;
  TLOAD(ldsA, re + (size_t)C0 * Dd + R0);   // re^T block
  TLOAD(ldsB, im + (size_t)C0 * Dd + R0);   // im^T block
  __syncthreads();
#pragma unroll
  for (int i = 0; i < 4; ++i) {
    const int r = R0 + ty + i * 16;
    const size_t base = (size_t)r * Dd + C0 + tx * 4;
    float4v vre = *(const float4v*)(re + base);
    float4v vim = *(const float4v*)(im + base);
    float4v oar, oai;
    U64 ph, pl, pih, pil, sh, sl;
#pragma unroll
    for (int j = 0; j < 4; ++j) {
      float are = 0.5f * (vre[j] - ldsA[tx * 4 + j][ty + i * 16]);
      float aim = 0.5f * (vim[j] + ldsB[tx * 4 + j][ty + i * 16]);
      oar[j] = are; oai[j] = aim;
      u16 h = f2bf(are); ph.u[j] = h; pl.u[j] = f2bf(are - bf2f(h));
      h = f2bf(aim); pih.u[j] = h; pil.u[j] = f2bf(aim - bf2f(h));
      float s = are + aim; h = f2bf(s); sh.u[j] = h; sl.u[j] = f2bf(s - bf2f(h));
    }
    const size_t pr = (size_t)y * 2 * DD + base, pi = pr + DD;
    *(float4v*)(Af32 + pr) = oar; *(float4v*)(Af32 + pi) = oai;
    *(unsigned long long*)(Ahi + pr) = ph.v; *(unsigned long long*)(Alo + pr) = pl.v;
    *(unsigned long long*)(Ahi + pi) = pih.v; *(unsigned long long*)(Alo + pi) = pil.v;
    const size_t ps = (size_t)y * DD + base;
    *(unsigned long long*)(AsumH + ps) = sh.v; *(unsigned long long*)(AsumL + ps) = sl.v;
  }
}

// X0 = I + A + A^2 ; A^2: re = -T0-T1 ; im = T2 - T2^T ; emit X planes + XT planes
__global__ void k_x0(const float* Af32, const float* T, float* Xf32, u16* Xhi, u16* XThi,
                     u16* XsumH, u16* XTsumH) {
  __shared__ float ldsA[64][65], ldsB[64][65];
  const int y = blockIdx.z;
  const int tx = threadIdx.x & 15, ty = threadIdx.x >> 4;
  const int R0 = blockIdx.y * 64, C0 = blockIdx.x * 64;
  const float* t0p = T + (size_t)y * 3 * DD;
  const float* t1p = t0p + DD;
  const float* t2p = t0p + 2 * DD;
  TLOAD(ldsA, t2p + (size_t)C0 * Dd + R0);  // T2^T block
  __syncthreads();
  float xr[4][4], xi[4][4];
#pragma unroll
  for (int i = 0; i < 4; ++i) {
    const int r = R0 + ty + i * 16;
    const size_t base = (size_t)r * Dd + C0 + tx * 4;
    float4v v0 = *(const float4v*)(t0p + base);
    float4v v1 = *(const float4v*)(t1p + base);
    float4v v2 = *(const float4v*)(t2p + base);
    const size_t pr = (size_t)y * 2 * DD + base, pi = pr + DD;
    float4v ar = *(const float4v*)(Af32 + pr);
    float4v ai = *(const float4v*)(Af32 + pi);
    float4v oxr, oxi;
    U64 ph, pih, sh;
#pragma unroll
    for (int j = 0; j < 4; ++j) {
      const int c = C0 + tx * 4 + j;
      float xre = ar[j] - v0[j] - v1[j] + (r == c ? 1.0f : 0.0f);
      float xim = ai[j] + v2[j] - ldsA[tx * 4 + j][ty + i * 16];
      xr[i][j] = xre; xi[i][j] = xim;
      oxr[j] = xre; oxi[j] = xim;
      ph.u[j] = f2bf(xre); pih.u[j] = f2bf(xim);
      sh.u[j] = f2bf(xre + xim);
    }
    *(float4v*)(Xf32 + pr) = oxr; *(float4v*)(Xf32 + pi) = oxi;
    *(unsigned long long*)(Xhi + pr) = ph.v; *(unsigned long long*)(Xhi + pi) = pih.v;
    *(unsigned long long*)(XsumH + (size_t)y * DD + base) = sh.v;
  }
  __syncthreads();
#pragma unroll
  for (int i = 0; i < 4; ++i)
#pragma unroll
    for (int j = 0; j < 4; ++j) {
      ldsA[ty + i * 16][tx * 4 + j] = xr[i][j];
      ldsB[ty + i * 16][tx * 4 + j] = xi[i][j];
    }
  __syncthreads();
#pragma unroll
  for (int i = 0; i < 4; ++i) {
    const int cc = C0 + ty + i * 16;
    const size_t tb = (size_t)cc * Dd + R0 + tx * 4;
    U64 ph, pih, sh;
#pragma unroll
    for (int j = 0; j < 4; ++j) {
      float xre = ldsA[tx * 4 + j][ty + i * 16];
      float xim = ldsB[tx * 4 + j][ty + i * 16];
      ph.u[j] = f2bf(xre); pih.u[j] = f2bf(xim);
      sh.u[j] = f2bf(xre + xim);
    }
    const size_t qr = (size_t)y * 2 * DD + tb;
    *(unsigned long long*)(XThi + qr) = ph.v;
    *(unsigned long long*)(XThi + qr + DD) = pih.v;
    *(unsigned long long*)(XTsumH + (size_t)y * DD + tb) = sh.v;
  }
}

// Wt[n][k] = (idc*I - X + Q)[k][n] with Q from Kara planes: qre=T1-T2, qim=T3-T1-T2.
// All sources read at (k,n) via transposed LDS tiles (5 planes, sequential).
__global__ void k_wt(const float* Xf32, const float* T, u16* WThi, u16* WTsumH, float idc) {
  __shared__ float lds[64][65];
  const int y = blockIdx.z;
  const int tx = threadIdx.x & 15, ty = threadIdx.x >> 4;
  const int N0 = blockIdx.y * 64, K0 = blockIdx.x * 64;
  const float* t1p = T + (size_t)y * 3 * DD;
  const float* xrp = Xf32 + (size_t)y * 2 * DD;
  float wre[4][4], wim[4][4];
#pragma unroll
  for (int i = 0; i < 4; ++i)
#pragma unroll
    for (int j = 0; j < 4; ++j) {
      wre[i][j] = ((N0 + ty + i * 16) == (K0 + tx * 4 + j)) ? idc : 0.0f;
      wim[i][j] = 0.0f;
    }
  const float* planes[5] = {t1p, t1p + DD, t1p + 2 * DD, xrp, xrp + DD};
#pragma unroll
  for (int p = 0; p < 5; ++p) {
    TLOAD(lds, planes[p] + (size_t)K0 * Dd + N0);
    __syncthreads();
#pragma unroll
    for (int i = 0; i < 4; ++i)
#pragma unroll
      for (int j = 0; j < 4; ++j) {
        float v = lds[tx * 4 + j][ty + i * 16];
        if (p == 0) { wre[i][j] += v; wim[i][j] -= v; }        // +T1 re, -T1 im
        else if (p == 1) { wre[i][j] -= v; wim[i][j] -= v; }   // -T2 re, -T2 im
        else if (p == 2) { wim[i][j] += v; }                   // +T3 im
        else if (p == 3) { wre[i][j] -= v; }                   // -Xre
        else { wim[i][j] -= v; }                               // -Xim
      }
    __syncthreads();
  }
#pragma unroll
  for (int i = 0; i < 4; ++i) {
    const size_t base = (size_t)(N0 + ty + i * 16) * Dd + K0 + tx * 4;
    U64 ph, pih, sh;
#pragma unroll
    for (int j = 0; j < 4; ++j) {
      ph.u[j] = f2bf(wre[i][j]); pih.u[j] = f2bf(wim[i][j]);
      sh.u[j] = f2bf(wre[i][j] + wim[i][j]);
    }
    const size_t pr = (size_t)y * 2 * DD + base;
    *(unsigned long long*)(WThi + pr) = ph.v;
    *(unsigned long long*)(WThi + pr + DD) = pih.v;
    *(unsigned long long*)(WTsumH + (size_t)y * DD + base) = sh.v;
  }
}

// X' from Kara planes: re = T1-T2, im = T3-T1-T2 ; X + XT (+ lo on last iter)
__global__ void k_xn(const float* T, float* Xf32, u16* Xhi, u16* XThi, u16* XsumH, u16* XTsumH,
                     u16* Xlo, u16* XTlo, u16* XTsumL) {
  __shared__ float ldsA[64][65], ldsB[64][65];
  const int y = blockIdx.z;
  const int tx = threadIdx.x & 15, ty = threadIdx.x >> 4;
  const int R0 = blockIdx.y * 64, C0 = blockIdx.x * 64;
  const float* t1p = T + (size_t)y * 3 * DD;
  float xr[4][4], xi[4][4];
#pragma unroll
  for (int i = 0; i < 4; ++i) {
    const size_t base = (size_t)(R0 + ty + i * 16) * Dd + C0 + tx * 4;
    float4v v1 = *(const float4v*)(t1p + base);
    float4v v2 = *(const float4v*)(t1p + DD + base);
    float4v v3 = *(const float4v*)(t1p + 2 * DD + base);
    float4v oxr, oxi;
    U64 ph, pih, sh, plr, pli;
#pragma unroll
    for (int j = 0; j < 4; ++j) {
      float xre = v1[j] - v2[j];
      float xim = v3[j] - v1[j] - v2[j];
      xr[i][j] = xre; xi[i][j] = xim;
      oxr[j] = xre; oxi[j] = xim;
      u16 hr = f2bf(xre), hi_ = f2bf(xim);
      ph.u[j] = hr; pih.u[j] = hi_;
      sh.u[j] = f2bf(xre + xim);
      plr.u[j] = f2bf(xre - bf2f(hr)); pli.u[j] = f2bf(xim - bf2f(hi_));
    }
    const size_t pr = (size_t)y * 2 * DD + base, pi = pr + DD;
    *(float4v*)(Xf32 + pr) = oxr; *(float4v*)(Xf32 + pi) = oxi;
    *(unsigned long long*)(Xhi + pr) = ph.v; *(unsigned long long*)(Xhi + pi) = pih.v;
    *(unsigned long long*)(XsumH + (size_t)y * DD + base) = sh.v;
    if (Xlo) {
      *(unsigned long long*)(Xlo + pr) = plr.v;
      *(unsigned long long*)(Xlo + pi) = pli.v;
    }
  }
  __syncthreads();
#pragma unroll
  for (int i = 0; i < 4; ++i)
#pragma unroll
    for (int j = 0; j < 4; ++j) {
      ldsA[ty + i * 16][tx * 4 + j] = xr[i][j];
      ldsB[ty + i * 16][tx * 4 + j] = xi[i][j];
    }
  __syncthreads();
#pragma unroll
  for (int i = 0; i < 4; ++i) {
    const int cc = C0 + ty + i * 16;
    const size_t tb = (size_t)cc * Dd + R0 + tx * 4;
    U64 ph, pih, sh, plr, pli, sl;
#pragma unroll
    for (int j = 0; j < 4; ++j) {
      float xre = ldsA[tx * 4 + j][ty + i * 16];
      float xim = ldsB[tx * 4 + j][ty + i * 16];
      u16 hr = f2bf(xre), hi_ = f2bf(xim);
      ph.u[j] = hr; pih.u[j] = hi_;
      float s = xre + xim; u16 hs = f2bf(s);
      sh.u[j] = hs;
      plr.u[j] = f2bf(xre - bf2f(hr)); pli.u[j] = f2bf(xim - bf2f(hi_));
      sl.u[j] = f2bf(s - bf2f(hs));
    }
    const size_t qr = (size_t)y * 2 * DD + tb;
    *(unsigned long long*)(XThi + qr) = ph.v;
    *(unsigned long long*)(XThi + qr + DD) = pih.v;
    *(unsigned long long*)(XTsumH + (size_t)y * DD + tb) = sh.v;
    if (Xlo) {
      *(unsigned long long*)(XTlo + qr) = plr.v;
      *(unsigned long long*)(XTlo + qr + DD) = pli.v;
      *(unsigned long long*)(XTsumL + (size_t)y * DD + tb) = sl.v;
    }
  }
}

// X_r = X + X@R ; Cay = 2*X_r - I ; emit GEMM operands (all coalesced, unchanged logic)
__global__ void k_finalUV(const float* Xf32, const float* T, const float* logsig,
                          u16* VsHi, u16* VsLo, u16* UHi, u16* ULo, u16* UsHi, u16* VHi,
                          u16* UdifH, u16* UdifL, u16* UssumH, u16* VssumH, u16* VssumL, u16* VdifH) {
  const int y = blockIdx.y;
  const size_t idx = (size_t)blockIdx.x * 256 + threadIdx.x;
  const size_t r = idx >> 10, c = idx & 1023;
  const size_t t0 = (size_t)y * 3 * DD;
  float t1 = T[t0 + idx], t2 = T[t0 + DD + idx], t3 = T[t0 + 2 * DD + idx];
  const size_t pr = (size_t)y * 2 * DD + idx, pi = pr + DD;
  float cre = 2.0f * (Xf32[pr] + (t1 - t2)) - (r == c ? 1.0f : 0.0f);
  float cim = 2.0f * (Xf32[pi] + (t3 - t1 - t2));
  if (y == 0) {
    u16 h = f2bf(cre); UHi[idx] = h; ULo[idx] = f2bf(cre - bf2f(h));
    h = f2bf(cim); UHi[DD + idx] = h; ULo[DD + idx] = f2bf(cim - bf2f(h));
    float d = cre - cim; h = f2bf(d); UdifH[idx] = h; UdifL[idx] = f2bf(d - bf2f(h));
    float s = expf(logsig[c]);
    UsHi[idx] = f2bf(cre * s); UsHi[DD + idx] = f2bf(cim * s);
    UssumH[idx] = f2bf((cre + cim) * s);
  } else {
    VHi[idx] = f2bf(cre); VHi[DD + idx] = f2bf(cim);
    VdifH[idx] = f2bf(cre - cim);
    float si = expf(-logsig[c]);
    float a = cre * si, b = cim * si;
    u16 h = f2bf(a); VsHi[idx] = h; VsLo[idx] = f2bf(a - bf2f(h));
    h = f2bf(b); VsHi[DD + idx] = h; VsLo[DD + idx] = f2bf(b - bf2f(h));
    float ss = (cre + cim) * si; h = f2bf(ss); VssumH[idx] = h; VssumL[idx] = f2bf(ss - bf2f(h));
  }
}

// Minv: re=T0+T1, im=T2-T0+T1 ; M: re=T3+T4, im=T5-T3+T4 (conj-Kara). Tiled; MiTc
// (cat-K Bt for G) written coalesced via LDS transpose.
__global__ void k_cmb_M(const float* T, u16* MiRe, u16* MiIm, u16* MiTcH, u16* MiTcL,
                        u16* MRe, u16* MIm) {
  __shared__ float ldsA[64][65], ldsB[64][65];
  const int tx = threadIdx.x & 15, ty = threadIdx.x >> 4;
  const int R0 = blockIdx.y * 64, C0 = blockIdx.x * 64;
#pragma unroll
  for (int i = 0; i < 4; ++i) {
    const size_t base = (size_t)(R0 + ty + i * 16) * Dd + C0 + tx * 4;
    float4v g1 = *(const float4v*)(T + base);
    float4v g2 = *(const float4v*)(T + DD + base);
    float4v g3 = *(const float4v*)(T + 2 * DD + base);
    float4v h1 = *(const float4v*)(T + 3 * DD + base);
    float4v h2 = *(const float4v*)(T + 4 * DD + base);
    float4v h3 = *(const float4v*)(T + 5 * DD + base);
    U64 pir, pii, pmr, pmi;
#pragma unroll
    for (int j = 0; j < 4; ++j) {
      float mire = g1[j] + g2[j];
      float miim = g3[j] - g1[j] + g2[j];
      float mre  = h1[j] + h2[j];
      float mim  = h3[j] - h1[j] + h2[j];
      pir.u[j] = f2bf(mire); pii.u[j] = f2bf(miim);
      pmr.u[j] = f2bf(mre);  pmi.u[j] = f2bf(mim);
      ldsA[ty + i * 16][tx * 4 + j] = mire;
      ldsB[ty + i * 16][tx * 4 + j] = miim;
    }
    *(unsigned long long*)(MiRe + base) = pir.v;
    *(unsigned long long*)(MiIm + base) = pii.v;
    *(unsigned long long*)(MRe + base) = pmr.v;
    *(unsigned long long*)(MIm + base) = pmi.v;
  }
  __syncthreads();
#pragma unroll
  for (int i = 0; i < 4; ++i) {
    const int cc = C0 + ty + i * 16;
    const size_t o = (size_t)cc * 2048 + R0 + tx * 4;
    U64 rh, rl, ih, il;
#pragma unroll
    for (int j = 0; j < 4; ++j) {
      float mire = ldsA[tx * 4 + j][ty + i * 16];
      float miim = ldsB[tx * 4 + j][ty + i * 16];
      u16 h = f2bf(mire); rh.u[j] = h; rl.u[j] = f2bf(mire - bf2f(h));
      h = f2bf(miim); ih.u[j] = h; il.u[j] = f2bf(miim - bf2f(h));
    }
    *(unsigned long long*)(MiTcH + o) = rh.v;
    *(unsigned long long*)(MiTcL + o) = rl.v;
    *(unsigned long long*)(MiTcH + o + 1024) = ih.v;
    *(unsigned long long*)(MiTcL + o + 1024) = il.v;
  }
}

__global__ void k_split(const float* src, u16* hi, u16* lo, size_t n) {
  const size_t idx = (size_t)blockIdx.x * 256 + threadIdx.x;
  if (idx >= n) return;
  float v = src[idx]; u16 h = f2bf(v); hi[idx] = h;
  if (lo) lo[idx] = f2bf(v - bf2f(h));
}

// fused split of x_input (hi/lo) + h_prev (hi), vectorized x4
__global__ void k_splitB(const float* x, const float* hsrc, u16* xh, u16* xl, u16* hb) {
  const size_t i4 = (size_t)blockIdx.x * 256 + threadIdx.x;  // < BD/4
  float4v xv = ((const float4v*)x)[i4];
  float4v hv = ((const float4v*)hsrc)[i4];
  U64 oh, ol, ob;
#pragma unroll
  for (int j = 0; j < 4; ++j) {
    u16 h = f2bf(xv[j]);
    oh.u[j] = h;
    ol.u[j] = f2bf(xv[j] - bf2f(h));
    ob.u[j] = f2bf(hv[j]);
  }
  ((unsigned long long*)xh)[i4] = oh.v;
  ((unsigned long long*)xl)[i4] = ol.v;
  ((unsigned long long*)hb)[i4] = ob.v;
}

__global__ void k_pointwise(const u16* HtRe, const u16* HtIm, const u16* XtRe, const u16* XtIm,
                            const float* delta, const float* dt, const float* ld, const float* lf,
                            const float* dts, const float* sre, const float* sim,
                            const float* lwre, const float* lwim, const float* selb,
                            u16* HnRe, u16* HnIm, float imSign) {
  const size_t idx = (size_t)blockIdx.x * 256 + threadIdx.x;  // < BD
  const int b = (int)(idx >> 10); const int c = (int)(idx & 1023);
  float dre = delta[(size_t)b * 2048 + c] + selb[c];
  float dim = delta[(size_t)b * 2048 + 1024 + c] + selb[1024 + c];
  float lamre = -expf(ld[c]) + lwre[c] + dre;
  float lamim = lf[c] + lwim[c] + dim;
  float dtv = dt[b];
  float dtn = dtv / dts[c];
  float zre = lamre * dtn, zim = lamim * dtn;
  float r2 = zre * zre + zim * zim;
  float er = expf(zre); float sn, cs; __sincosf(zim, &sn, &cs);
  float dcre = er * cs, dcim = er * sn;
  float p1re, p1im;
  if (r2 < 1e-8f) {
    p1re = 1.0f + 0.5f * zre + (zre * zre - zim * zim) * (1.0f / 6.0f);
    p1im = 0.5f * zim + (zre * zim) * (1.0f / 3.0f);
  } else {
    float inv = 1.0f / r2;
    float nre = dcre - 1.0f, nim = dcim;
    p1re = (nre * zre + nim * zim) * inv;
    p1im = (nim * zre - nre * zim) * inv;
  }
  float fre = p1re * dtv, fim = p1im * dtv;
  float hre = bf2f(HtRe[idx]), him = bf2f(HtIm[idx]);
  float xre = bf2f(XtRe[idx]) + sre[c], xim = bf2f(XtIm[idx]) + sim[c];
  float ore = hre * dcre - him * dcim + xre * fre - xim * fim;
  float oim = hre * dcim + him * dcre + xre * fim + xim * fre;
  HnRe[idx] = f2bf(ore); HnIm[idx] = f2bf(imSign * oim);
}

__global__ void k_fill(float* p, size_t n, float v) {
  const size_t idx = (size_t)blockIdx.x * 256 + threadIdx.x;
  if (idx < n) p[idx] = v;
}

// ---------------- host ----------------
static void launch_gemm(int mode, int out, int M, int N, int K, int lda, int ldb,
                        long ldc, int cstride, int nz, const ZP* z, hipStream_t s) {
  GArgs a; a.K = K; a.lda = lda; a.ldb = ldb; a.ldc = ldc; a.cstride = cstride;
  for (int i = 0; i < 8; ++i) a.z[i] = z[i < nz ? i : 0];
  dim3 g(N / 128, M / 128, nz), blk(256);
  if (mode == 1 && out == 0)      gemm_nt<1, 0><<<g, blk, 0, s>>>(a);
  else if (mode == 1 && out == 2) gemm_nt<1, 2><<<g, blk, 0, s>>>(a);
  else if (mode == 2)             gemm_nt<2, 0><<<g, blk, 0, s>>>(a);
  else if (out == 1)              gemm_nt<0, 1><<<g, blk, 0, s>>>(a);
  else                            gemm_nt<0, 0><<<g, blk, 0, s>>>(a);
}

static void launch_gemm256(int out, int M, int N, int K, int lda, int ldb,
                           long ldc, int cstride, int nz, const ZP* z, hipStream_t s) {
  GArgs a; a.K = K; a.lda = lda; a.ldb = ldb; a.ldc = ldc; a.cstride = cstride;
  for (int i = 0; i < 8; ++i) a.z[i] = z[i < nz ? i : 0];
  dim3 g(N / 256, M / 256, nz), blk(512);
  if (out == 1) gemm_nt256<1><<<g, blk, 0, s>>>(a);
  else          gemm_nt256<0><<<g, blk, 0, s>>>(a);
}

extern "C" void kernel_launch(void* const* d_in, const int* in_sizes, int n_in,
                              void* d_out, int out_size, void* d_ws, size_t ws_size,
                              hipStream_t stream) {
  const float* h_prev  = (const float*)d_in[0];
  const float* x_input = (const float*)d_in[1];
  const float* dt      = (const float*)d_in[2];
  const float* ur      = (const float*)d_in[3];
  const float* ui      = (const float*)d_in[4];
  const float* vr      = (const float*)d_in[5];
  const float* vi      = (const float*)d_in[6];
  const float* logsig  = (const float*)d_in[7];
  const float* ld      = (const float*)d_in[8];
  const float* lf      = (const float*)d_in[9];
  const float* dts     = (const float*)d_in[10];
  const float* sre     = (const float*)d_in[11];
  const float* sim     = (const float*)d_in[12];
  const float* lwre    = (const float*)d_in[13];
  const float* lwim    = (const float*)d_in[14];
  const float* sel_w   = (const float*)d_in[15];
  const float* sel_b   = (const float*)d_in[16];
  float* out = (float*)d_out;
  char* ws = (char*)d_ws;

  const bool realOnly = ((size_t)out_size == BD);
  const bool interleaved = ((size_t)out_size == 2 * BD);
  if ((!realOnly && !interleaved) || ws_size < 224 * MBy) {
    k_fill<<<dim3(((size_t)out_size + 255) / 256), dim3(256), 0, stream>>>(out, (size_t)out_size, 1e9f);
    return;
  }

  // persistent region [0,16MB)
  u16* MiRe_b = (u16*)(ws + 0 * MBy);
  u16* MiIm_b = (u16*)(ws + 2 * MBy);
  u16* MRe_b  = (u16*)(ws + 4 * MBy);
  u16* MIm_b  = (u16*)(ws + 6 * MBy);
  u16* G_hi   = (u16*)(ws + 8 * MBy);
  u16* G_lo   = (u16*)(ws + 12 * MBy);
  char* AR = ws + 16 * MBy;  // arena
  // phase A
  float* Af32   = (float*)(AR + 0);        // 16 MB
  u16* Ahi      = (u16*)(AR + 16 * MBy);   // 8
  u16* Alo      = (u16*)(AR + 24 * MBy);   // 8
  u16* AsumH    = (u16*)(AR + 32 * MBy);   // 4
  u16* AsumL    = (u16*)(AR + 36 * MBy);   // 4
  float* Xf32   = (float*)(AR + 40 * MBy); // 16
  u16* Xhi      = (u16*)(AR + 56 * MBy);   // 8
  u16* Xlo      = (u16*)(AR + 64 * MBy);   // 8
  u16* XThi     = (u16*)(AR + 72 * MBy);   // 8
  u16* XTlo     = (u16*)(AR + 80 * MBy);   // 8
  u16* XsumH    = (u16*)(AR + 88 * MBy);   // 4
  u16* XTsumH   = (u16*)(AR + 92 * MBy);   // 4
  u16* XTsumL   = (u16*)(AR + 96 * MBy);   // 4
  u16* WThi     = (u16*)(AR + 100 * MBy);  // 8
  u16* WTsumH   = (u16*)(AR + 108 * MBy);  // 4
  float* T      = (float*)(AR + 112 * MBy);// 24 (6 f32 planes)
  u16* VsHi     = (u16*)(AR + 136 * MBy);  // 4
  u16* VsLo     = (u16*)(AR + 140 * MBy);  // 4
  u16* UHi      = (u16*)(AR + 144 * MBy);  // 4
  u16* ULo      = (u16*)(AR + 148 * MBy);  // 4
  u16* UsHi     = (u16*)(AR + 152 * MBy);  // 4
  u16* VHi      = (u16*)(AR + 156 * MBy);  // 4
  u16* UdifH    = (u16*)(AR + 160 * MBy);  // 2
  u16* UdifL    = (u16*)(AR + 162 * MBy);  // 2
  u16* UssumH   = (u16*)(AR + 164 * MBy);  // 2
  u16* VssumH   = (u16*)(AR + 166 * MBy);  // 2
  u16* VssumL   = (u16*)(AR + 168 * MBy);  // 2
  u16* VdifH    = (u16*)(AR + 170 * MBy);  // 2
  u16* MiTcH    = (u16*)(AR + 172 * MBy);  // 4 (1024 x 2048 cat-K Bt, hi)
  u16* MiTcL    = (u16*)(AR + 176 * MBy);  // 4
  u16* W_hi     = (u16*)(AR + 180 * MBy);  // 8
  u16* W_lo     = (u16*)(AR + 188 * MBy);  // 8
  // phase B (reuses arena)
  u16* Hb     = (u16*)(AR + 0);
  u16* XbHi   = (u16*)(AR + 16 * MBy);
  u16* XbLo   = (u16*)(AR + 32 * MBy);
  u16* HtRe   = (u16*)(AR + 48 * MBy);
  u16* HtIm   = (u16*)(AR + 64 * MBy);
  u16* XtRe   = (u16*)(AR + 80 * MBy);
  u16* XtIm   = (u16*)(AR + 96 * MBy);
  float* delta= (float*)(AR + 112 * MBy);
  u16* HnRe   = (u16*)(AR + 176 * MBy);
  u16* HnIm   = (u16*)(AR + 192 * MBy);

  dim3 b256(256);
  const dim3 tdd(16, 16, 2);   // 64x64-tile elementwise grid

  // ---- Phase A: Cayley(U), Cayley(V) via Newton + Karatsuba ----
  k_buildA<<<tdd, b256, 0, stream>>>(ur, ui, vr, vi, Af32, Ahi, Alo, AsumH, AsumL);

  {  // A^2: 3 products per y
    ZP z[6];
    for (int y = 0; y < 2; ++y) {
      const u16* are = Ahi + (size_t)y * 2 * DD; const u16* aim = are + DD;
      float* t = T + (size_t)y * 3 * DD;
      z[y*3+0] = {are, nullptr, are, nullptr, t,          nullptr, 1.f, 0.f};
      z[y*3+1] = {aim, nullptr, aim, nullptr, t + DD,     nullptr, 1.f, 0.f};
      z[y*3+2] = {are, nullptr, aim, nullptr, t + 2*DD,   nullptr, 1.f, 0.f};
    }
    launch_gemm(0, 0, 1024, 1024, 1024, 1024, 1024, 1024, 1, 6, z, stream);
  }
  k_x0<<<tdd, b256, 0, stream>>>(Af32, T, Xf32, Xhi, XThi, XsumH, XTsumH);

  for (int it = 0; it < 2; ++it) {  // bf16 Newton iterations (Kara)
    {  // Q = A@X
      ZP z[6];
      for (int y = 0; y < 2; ++y) {
        const u16* are = Ahi + (size_t)y*2*DD; const u16* aim = are + DD;
        const u16* xtr = XThi + (size_t)y*2*DD; const u16* xti = xtr + DD;
        float* t = T + (size_t)y*3*DD;
        z[y*3+0] = {are, nullptr, xtr, nullptr, t,        nullptr, 1.f, 0.f};
        z[y*3+1] = {aim, nullptr, xti, nullptr, t + DD,   nullptr, 1.f, 0.f};
        z[y*3+2] = {AsumH + (size_t)y*DD, nullptr, XTsumH + (size_t)y*DD, nullptr, t + 2*DD, nullptr, 1.f, 0.f};
      }
      launch_gemm(0, 0, 1024, 1024, 1024, 1024, 1024, 1024, 1, 6, z, stream);
    }
    k_wt<<<tdd, b256, 0, stream>>>(Xf32, T, WThi, WTsumH, 2.0f);
    {  // X' = X@W
      ZP z[6];
      for (int y = 0; y < 2; ++y) {
        const u16* xre = Xhi + (size_t)y*2*DD; const u16* xim = xre + DD;
        const u16* wtr = WThi + (size_t)y*2*DD; const u16* wti = wtr + DD;
        float* t = T + (size_t)y*3*DD;
        z[y*3+0] = {xre, nullptr, wtr, nullptr, t,        nullptr, 1.f, 0.f};
        z[y*3+1] = {xim, nullptr, wti, nullptr, t + DD,   nullptr, 1.f, 0.f};
        z[y*3+2] = {XsumH + (size_t)y*DD, nullptr, WTsumH + (size_t)y*DD, nullptr, t + 2*DD, nullptr, 1.f, 0.f};
      }
      launch_gemm(0, 0, 1024, 1024, 1024, 1024, 1024, 1024, 1, 6, z, stream);
    }
    const bool last = (it == 1);
    k_xn<<<tdd, b256, 0, stream>>>(T, Xf32, Xhi, XThi, XsumH, XTsumH,
                                   last ? Xlo : nullptr, last ? XTlo : nullptr,
                                   last ? XTsumL : nullptr);
  }

  {  // refine: Q = A@X split precision (Kara)
    ZP z[6];
    for (int y = 0; y < 2; ++y) {
      const u16* areh = Ahi + (size_t)y*2*DD; const u16* aimh = areh + DD;
      const u16* arel = Alo + (size_t)y*2*DD; const u16* aiml = arel + DD;
      const u16* xtrh = XThi + (size_t)y*2*DD; const u16* xtih = xtrh + DD;
      const u16* xtrl = XTlo + (size_t)y*2*DD; const u16* xtil = xtrl + DD;
      float* t = T + (size_t)y*3*DD;
      z[y*3+0] = {areh, arel, xtrh, xtrl, t,        nullptr, 1.f, 0.f};
      z[y*3+1] = {aimh, aiml, xtih, xtil, t + DD,   nullptr, 1.f, 0.f};
      z[y*3+2] = {AsumH + (size_t)y*DD, AsumL + (size_t)y*DD,
                  XTsumH + (size_t)y*DD, XTsumL + (size_t)y*DD, t + 2*DD, nullptr, 1.f, 0.f};
    }
    launch_gemm(1, 0, 1024, 1024, 1024, 1024, 1024, 1024, 1, 6, z, stream);
  }
  k_wt<<<tdd, b256, 0, stream>>>(Xf32, T, WThi, WTsumH, 1.0f);
  {  // XR = X@R (plain, Kara)
    ZP z[6];
    for (int y = 0; y < 2; ++y) {
      const u16* xre = Xhi + (size_t)y*2*DD; const u16* xim = xre + DD;
      const u16* rtr = WThi + (size_t)y*2*DD; const u16* rti = rtr + DD;
      float* t = T + (size_t)y*3*DD;
      z[y*3+0] = {xre, nullptr, rtr, nullptr, t,        nullptr, 1.f, 0.f};
      z[y*3+1] = {xim, nullptr, rti, nullptr, t + DD,   nullptr, 1.f, 0.f};
      z[y*3+2] = {XsumH + (size_t)y*DD, nullptr, WTsumH + (size_t)y*DD, nullptr, t + 2*DD, nullptr, 1.f, 0.f};
    }
    launch_gemm(0, 0, 1024, 1024, 1024, 1024, 1024, 1024, 1, 6, z, stream);
  }
  k_finalUV<<<dim3(4096, 2), b256, 0, stream>>>(Xf32, T, logsig, VsHi, VsLo, UHi, ULo, UsHi, VHi,
                                                UdifH, UdifL, UssumH, VssumH, VssumL, VdifH);

  {  // Minv = (V s_inv) @ U^H : conj-Kara, split
    ZP z[3] = {
      {VsHi,      VsLo,      UHi,      ULo,      T,        nullptr, 1.f, 0.f},
      {VsHi + DD, VsLo + DD, UHi + DD, ULo + DD, T + DD,   nullptr, 1.f, 0.f},
      {VssumH,    VssumL,    UdifH,    UdifL,    T + 2*DD, nullptr, 1.f, 0.f}};
    launch_gemm(1, 0, 1024, 1024, 1024, 1024, 1024, 1024, 1, 3, z, stream);
  }
  {  // M = (U s) @ V^H : conj-Kara, plain
    ZP z[3] = {
      {UsHi,      nullptr, VHi,      nullptr, T + 3*DD, nullptr, 1.f, 0.f},
      {UsHi + DD, nullptr, VHi + DD, nullptr, T + 4*DD, nullptr, 1.f, 0.f},
      {UssumH,    nullptr, VdifH,    nullptr, T + 5*DD, nullptr, 1.f, 0.f}};
    launch_gemm(0, 0, 1024, 1024, 1024, 1024, 1024, 1024, 1, 3, z, stream);
  }
  k_cmb_M<<<dim3(16, 16), b256, 0, stream>>>(T, MiRe_b, MiIm_b, MiTcH, MiTcL, MRe_b, MIm_b);

  // G = [W1|W2] @ [MiRe^T | MiIm^T]  (single K=2048 split GEMM, split-pair output)
  k_split<<<dim3(16384), b256, 0, stream>>>(sel_w, W_hi, W_lo, (size_t)2048 * 2048);
  {
    ZP z1[1] = {{W_hi, W_lo, MiTcH, MiTcL, G_hi, G_lo, 1.f, 0.f}};
    launch_gemm(1, 2, 2048, 1024, 2048, 2048, 2048, 1024, 1, 1, z1, stream);
  }

  // ---- Phase B ----
  k_splitB<<<dim3(8192), b256, 0, stream>>>(x_input, h_prev, XbHi, XbLo, Hb);
  {  // encode: h_tilde / x_tilde (bf16 out) — 256^2 tile
    ZP z[4] = {
      {Hb,   nullptr, MiRe_b, nullptr, HtRe, nullptr, 1.f, 0.f},
      {Hb,   nullptr, MiIm_b, nullptr, HtIm, nullptr, 1.f, 0.f},
      {XbHi, nullptr, MiRe_b, nullptr, XtRe, nullptr, 1.f, 0.f},
      {XbHi, nullptr, MiIm_b, nullptr, XtIm, nullptr, 1.f, 0.f}};
    launch_gemm256(1, 8192, 1024, 1024, 1024, 1024, 1024, 1, 4, z, stream);
  }
  // delta = x @ G^T: split only for dt_n-large cols ([0,512) and [1024,1536))
  {  // split half
    ZP z[2] = {
      {XbHi, XbLo, G_hi,                     G_lo,                     delta,        nullptr, 1.f, 0.f},
      {XbHi, XbLo, G_hi + 1024 * (size_t)Dd, G_lo + 1024 * (size_t)Dd, delta + 1024, nullptr, 1.f, 0.f}};
    launch_gemm(1, 0, 8192, 512, 1024, 1024, 1024, 2048, 1, 2, z, stream);
  }
  {  // plain half
    ZP z[2] = {
      {XbHi, nullptr, G_hi + 512 * (size_t)Dd,  nullptr, delta + 512,  nullptr, 1.f, 0.f},
      {XbHi, nullptr, G_hi + 1536 * (size_t)Dd, nullptr, delta + 1536, nullptr, 1.f, 0.f}};
    launch_gemm(0, 0, 8192, 512, 1024, 1024, 1024, 2048, 1, 2, z, stream);
  }

  if (realOnly) {
    k_pointwise<<<dim3(32768), b256, 0, stream>>>(HtRe, HtIm, XtRe, XtIm, delta, dt, ld, lf, dts,
                                                  sre, sim, lwre, lwim, sel_b, HnRe, HnIm, -1.0f);
    ZP z1[1] = {{HnRe, HnIm, MRe_b, MIm_b, out, nullptr, 1.f, 0.f}};
    launch_gemm(2, 0, 8192, 1024, 1024, 1024, 1024, 1024, 1, 1, z1, stream);
  } else {
    k_pointwise<<<dim3(32768), b256, 0, stream>>>(HtRe, HtIm, XtRe, XtIm, delta, dt, ld, lf, dts,
                                                  sre, sim, lwre, lwim, sel_b, HnRe, HnIm, 1.0f);
    {
      ZP z[2] = {
        {HnRe, nullptr, MRe_b, nullptr, out,     nullptr, 1.f, 0.f},
        {HnRe, nullptr, MIm_b, nullptr, out + 1, nullptr, 1.f, 0.f}};
      launch_gemm(0, 0, 8192, 1024, 1024, 1024, 1024, 2048, 2, 2, z, stream);
    }
    {
      ZP z[2] = {
        {HnIm, nullptr, MIm_b, nullptr, out,     nullptr, -1.f, 1.f},
        {HnIm, nullptr, MRe_b, nullptr, out + 1, nullptr,  1.f, 1.f}};
      launch_gemm(0, 0, 8192, 1024, 1024, 1024, 1024, 2048, 2, 2, z, stream);
    }
  }
}

// Round 9
// 658.070 us; speedup vs baseline: 1.6225x; 1.0495x over previous
//
#include <hip/hip_runtime.h>
#include <hip/hip_bf16.h>

#define Dd 1024
#define Bb 8192

typedef unsigned short u16;
typedef __attribute__((ext_vector_type(8))) short short8;
typedef __attribute__((ext_vector_type(4))) float f32x4;
typedef __attribute__((ext_vector_type(4))) float float4v;

static constexpr size_t DD  = (size_t)Dd * Dd;   // 1M
static constexpr size_t BD  = (size_t)Bb * Dd;   // 8M
static constexpr size_t MBy = 1ull << 20;

__device__ __forceinline__ float bf2f(u16 v) {
  union { unsigned u; float f; } c; c.u = ((unsigned)v) << 16; return c.f;
}
__device__ __forceinline__ u16 f2bf(float f) {
  union { float f; unsigned u; } c; c.f = f;
  return (u16)((c.u + 0x7fffu + ((c.u >> 16) & 1u)) >> 16);
}

union U64 { u16 u[4]; unsigned long long v; };

// ---------------- NT GEMM: C[m][n] = alpha * sum_k A[m][k]*Bt[n][k] (+beta*C) ----------
// MODE 0: 1 MFMA (Ah*Bh), BK=64, 2 LDS arrays ; MODE 1: 3 MFMA split, BK=32, 4 arrays.
// Both: 32 KB/buffer, dbuf 64 KB -> 2 blocks/CU. OUT 0: f32(+beta) ; 1: bf16 ; 2: bf16 hi/lo.
struct ZP { const u16* Ah; const u16* Al; const u16* Bh; const u16* Bl; void* C; void* C2; float alpha; float beta; };
struct GArgs { ZP z[8]; int K, lda, ldb; long ldc; int cstride; };

template<int OUT>
__device__ __forceinline__ void c_store(const ZP& p, long cidx, float acc) {
  float v = acc * p.alpha;
  if constexpr (OUT == 1) {
    ((u16*)p.C)[cidx] = f2bf(v);
  } else if constexpr (OUT == 2) {
    u16 h = f2bf(v);
    ((u16*)p.C)[cidx] = h;
    ((u16*)p.C2)[cidx] = f2bf(v - bf2f(h));
  } else {
    float* C = (float*)p.C;
    if (p.beta != 0.0f) v += p.beta * C[cidx];
    C[cidx] = v;
  }
}

template<int MODE, int OUT>
__global__ __launch_bounds__(256) void gemm_nt(GArgs a) {
  constexpr bool X2 = (MODE != 0);
  constexpr int BK  = X2 ? 32 : 64;
  constexpr int BUFS = 16384;                    // u16 per buffer (32 KB) both modes
  __shared__ __align__(16) u16 smem[2 * BUFS];   // 64 KB -> 2 blocks/CU
  const ZP p = a.z[blockIdx.z];
  const int tid  = threadIdx.x;
  const int lane = tid & 63, wv = tid >> 6;

  int bx = blockIdx.x, by = blockIdx.y;          // T1 XCD-chunked swizzle
  {
    const int gx = gridDim.x;
    const int nwg = gx * gridDim.y;
    if ((nwg & 7) == 0 && nwg >= 16) {
      const int flat = by * gx + bx;
      const int ch = nwg >> 3;
      const int nf = (flat & 7) * ch + (flat >> 3);
      bx = nf % gx; by = nf / gx;
    }
  }

  const long brow = (long)by * 128, bcol = (long)bx * 128;
  const int wm = (wv & 1) * 64, wn = (wv >> 1) * 64;
  // MODE0 staging geometry (BK=64): row=wv*8+(lane>>3) per i*32 ; chunk swz c^(row&7)
  const int srow = wv * 8 + (lane >> 3);
  const int sgc64 = ((lane & 7) ^ (lane >> 3)) * 8;
  // MODE1 staging geometry (BK=32): row=tid>>2 (+64/pass) ; chunk swz c^((row>>1)&3)
  const int sgc32 = ((tid & 3) ^ ((tid >> 3) & 3)) * 8;

  f32x4 acc[4][4];
#pragma unroll
  for (int i = 0; i < 4; ++i)
#pragma unroll
    for (int j = 0; j < 4; ++j) { f32x4 zv = {0.f, 0.f, 0.f, 0.f}; acc[i][j] = zv; }

  auto STAGE = [&](int kt, int buf) {
    u16* base = smem + buf * BUFS;
    if constexpr (!X2) {
      u16* As = base;
      u16* Bs = base + 8192;
#pragma unroll
      for (int i = 0; i < 4; ++i) {
        const int rr = i * 32 + srow;
        const int lb = (i * 32 + wv * 8) * 64;
        const u16* ga = p.Ah + (brow + rr) * (long)a.lda + kt + sgc64;
        const u16* gb = p.Bh + (bcol + rr) * (long)a.ldb + kt + sgc64;
        __builtin_amdgcn_global_load_lds((const __attribute__((address_space(1))) void*)ga,
                                         (__attribute__((address_space(3))) void*)(As + lb), 16, 0, 0);
        __builtin_amdgcn_global_load_lds((const __attribute__((address_space(1))) void*)gb,
                                         (__attribute__((address_space(3))) void*)(Bs + lb), 16, 0, 0);
      }
    } else {
      // arrays: Ah @0, Bh @4096, Al @8192, Bl @12288 ; per array 128x32, 2 passes
#pragma unroll
      for (int pass = 0; pass < 2; ++pass) {
        const int row = pass * 64 + (tid >> 2);
        const int lb = pass * 2048 + tid * 8;
        const u16* ga = p.Ah + (brow + row) * (long)a.lda + kt + sgc32;
        const u16* gb = p.Bh + (bcol + row) * (long)a.ldb + kt + sgc32;
        const u16* ga2 = p.Al + (brow + row) * (long)a.lda + kt + sgc32;
        const u16* gb2 = p.Bl + (bcol + row) * (long)a.ldb + kt + sgc32;
        __builtin_amdgcn_global_load_lds((const __attribute__((address_space(1))) void*)ga,
                                         (__attribute__((address_space(3))) void*)(base + lb), 16, 0, 0);
        __builtin_amdgcn_global_load_lds((const __attribute__((address_space(1))) void*)gb,
                                         (__attribute__((address_space(3))) void*)(base + 4096 + lb), 16, 0, 0);
        __builtin_amdgcn_global_load_lds((const __attribute__((address_space(1))) void*)ga2,
                                         (__attribute__((address_space(3))) void*)(base + 8192 + lb), 16, 0, 0);
        __builtin_amdgcn_global_load_lds((const __attribute__((address_space(1))) void*)gb2,
                                         (__attribute__((address_space(3))) void*)(base + 12288 + lb), 16, 0, 0);
      }
    }
  };

  auto COMPUTE = [&](int buf) {
    u16* base = smem + buf * BUFS;
    if constexpr (!X2) {
      u16* As = base;
      u16* Bs = base + 8192;
#pragma unroll
      for (int kk = 0; kk < 64; kk += 32) {
        const int jf = (kk >> 3) + (lane >> 4);
        const int cs = ((jf ^ (lane & 7)) << 3);
        short8 af[4], bfv[4];
#pragma unroll
        for (int i = 0; i < 4; ++i) {
          af[i]  = *(const short8*)(As + (wm + i * 16 + (lane & 15)) * 64 + cs);
          bfv[i] = *(const short8*)(Bs + (wn + i * 16 + (lane & 15)) * 64 + cs);
        }
#pragma unroll
        for (int i = 0; i < 4; ++i)
#pragma unroll
          for (int j = 0; j < 4; ++j)
            acc[i][j] = __builtin_amdgcn_mfma_f32_16x16x32_bf16(af[i], bfv[j], acc[i][j], 0, 0, 0);
      }
    } else {
      const int jf = lane >> 4;                      // chunk 0..3 (K=32)
      const int cs = ((jf ^ ((lane >> 1) & 3)) << 3);// row-swz: ((lane&15)>>1)&3
      short8 af[4], bfv[4], al[4], bl[4];
#pragma unroll
      for (int i = 0; i < 4; ++i) {
        const int ra = (wm + i * 16 + (lane & 15)) * 32 + cs;
        const int rb = (wn + i * 16 + (lane & 15)) * 32 + cs;
        af[i]  = *(const short8*)(base + ra);
        bfv[i] = *(const short8*)(base + 4096 + rb);
        al[i]  = *(const short8*)(base + 8192 + ra);
        bl[i]  = *(const short8*)(base + 12288 + rb);
      }
#pragma unroll
      for (int i = 0; i < 4; ++i)
#pragma unroll
        for (int j = 0; j < 4; ++j) {
          acc[i][j] = __builtin_amdgcn_mfma_f32_16x16x32_bf16(af[i], bfv[j], acc[i][j], 0, 0, 0);
          acc[i][j] = __builtin_amdgcn_mfma_f32_16x16x32_bf16(al[i], bfv[j], acc[i][j], 0, 0, 0);
          acc[i][j] = __builtin_amdgcn_mfma_f32_16x16x32_bf16(af[i], bl[j], acc[i][j], 0, 0, 0);
        }
    }
  };

  const int nkt = a.K / BK;
  STAGE(0, 0);
  __syncthreads();
  int cur = 0;
  for (int t = 0; t < nkt - 1; ++t) {
    STAGE((t + 1) * BK, cur ^ 1);
    COMPUTE(cur);
    __syncthreads();
    cur ^= 1;
  }
  COMPUTE(cur);

  const long crow = brow + wm + ((lane >> 4) * 4);
  const long ccol = bcol + wn + (lane & 15);
#pragma unroll
  for (int i = 0; i < 4; ++i)
#pragma unroll
    for (int j = 0; j < 4; ++j)
#pragma unroll
      for (int r = 0; r < 4; ++r) {
        const long cidx = (crow + i * 16 + r) * a.ldc + (ccol + j * 16) * (long)a.cstride;
        c_store<OUT>(p, cidx, acc[i][j][r]);
      }
}

// ---- 256x256-tile MODE0 GEMM (8 waves / 512 thr) ----
template<int OUT>
__global__ __launch_bounds__(512, 1) void gemm_nt256(GArgs a) {
  constexpr int BUFS = 32768;
  __shared__ __align__(16) u16 smem[2 * BUFS];
  const ZP p = a.z[blockIdx.z];
  const int tid  = threadIdx.x;
  const int lane = tid & 63, wv = tid >> 6;
  const int wr = wv >> 2, wc = wv & 3;

  int bx = blockIdx.x, by = blockIdx.y;
  {
    const int gx = gridDim.x;
    const int nwg = gx * gridDim.y;
    if ((nwg & 7) == 0 && nwg >= 16) {
      const int flat = by * gx + bx;
      const int ch = nwg >> 3;
      const int nf = (flat & 7) * ch + (flat >> 3);
      bx = nf % gx; by = nf / gx;
    }
  }

  const long brow = (long)by * 256, bcol = (long)bx * 256;
  const int sgc = ((tid & 7) ^ ((tid >> 3) & 7)) * 8;

  f32x4 acc[8][4];
#pragma unroll
  for (int i = 0; i < 8; ++i)
#pragma unroll
    for (int j = 0; j < 4; ++j) { f32x4 zv = {0.f, 0.f, 0.f, 0.f}; acc[i][j] = zv; }

  auto STAGE = [&](int kt, int buf) {
    u16* As = smem + buf * BUFS;
    u16* Bs = As + 16384;
#pragma unroll
    for (int i = 0; i < 4; ++i) {
      const int rr = i * 64 + (tid >> 3);
      const int lb = i * 4096 + tid * 8;
      const u16* ga = p.Ah + (brow + rr) * (long)a.lda + kt + sgc;
      const u16* gb = p.Bh + (bcol + rr) * (long)a.ldb + kt + sgc;
      __builtin_amdgcn_global_load_lds((const __attribute__((address_space(1))) void*)ga,
                                       (__attribute__((address_space(3))) void*)(As + lb), 16, 0, 0);
      __builtin_amdgcn_global_load_lds((const __attribute__((address_space(1))) void*)gb,
                                       (__attribute__((address_space(3))) void*)(Bs + lb), 16, 0, 0);
    }
  };

  auto COMPUTE = [&](int buf) {
    u16* As = smem + buf * BUFS;
    u16* Bs = As + 16384;
#pragma unroll
    for (int kk = 0; kk < 64; kk += 32) {
      const int jf = (kk >> 3) + (lane >> 4);
      const int cs = ((jf ^ (lane & 7)) << 3);
      short8 af[8], bfv[4];
#pragma unroll
      for (int i = 0; i < 8; ++i)
        af[i] = *(const short8*)(As + (wr * 128 + i * 16 + (lane & 15)) * 64 + cs);
#pragma unroll
      for (int j = 0; j < 4; ++j)
        bfv[j] = *(const short8*)(Bs + (wc * 64 + j * 16 + (lane & 15)) * 64 + cs);
#pragma unroll
      for (int i = 0; i < 8; ++i)
#pragma unroll
        for (int j = 0; j < 4; ++j)
          acc[i][j] = __builtin_amdgcn_mfma_f32_16x16x32_bf16(af[i], bfv[j], acc[i][j], 0, 0, 0);
    }
  };

  const int nkt = a.K >> 6;
  STAGE(0, 0);
  __syncthreads();
  int cur = 0;
  for (int t = 0; t < nkt - 1; ++t) {
    STAGE((t + 1) * 64, cur ^ 1);
    COMPUTE(cur);
    __syncthreads();
    cur ^= 1;
  }
  COMPUTE(cur);

  const long crow = brow + wr * 128 + ((lane >> 4) * 4);
  const long ccol = bcol + wc * 64 + (lane & 15);
#pragma unroll
  for (int i = 0; i < 8; ++i)
#pragma unroll
    for (int j = 0; j < 4; ++j)
#pragma unroll
      for (int r = 0; r < 4; ++r) {
        const long cidx = (crow + i * 16 + r) * a.ldc + (ccol + j * 16) * (long)a.cstride;
        c_store<OUT>(p, cidx, acc[i][j][r]);
      }
}

// ---------------- elementwise kernels (64x64 LDS-tile, coalesced) ----------------
#define TLOAD(ldsbuf, srcp) do { \
  _Pragma("unroll") \
  for (int i_ = 0; i_ < 4; ++i_) { \
    int row_ = ty + i_ * 16; \
    float4v v_ = *(const float4v*)((srcp) + (size_t)row_ * Dd + tx * 4); \
    ldsbuf[row_][tx * 4 + 0] = v_[0]; ldsbuf[row_][tx * 4 + 1] = v_[1]; \
    ldsbuf[row_][tx * 4 + 2] = v_[2]; ldsbuf[row_][tx * 4 + 3] = v_[3]; \
  } } while (0)

__global__ void k_buildA(const float* ur, const float* ui, const float* vr, const float* vi,
                         float* Af32, u16* Ahi, u16* Alo, u16* AsumH, u16* AsumL) {
  __shared__ float ldsA[64][65], ldsB[64][65];
  const int y = blockIdx.z;
  const int tx = threadIdx.x & 15, ty = threadIdx.x >> 4;
  const int R0 = blockIdx.y * 64, C0 = blockIdx.x * 64;
  const float* re = y ? vr : ur; const float* im = y ? vi : ui;
  TLOAD(ldsA, re + (size_t)C0 * Dd + R0);
  TLOAD(ldsB, im + (size_t)C0 * Dd + R0);
  __syncthreads();
#pragma unroll
  for (int i = 0; i < 4; ++i) {
    const int r = R0 + ty + i * 16;
    const size_t base = (size_t)r * Dd + C0 + tx * 4;
    float4v vre = *(const float4v*)(re + base);
    float4v vim = *(const float4v*)(im + base);
    float4v oar, oai;
    U64 ph, pl, pih, pil, sh, sl;
#pragma unroll
    for (int j = 0; j < 4; ++j) {
      float are = 0.5f * (vre[j] - ldsA[tx * 4 + j][ty + i * 16]);
      float aim = 0.5f * (vim[j] + ldsB[tx * 4 + j][ty + i * 16]);
      oar[j] = are; oai[j] = aim;
      u16 h = f2bf(are); ph.u[j] = h; pl.u[j] = f2bf(are - bf2f(h));
      h = f2bf(aim); pih.u[j] = h; pil.u[j] = f2bf(aim - bf2f(h));
      float s = are + aim; h = f2bf(s); sh.u[j] = h; sl.u[j] = f2bf(s - bf2f(h));
    }
    const size_t pr = (size_t)y * 2 * DD + base, pi = pr + DD;
    *(float4v*)(Af32 + pr) = oar; *(float4v*)(Af32 + pi) = oai;
    *(unsigned long long*)(Ahi + pr) = ph.v; *(unsigned long long*)(Alo + pr) = pl.v;
    *(unsigned long long*)(Ahi + pi) = pih.v; *(unsigned long long*)(Alo + pi) = pil.v;
    const size_t ps = (size_t)y * DD + base;
    *(unsigned long long*)(AsumH + ps) = sh.v; *(unsigned long long*)(AsumL + ps) = sl.v;
  }
}

__global__ void k_x0(const float* Af32, const float* T, float* Xf32, u16* Xhi, u16* XThi,
                     u16* XsumH, u16* XTsumH) {
  __shared__ float ldsA[64][65], ldsB[64][65];
  const int y = blockIdx.z;
  const int tx = threadIdx.x & 15, ty = threadIdx.x >> 4;
  const int R0 = blockIdx.y * 64, C0 = blockIdx.x * 64;
  const float* t0p = T + (size_t)y * 3 * DD;
  const float* t1p = t0p + DD;
  const float* t2p = t0p + 2 * DD;
  TLOAD(ldsA, t2p + (size_t)C0 * Dd + R0);
  __syncthreads();
  float xr[4][4], xi[4][4];
#pragma unroll
  for (int i = 0; i < 4; ++i) {
    const int r = R0 + ty + i * 16;
    const size_t base = (size_t)r * Dd + C0 + tx * 4;
    float4v v0 = *(const float4v*)(t0p + base);
    float4v v1 = *(const float4v*)(t1p + base);
    float4v v2 = *(const float4v*)(t2p + base);
    const size_t pr = (size_t)y * 2 * DD + base, pi = pr + DD;
    float4v ar = *(const float4v*)(Af32 + pr);
    float4v ai = *(const float4v*)(Af32 + pi);
    float4v oxr, oxi;
    U64 ph, pih, sh;
#pragma unroll
    for (int j = 0; j < 4; ++j) {
      const int c = C0 + tx * 4 + j;
      float xre = ar[j] - v0[j] - v1[j] + (r == c ? 1.0f : 0.0f);
      float xim = ai[j] + v2[j] - ldsA[tx * 4 + j][ty + i * 16];
      xr[i][j] = xre; xi[i][j] = xim;
      oxr[j] = xre; oxi[j] = xim;
      ph.u[j] = f2bf(xre); pih.u[j] = f2bf(xim);
      sh.u[j] = f2bf(xre + xim);
    }
    *(float4v*)(Xf32 + pr) = oxr; *(float4v*)(Xf32 + pi) = oxi;
    *(unsigned long long*)(Xhi + pr) = ph.v; *(unsigned long long*)(Xhi + pi) = pih.v;
    *(unsigned long long*)(XsumH + (size_t)y * DD + base) = sh.v;
  }
  __syncthreads();
#pragma unroll
  for (int i = 0; i < 4; ++i)
#pragma unroll
    for (int j = 0; j < 4; ++j) {
      ldsA[ty + i * 16][tx * 4 + j] = xr[i][j];
      ldsB[ty + i * 16][tx * 4 + j] = xi[i][j];
    }
  __syncthreads();
#pragma unroll
  for (int i = 0; i < 4; ++i) {
    const int cc = C0 + ty + i * 16;
    const size_t tb = (size_t)cc * Dd + R0 + tx * 4;
    U64 ph, pih, sh;
#pragma unroll
    for (int j = 0; j < 4; ++j) {
      float xre = ldsA[tx * 4 + j][ty + i * 16];
      float xim = ldsB[tx * 4 + j][ty + i * 16];
      ph.u[j] = f2bf(xre); pih.u[j] = f2bf(xim);
      sh.u[j] = f2bf(xre + xim);
    }
    const size_t qr = (size_t)y * 2 * DD + tb;
    *(unsigned long long*)(XThi + qr) = ph.v;
    *(unsigned long long*)(XThi + qr + DD) = pih.v;
    *(unsigned long long*)(XTsumH + (size_t)y * DD + tb) = sh.v;
  }
}

__global__ void k_wt(const float* Xf32, const float* T, u16* WThi, u16* WTsumH, float idc) {
  __shared__ float lds[64][65];
  const int y = blockIdx.z;
  const int tx = threadIdx.x & 15, ty = threadIdx.x >> 4;
  const int N0 = blockIdx.y * 64, K0 = blockIdx.x * 64;
  const float* t1p = T + (size_t)y * 3 * DD;
  const float* xrp = Xf32 + (size_t)y * 2 * DD;
  float wre[4][4], wim[4][4];
#pragma unroll
  for (int i = 0; i < 4; ++i)
#pragma unroll
    for (int j = 0; j < 4; ++j) {
      wre[i][j] = ((N0 + ty + i * 16) == (K0 + tx * 4 + j)) ? idc : 0.0f;
      wim[i][j] = 0.0f;
    }
  const float* planes[5] = {t1p, t1p + DD, t1p + 2 * DD, xrp, xrp + DD};
#pragma unroll
  for (int p = 0; p < 5; ++p) {
    TLOAD(lds, planes[p] + (size_t)K0 * Dd + N0);
    __syncthreads();
#pragma unroll
    for (int i = 0; i < 4; ++i)
#pragma unroll
      for (int j = 0; j < 4; ++j) {
        float v = lds[tx * 4 + j][ty + i * 16];
        if (p == 0) { wre[i][j] += v; wim[i][j] -= v; }
        else if (p == 1) { wre[i][j] -= v; wim[i][j] -= v; }
        else if (p == 2) { wim[i][j] += v; }
        else if (p == 3) { wre[i][j] -= v; }
        else { wim[i][j] -= v; }
      }
    __syncthreads();
  }
#pragma unroll
  for (int i = 0; i < 4; ++i) {
    const size_t base = (size_t)(N0 + ty + i * 16) * Dd + K0 + tx * 4;
    U64 ph, pih, sh;
#pragma unroll
    for (int j = 0; j < 4; ++j) {
      ph.u[j] = f2bf(wre[i][j]); pih.u[j] = f2bf(wim[i][j]);
      sh.u[j] = f2bf(wre[i][j] + wim[i][j]);
    }
    const size_t pr = (size_t)y * 2 * DD + base;
    *(unsigned long long*)(WThi + pr) = ph.v;
    *(unsigned long long*)(WThi + pr + DD) = pih.v;
    *(unsigned long long*)(WTsumH + (size_t)y * DD + base) = sh.v;
  }
}

__global__ void k_xn(const float* T, float* Xf32, u16* Xhi, u16* XThi, u16* XsumH, u16* XTsumH,
                     u16* Xlo, u16* XTlo, u16* XTsumL) {
  __shared__ float ldsA[64][65], ldsB[64][65];
  const int y = blockIdx.z;
  const int tx = threadIdx.x & 15, ty = threadIdx.x >> 4;
  const int R0 = blockIdx.y * 64, C0 = blockIdx.x * 64;
  const float* t1p = T + (size_t)y * 3 * DD;
  float xr[4][4], xi[4][4];
#pragma unroll
  for (int i = 0; i < 4; ++i) {
    const size_t base = (size_t)(R0 + ty + i * 16) * Dd + C0 + tx * 4;
    float4v v1 = *(const float4v*)(t1p + base);
    float4v v2 = *(const float4v*)(t1p + DD + base);
    float4v v3 = *(const float4v*)(t1p + 2 * DD + base);
    float4v oxr, oxi;
    U64 ph, pih, sh, plr, pli;
#pragma unroll
    for (int j = 0; j < 4; ++j) {
      float xre = v1[j] - v2[j];
      float xim = v3[j] - v1[j] - v2[j];
      xr[i][j] = xre; xi[i][j] = xim;
      oxr[j] = xre; oxi[j] = xim;
      u16 hr = f2bf(xre), hi_ = f2bf(xim);
      ph.u[j] = hr; pih.u[j] = hi_;
      sh.u[j] = f2bf(xre + xim);
      plr.u[j] = f2bf(xre - bf2f(hr)); pli.u[j] = f2bf(xim - bf2f(hi_));
    }
    const size_t pr = (size_t)y * 2 * DD + base, pi = pr + DD;
    *(float4v*)(Xf32 + pr) = oxr; *(float4v*)(Xf32 + pi) = oxi;
    *(unsigned long long*)(Xhi + pr) = ph.v; *(unsigned long long*)(Xhi + pi) = pih.v;
    *(unsigned long long*)(XsumH + (size_t)y * DD + base) = sh.v;
    if (Xlo) {
      *(unsigned long long*)(Xlo + pr) = plr.v;
      *(unsigned long long*)(Xlo + pi) = pli.v;
    }
  }
  __syncthreads();
#pragma unroll
  for (int i = 0; i < 4; ++i)
#pragma unroll
    for (int j = 0; j < 4; ++j) {
      ldsA[ty + i * 16][tx * 4 + j] = xr[i][j];
      ldsB[ty + i * 16][tx * 4 + j] = xi[i][j];
    }
  __syncthreads();
#pragma unroll
  for (int i = 0; i < 4; ++i) {
    const int cc = C0 + ty + i * 16;
    const size_t tb = (size_t)cc * Dd + R0 + tx * 4;
    U64 ph, pih, sh, plr, pli, sl;
#pragma unroll
    for (int j = 0; j < 4; ++j) {
      float xre = ldsA[tx * 4 + j][ty + i * 16];
      float xim = ldsB[tx * 4 + j][ty + i * 16];
      u16 hr = f2bf(xre), hi_ = f2bf(xim);
      ph.u[j] = hr; pih.u[j] = hi_;
      float s = xre + xim; u16 hs = f2bf(s);
      sh.u[j] = hs;
      plr.u[j] = f2bf(xre - bf2f(hr)); pli.u[j] = f2bf(xim - bf2f(hi_));
      sl.u[j] = f2bf(s - bf2f(hs));
    }
    const size_t qr = (size_t)y * 2 * DD + tb;
    *(unsigned long long*)(XThi + qr) = ph.v;
    *(unsigned long long*)(XThi + qr + DD) = pih.v;
    *(unsigned long long*)(XTsumH + (size_t)y * DD + tb) = sh.v;
    if (Xlo) {
      *(unsigned long long*)(XTlo + qr) = plr.v;
      *(unsigned long long*)(XTlo + qr + DD) = pli.v;
      *(unsigned long long*)(XTsumL + (size_t)y * DD + tb) = sl.v;
    }
  }
}

__global__ void k_finalUV(const float* Xf32, const float* T, const float* logsig,
                          u16* VsHi, u16* VsLo, u16* UHi, u16* ULo, u16* UsHi, u16* VHi,
                          u16* UdifH, u16* UdifL, u16* UssumH, u16* VssumH, u16* VssumL, u16* VdifH) {
  const int y = blockIdx.y;
  const size_t idx = (size_t)blockIdx.x * 256 + threadIdx.x;
  const size_t r = idx >> 10, c = idx & 1023;
  const size_t t0 = (size_t)y * 3 * DD;
  float t1 = T[t0 + idx], t2 = T[t0 + DD + idx], t3 = T[t0 + 2 * DD + idx];
  const size_t pr = (size_t)y * 2 * DD + idx, pi = pr + DD;
  float cre = 2.0f * (Xf32[pr] + (t1 - t2)) - (r == c ? 1.0f : 0.0f);
  float cim = 2.0f * (Xf32[pi] + (t3 - t1 - t2));
  if (y == 0) {
    u16 h = f2bf(cre); UHi[idx] = h; ULo[idx] = f2bf(cre - bf2f(h));
    h = f2bf(cim); UHi[DD + idx] = h; ULo[DD + idx] = f2bf(cim - bf2f(h));
    float d = cre - cim; h = f2bf(d); UdifH[idx] = h; UdifL[idx] = f2bf(d - bf2f(h));
    float s = expf(logsig[c]);
    UsHi[idx] = f2bf(cre * s); UsHi[DD + idx] = f2bf(cim * s);
    UssumH[idx] = f2bf((cre + cim) * s);
  } else {
    VHi[idx] = f2bf(cre); VHi[DD + idx] = f2bf(cim);
    VdifH[idx] = f2bf(cre - cim);
    float si = expf(-logsig[c]);
    float a = cre * si, b = cim * si;
    u16 h = f2bf(a); VsHi[idx] = h; VsLo[idx] = f2bf(a - bf2f(h));
    h = f2bf(b); VsHi[DD + idx] = h; VsLo[DD + idx] = f2bf(b - bf2f(h));
    float ss = (cre + cim) * si; h = f2bf(ss); VssumH[idx] = h; VssumL[idx] = f2bf(ss - bf2f(h));
  }
}

// Minv: re=T0+T1, im=T2-T0+T1 ; M: re=T3+T4, im=T5-T3+T4 (conj-Kara).
// MiRe/MiIm (adjacent -> N-stacked encode Bt) ; Mcat=[MRe|MIm] K-concat (final Bt) ;
// MiTc cat-K Bt for G (hi/lo) via LDS transpose.
__global__ void k_cmb_M(const float* T, u16* MiRe, u16* MiIm, u16* MiTcH, u16* MiTcL,
                        u16* Mcat) {
  __shared__ float ldsA[64][65], ldsB[64][65];
  const int tx = threadIdx.x & 15, ty = threadIdx.x >> 4;
  const int R0 = blockIdx.y * 64, C0 = blockIdx.x * 64;
#pragma unroll
  for (int i = 0; i < 4; ++i) {
    const size_t base = (size_t)(R0 + ty + i * 16) * Dd + C0 + tx * 4;
    const size_t r = R0 + ty + i * 16;
    float4v g1 = *(const float4v*)(T + base);
    float4v g2 = *(const float4v*)(T + DD + base);
    float4v g3 = *(const float4v*)(T + 2 * DD + base);
    float4v h1 = *(const float4v*)(T + 3 * DD + base);
    float4v h2 = *(const float4v*)(T + 4 * DD + base);
    float4v h3 = *(const float4v*)(T + 5 * DD + base);
    U64 pir, pii, pmr, pmi;
#pragma unroll
    for (int j = 0; j < 4; ++j) {
      float mire = g1[j] + g2[j];
      float miim = g3[j] - g1[j] + g2[j];
      float mre  = h1[j] + h2[j];
      float mim  = h3[j] - h1[j] + h2[j];
      pir.u[j] = f2bf(mire); pii.u[j] = f2bf(miim);
      pmr.u[j] = f2bf(mre);  pmi.u[j] = f2bf(mim);
      ldsA[ty + i * 16][tx * 4 + j] = mire;
      ldsB[ty + i * 16][tx * 4 + j] = miim;
    }
    *(unsigned long long*)(MiRe + base) = pir.v;
    *(unsigned long long*)(MiIm + base) = pii.v;
    const size_t mb = r * 2048 + C0 + tx * 4;
    *(unsigned long long*)(Mcat + mb) = pmr.v;
    *(unsigned long long*)(Mcat + mb + 1024) = pmi.v;
  }
  __syncthreads();
#pragma unroll
  for (int i = 0; i < 4; ++i) {
    const int cc = C0 + ty + i * 16;
    const size_t o = (size_t)cc * 2048 + R0 + tx * 4;
    U64 rh, rl, ih, il;
#pragma unroll
    for (int j = 0; j < 4; ++j) {
      float mire = ldsA[tx * 4 + j][ty + i * 16];
      float miim = ldsB[tx * 4 + j][ty + i * 16];
      u16 h = f2bf(mire); rh.u[j] = h; rl.u[j] = f2bf(mire - bf2f(h));
      h = f2bf(miim); ih.u[j] = h; il.u[j] = f2bf(miim - bf2f(h));
    }
    *(unsigned long long*)(MiTcH + o) = rh.v;
    *(unsigned long long*)(MiTcL + o) = rl.v;
    *(unsigned long long*)(MiTcH + o + 1024) = ih.v;
    *(unsigned long long*)(MiTcL + o + 1024) = il.v;
  }
}

__global__ void k_split(const float* src, u16* hi, u16* lo, size_t n) {
  const size_t idx = (size_t)blockIdx.x * 256 + threadIdx.x;
  if (idx >= n) return;
  float v = src[idx]; u16 h = f2bf(v); hi[idx] = h;
  if (lo) lo[idx] = f2bf(v - bf2f(h));
}

__global__ void k_splitB(const float* x, const float* hsrc, u16* xh, u16* xl, u16* hb) {
  const size_t i4 = (size_t)blockIdx.x * 256 + threadIdx.x;
  float4v xv = ((const float4v*)x)[i4];
  float4v hv = ((const float4v*)hsrc)[i4];
  U64 oh, ol, ob;
#pragma unroll
  for (int j = 0; j < 4; ++j) {
    u16 h = f2bf(xv[j]);
    oh.u[j] = h;
    ol.u[j] = f2bf(xv[j] - bf2f(h));
    ob.u[j] = f2bf(hv[j]);
  }
  ((unsigned long long*)xh)[i4] = oh.v;
  ((unsigned long long*)xl)[i4] = ol.v;
  ((unsigned long long*)hb)[i4] = ob.v;
}

// HtCat/XtCat layout: [b][0:1024]=Re, [b][1024:2048]=Im ; writes Hncat=[HnRe | imSign*HnIm]
__global__ void k_pointwise(const u16* HtCat, const u16* XtCat,
                            const float* delta, const float* dt, const float* ld, const float* lf,
                            const float* dts, const float* sre, const float* sim,
                            const float* lwre, const float* lwim, const float* selb,
                            u16* Hncat, float imSign) {
  const size_t idx = (size_t)blockIdx.x * 256 + threadIdx.x;  // < BD
  const int b = (int)(idx >> 10); const int c = (int)(idx & 1023);
  const size_t ro = (size_t)b * 2048 + c;
  float dre = delta[ro] + selb[c];
  float dim = delta[ro + 1024] + selb[1024 + c];
  float lamre = -expf(ld[c]) + lwre[c] + dre;
  float lamim = lf[c] + lwim[c] + dim;
  float dtv = dt[b];
  float dtn = dtv / dts[c];
  float zre = lamre * dtn, zim = lamim * dtn;
  float r2 = zre * zre + zim * zim;
  float er = expf(zre); float sn, cs; __sincosf(zim, &sn, &cs);
  float dcre = er * cs, dcim = er * sn;
  float p1re, p1im;
  if (r2 < 1e-8f) {
    p1re = 1.0f + 0.5f * zre + (zre * zre - zim * zim) * (1.0f / 6.0f);
    p1im = 0.5f * zim + (zre * zim) * (1.0f / 3.0f);
  } else {
    float inv = 1.0f / r2;
    float nre = dcre - 1.0f, nim = dcim;
    p1re = (nre * zre + nim * zim) * inv;
    p1im = (nim * zre - nre * zim) * inv;
  }
  float fre = p1re * dtv, fim = p1im * dtv;
  float hre = bf2f(HtCat[ro]), him = bf2f(HtCat[ro + 1024]);
  float xre = bf2f(XtCat[ro]) + sre[c], xim = bf2f(XtCat[ro + 1024]) + sim[c];
  float ore = hre * dcre - him * dcim + xre * fre - xim * fim;
  float oim = hre * dcim + him * dcre + xre * fim + xim * fre;
  Hncat[ro] = f2bf(ore); Hncat[ro + 1024] = f2bf(imSign * oim);
}

__global__ void k_fill(float* p, size_t n, float v) {
  const size_t idx = (size_t)blockIdx.x * 256 + threadIdx.x;
  if (idx < n) p[idx] = v;
}

// ---------------- host ----------------
static void launch_gemm(int mode, int out, int M, int N, int K, int lda, int ldb,
                        long ldc, int cstride, int nz, const ZP* z, hipStream_t s) {
  GArgs a; a.K = K; a.lda = lda; a.ldb = ldb; a.ldc = ldc; a.cstride = cstride;
  for (int i = 0; i < 8; ++i) a.z[i] = z[i < nz ? i : 0];
  dim3 g(N / 128, M / 128, nz), blk(256);
  if (mode == 1 && out == 0)      gemm_nt<1, 0><<<g, blk, 0, s>>>(a);
  else if (mode == 1 && out == 2) gemm_nt<1, 2><<<g, blk, 0, s>>>(a);
  else if (out == 1)              gemm_nt<0, 1><<<g, blk, 0, s>>>(a);
  else                            gemm_nt<0, 0><<<g, blk, 0, s>>>(a);
}

static void launch_gemm256(int out, int M, int N, int K, int lda, int ldb,
                           long ldc, int cstride, int nz, const ZP* z, hipStream_t s) {
  GArgs a; a.K = K; a.lda = lda; a.ldb = ldb; a.ldc = ldc; a.cstride = cstride;
  for (int i = 0; i < 8; ++i) a.z[i] = z[i < nz ? i : 0];
  dim3 g(N / 256, M / 256, nz), blk(512);
  if (out == 1) gemm_nt256<1><<<g, blk, 0, s>>>(a);
  else          gemm_nt256<0><<<g, blk, 0, s>>>(a);
}

extern "C" void kernel_launch(void* const* d_in, const int* in_sizes, int n_in,
                              void* d_out, int out_size, void* d_ws, size_t ws_size,
                              hipStream_t stream) {
  const float* h_prev  = (const float*)d_in[0];
  const float* x_input = (const float*)d_in[1];
  const float* dt      = (const float*)d_in[2];
  const float* ur      = (const float*)d_in[3];
  const float* ui      = (const float*)d_in[4];
  const float* vr      = (const float*)d_in[5];
  const float* vi      = (const float*)d_in[6];
  const float* logsig  = (const float*)d_in[7];
  const float* ld      = (const float*)d_in[8];
  const float* lf      = (const float*)d_in[9];
  const float* dts     = (const float*)d_in[10];
  const float* sre     = (const float*)d_in[11];
  const float* sim     = (const float*)d_in[12];
  const float* lwre    = (const float*)d_in[13];
  const float* lwim    = (const float*)d_in[14];
  const float* sel_w   = (const float*)d_in[15];
  const float* sel_b   = (const float*)d_in[16];
  float* out = (float*)d_out;
  char* ws = (char*)d_ws;

  const bool realOnly = ((size_t)out_size == BD);
  const bool interleaved = ((size_t)out_size == 2 * BD);
  if ((!realOnly && !interleaved) || ws_size < 224 * MBy) {
    k_fill<<<dim3(((size_t)out_size + 255) / 256), dim3(256), 0, stream>>>(out, (size_t)out_size, 1e9f);
    return;
  }

  // persistent region [0,16MB)
  u16* MiRe_b = (u16*)(ws + 0 * MBy);   // MiRe (2 MB) + MiIm (2 MB) ADJACENT (N-stacked Bt)
  u16* MiIm_b = (u16*)(ws + 2 * MBy);
  u16* Mcat   = (u16*)(ws + 4 * MBy);   // [1024][2048] = [MRe | MIm]
  u16* G_hi   = (u16*)(ws + 8 * MBy);
  u16* G_lo   = (u16*)(ws + 12 * MBy);
  char* AR = ws + 16 * MBy;  // arena
  // phase A
  float* Af32   = (float*)(AR + 0);
  u16* Ahi      = (u16*)(AR + 16 * MBy);
  u16* Alo      = (u16*)(AR + 24 * MBy);
  u16* AsumH    = (u16*)(AR + 32 * MBy);
  u16* AsumL    = (u16*)(AR + 36 * MBy);
  float* Xf32   = (float*)(AR + 40 * MBy);
  u16* Xhi      = (u16*)(AR + 56 * MBy);
  u16* Xlo      = (u16*)(AR + 64 * MBy);
  u16* XThi     = (u16*)(AR + 72 * MBy);
  u16* XTlo     = (u16*)(AR + 80 * MBy);
  u16* XsumH    = (u16*)(AR + 88 * MBy);
  u16* XTsumH   = (u16*)(AR + 92 * MBy);
  u16* XTsumL   = (u16*)(AR + 96 * MBy);
  u16* WThi     = (u16*)(AR + 100 * MBy);
  u16* WTsumH   = (u16*)(AR + 108 * MBy);
  float* T      = (float*)(AR + 112 * MBy);
  u16* VsHi     = (u16*)(AR + 136 * MBy);
  u16* VsLo     = (u16*)(AR + 140 * MBy);
  u16* UHi      = (u16*)(AR + 144 * MBy);
  u16* ULo      = (u16*)(AR + 148 * MBy);
  u16* UsHi     = (u16*)(AR + 152 * MBy);
  u16* VHi      = (u16*)(AR + 156 * MBy);
  u16* UdifH    = (u16*)(AR + 160 * MBy);
  u16* UdifL    = (u16*)(AR + 162 * MBy);
  u16* UssumH   = (u16*)(AR + 164 * MBy);
  u16* VssumH   = (u16*)(AR + 166 * MBy);
  u16* VssumL   = (u16*)(AR + 168 * MBy);
  u16* VdifH    = (u16*)(AR + 170 * MBy);
  u16* MiTcH    = (u16*)(AR + 172 * MBy);
  u16* MiTcL    = (u16*)(AR + 176 * MBy);
  u16* W_hi     = (u16*)(AR + 180 * MBy);
  u16* W_lo     = (u16*)(AR + 188 * MBy);
  // phase B (reuses arena)
  u16* Hb     = (u16*)(AR + 0);            // 16 MB
  u16* XbHi   = (u16*)(AR + 16 * MBy);     // 16
  u16* XbLo   = (u16*)(AR + 32 * MBy);     // 16
  u16* HtCat  = (u16*)(AR + 48 * MBy);     // 32 ([8192][2048])
  u16* XtCat  = (u16*)(AR + 80 * MBy);     // 32
  float* delta= (float*)(AR + 112 * MBy);  // 64 ([8192][2048] f32)
  u16* Hncat  = (u16*)(AR + 176 * MBy);    // 32 -> 208 end

  dim3 b256(256);
  const dim3 tdd(16, 16, 2);

  // ---- Phase A ----
  k_buildA<<<tdd, b256, 0, stream>>>(ur, ui, vr, vi, Af32, Ahi, Alo, AsumH, AsumL);

  {  // A^2: 3 products per y
    ZP z[6];
    for (int y = 0; y < 2; ++y) {
      const u16* are = Ahi + (size_t)y * 2 * DD; const u16* aim = are + DD;
      float* t = T + (size_t)y * 3 * DD;
      z[y*3+0] = {are, nullptr, are, nullptr, t,          nullptr, 1.f, 0.f};
      z[y*3+1] = {aim, nullptr, aim, nullptr, t + DD,     nullptr, 1.f, 0.f};
      z[y*3+2] = {are, nullptr, aim, nullptr, t + 2*DD,   nullptr, 1.f, 0.f};
    }
    launch_gemm(0, 0, 1024, 1024, 1024, 1024, 1024, 1024, 1, 6, z, stream);
  }
  k_x0<<<tdd, b256, 0, stream>>>(Af32, T, Xf32, Xhi, XThi, XsumH, XTsumH);

  for (int it = 0; it < 2; ++it) {
    {  // Q = A@X
      ZP z[6];
      for (int y = 0; y < 2; ++y) {
        const u16* are = Ahi + (size_t)y*2*DD; const u16* aim = are + DD;
        const u16* xtr = XThi + (size_t)y*2*DD; const u16* xti = xtr + DD;
        float* t = T + (size_t)y*3*DD;
        z[y*3+0] = {are, nullptr, xtr, nullptr, t,        nullptr, 1.f, 0.f};
        z[y*3+1] = {aim, nullptr, xti, nullptr, t + DD,   nullptr, 1.f, 0.f};
        z[y*3+2] = {AsumH + (size_t)y*DD, nullptr, XTsumH + (size_t)y*DD, nullptr, t + 2*DD, nullptr, 1.f, 0.f};
      }
      launch_gemm(0, 0, 1024, 1024, 1024, 1024, 1024, 1024, 1, 6, z, stream);
    }
    k_wt<<<tdd, b256, 0, stream>>>(Xf32, T, WThi, WTsumH, 2.0f);
    {  // X' = X@W
      ZP z[6];
      for (int y = 0; y < 2; ++y) {
        const u16* xre = Xhi + (size_t)y*2*DD; const u16* xim = xre + DD;
        const u16* wtr = WThi + (size_t)y*2*DD; const u16* wti = wtr + DD;
        float* t = T + (size_t)y*3*DD;
        z[y*3+0] = {xre, nullptr, wtr, nullptr, t,        nullptr, 1.f, 0.f};
        z[y*3+1] = {xim, nullptr, wti, nullptr, t + DD,   nullptr, 1.f, 0.f};
        z[y*3+2] = {XsumH + (size_t)y*DD, nullptr, WTsumH + (size_t)y*DD, nullptr, t + 2*DD, nullptr, 1.f, 0.f};
      }
      launch_gemm(0, 0, 1024, 1024, 1024, 1024, 1024, 1024, 1, 6, z, stream);
    }
    const bool last = (it == 1);
    k_xn<<<tdd, b256, 0, stream>>>(T, Xf32, Xhi, XThi, XsumH, XTsumH,
                                   last ? Xlo : nullptr, last ? XTlo : nullptr,
                                   last ? XTsumL : nullptr);
  }

  {  // refine: Q = A@X split precision (Kara)
    ZP z[6];
    for (int y = 0; y < 2; ++y) {
      const u16* areh = Ahi + (size_t)y*2*DD; const u16* aimh = areh + DD;
      const u16* arel = Alo + (size_t)y*2*DD; const u16* aiml = arel + DD;
      const u16* xtrh = XThi + (size_t)y*2*DD; const u16* xtih = xtrh + DD;
      const u16* xtrl = XTlo + (size_t)y*2*DD; const u16* xtil = xtrl + DD;
      float* t = T + (size_t)y*3*DD;
      z[y*3+0] = {areh, arel, xtrh, xtrl, t,        nullptr, 1.f, 0.f};
      z[y*3+1] = {aimh, aiml, xtih, xtil, t + DD,   nullptr, 1.f, 0.f};
      z[y*3+2] = {AsumH + (size_t)y*DD, AsumL + (size_t)y*DD,
                  XTsumH + (size_t)y*DD, XTsumL + (size_t)y*DD, t + 2*DD, nullptr, 1.f, 0.f};
    }
    launch_gemm(1, 0, 1024, 1024, 1024, 1024, 1024, 1024, 1, 6, z, stream);
  }
  k_wt<<<tdd, b256, 0, stream>>>(Xf32, T, WThi, WTsumH, 1.0f);
  {  // XR = X@R (plain, Kara)
    ZP z[6];
    for (int y = 0; y < 2; ++y) {
      const u16* xre = Xhi + (size_t)y*2*DD; const u16* xim = xre + DD;
      const u16* rtr = WThi + (size_t)y*2*DD; const u16* rti = rtr + DD;
      float* t = T + (size_t)y*3*DD;
      z[y*3+0] = {xre, nullptr, rtr, nullptr, t,        nullptr, 1.f, 0.f};
      z[y*3+1] = {xim, nullptr, rti, nullptr, t + DD,   nullptr, 1.f, 0.f};
      z[y*3+2] = {XsumH + (size_t)y*DD, nullptr, WTsumH + (size_t)y*DD, nullptr, t + 2*DD, nullptr, 1.f, 0.f};
    }
    launch_gemm(0, 0, 1024, 1024, 1024, 1024, 1024, 1024, 1, 6, z, stream);
  }
  k_finalUV<<<dim3(4096, 2), b256, 0, stream>>>(Xf32, T, logsig, VsHi, VsLo, UHi, ULo, UsHi, VHi,
                                                UdifH, UdifL, UssumH, VssumH, VssumL, VdifH);

  {  // Minv = (V s_inv) @ U^H : conj-Kara, split
    ZP z[3] = {
      {VsHi,      VsLo,      UHi,      ULo,      T,        nullptr, 1.f, 0.f},
      {VsHi + DD, VsLo + DD, UHi + DD, ULo + DD, T + DD,   nullptr, 1.f, 0.f},
      {VssumH,    VssumL,    UdifH,    UdifL,    T + 2*DD, nullptr, 1.f, 0.f}};
    launch_gemm(1, 0, 1024, 1024, 1024, 1024, 1024, 1024, 1, 3, z, stream);
  }
  {  // M = (U s) @ V^H : conj-Kara, plain
    ZP z[3] = {
      {UsHi,      nullptr, VHi,      nullptr, T + 3*DD, nullptr, 1.f, 0.f},
      {UsHi + DD, nullptr, VHi + DD, nullptr, T + 4*DD, nullptr, 1.f, 0.f},
      {UssumH,    nullptr, VdifH,    nullptr, T + 5*DD, nullptr, 1.f, 0.f}};
    launch_gemm(0, 0, 1024, 1024, 1024, 1024, 1024, 1024, 1, 3, z, stream);
  }
  k_cmb_M<<<dim3(16, 16), b256, 0, stream>>>(T, MiRe_b, MiIm_b, MiTcH, MiTcL, Mcat);

  // G = [W1|W2] @ [MiRe^T | MiIm^T]  (K=2048 split GEMM, split-pair output)
  k_split<<<dim3(16384), b256, 0, stream>>>(sel_w, W_hi, W_lo, (size_t)2048 * 2048);
  {
    ZP z1[1] = {{W_hi, W_lo, MiTcH, MiTcL, G_hi, G_lo, 1.f, 0.f}};
    launch_gemm(1, 2, 2048, 1024, 2048, 2048, 2048, 1024, 1, 1, z1, stream);
  }

  // ---- Phase B ----
  k_splitB<<<dim3(8192), b256, 0, stream>>>(x_input, h_prev, XbHi, XbLo, Hb);
  {  // encode: N-stacked Bt (MiRe|MiIm adjacent) -> HtCat/XtCat, z=2, 256^2 tile
    ZP z[2] = {
      {Hb,   nullptr, MiRe_b, nullptr, HtCat, nullptr, 1.f, 0.f},
      {XbHi, nullptr, MiRe_b, nullptr, XtCat, nullptr, 1.f, 0.f}};
    launch_gemm256(1, 8192, 2048, 1024, 1024, 1024, 2048, 1, 2, z, stream);
  }
  // delta = x @ G^T: split only for dt_n-large cols ([0,512) and [1024,1536))
  {  // split half (MODE1, now BK=32 / 2 blocks/CU)
    ZP z[2] = {
      {XbHi, XbLo, G_hi,                     G_lo,                     delta,        nullptr, 1.f, 0.f},
      {XbHi, XbLo, G_hi + 1024 * (size_t)Dd, G_lo + 1024 * (size_t)Dd, delta + 1024, nullptr, 1.f, 0.f}};
    launch_gemm(1, 0, 8192, 512, 1024, 1024, 1024, 2048, 1, 2, z, stream);
  }
  {  // plain half
    ZP z[2] = {
      {XbHi, nullptr, G_hi + 512 * (size_t)Dd,  nullptr, delta + 512,  nullptr, 1.f, 0.f},
      {XbHi, nullptr, G_hi + 1536 * (size_t)Dd, nullptr, delta + 1536, nullptr, 1.f, 0.f}};
    launch_gemm(0, 0, 8192, 512, 1024, 1024, 1024, 2048, 1, 2, z, stream);
  }

  if (realOnly) {
    // Hncat = [HnRe | -HnIm] ; out = Hncat @ Mcat^T (K=2048 concat, MODE0)
    k_pointwise<<<dim3(32768), b256, 0, stream>>>(HtCat, XtCat, delta, dt, ld, lf, dts,
                                                  sre, sim, lwre, lwim, sel_b, Hncat, -1.0f);
    ZP z1[1] = {{Hncat, nullptr, Mcat, nullptr, out, nullptr, 1.f, 0.f}};
    launch_gemm(0, 0, 8192, 1024, 2048, 2048, 2048, 1024, 1, 1, z1, stream);
  } else {
    k_pointwise<<<dim3(32768), b256, 0, stream>>>(HtCat, XtCat, delta, dt, ld, lf, dts,
                                                  sre, sim, lwre, lwim, sel_b, Hncat, -1.0f);
    {  // out_re = Hncat @ Mcat^T (K=2048), interleaved stride 2
      ZP z1[1] = {{Hncat, nullptr, Mcat, nullptr, out, nullptr, 1.f, 0.f}};
      launch_gemm(0, 0, 8192, 1024, 2048, 2048, 2048, 2048, 2, 1, z1, stream);
    }
    {  // out_im pass 1: HnRe @ MIm^T
      ZP z1[1] = {{Hncat, nullptr, Mcat + 1024, nullptr, out + 1, nullptr, 1.f, 0.f}};
      launch_gemm(0, 0, 8192, 1024, 1024, 2048, 2048, 2048, 2, 1, z1, stream);
    }
    {  // out_im pass 2: -(-HnIm) @ MRe^T (accumulate)
      ZP z1[1] = {{Hncat + 1024, nullptr, Mcat, nullptr, out + 1, nullptr, -1.f, 1.f}};
      launch_gemm(0, 0, 8192, 1024, 1024, 2048, 2048, 2048, 2, 1, z1, stream);
    }
  }
}

// Round 10
// 616.026 us; speedup vs baseline: 1.7332x; 1.0683x over previous
//
#include <hip/hip_runtime.h>
#include <hip/hip_bf16.h>

#define Dd 1024
#define Bb 8192

typedef unsigned short u16;
typedef __attribute__((ext_vector_type(8))) short short8;
typedef __attribute__((ext_vector_type(4))) float f32x4;
typedef __attribute__((ext_vector_type(4))) float float4v;

static constexpr size_t DD  = (size_t)Dd * Dd;   // 1M
static constexpr size_t BD  = (size_t)Bb * Dd;   // 8M
static constexpr size_t MBy = 1ull << 20;

__device__ __forceinline__ float bf2f(u16 v) {
  union { unsigned u; float f; } c; c.u = ((unsigned)v) << 16; return c.f;
}
__device__ __forceinline__ u16 f2bf(float f) {
  union { float f; unsigned u; } c; c.f = f;
  return (u16)((c.u + 0x7fffu + ((c.u >> 16) & 1u)) >> 16);
}

union U64 { u16 u[4]; unsigned long long v; };

// ---------------- NT GEMM: C[m][n] = alpha * sum_k A[m][k]*Bt[n][k] (+beta*C) ----------
// MODE 0: 1 MFMA (Ah*Bh), BK=64, 2 LDS arrays ; MODE 1: 3 MFMA split, BK=32, 4 arrays.
// Both: 32 KB/buffer, dbuf 64 KB -> 2 blocks/CU. OUT 0: f32(+beta) ; 1: bf16 ; 2: bf16 hi/lo.
struct ZP { const u16* Ah; const u16* Al; const u16* Bh; const u16* Bl; void* C; void* C2; float alpha; float beta; };
struct GArgs { ZP z[8]; int K, lda, ldb; long ldc; int cstride; };

template<int OUT>
__device__ __forceinline__ void c_store(const ZP& p, long cidx, float acc) {
  float v = acc * p.alpha;
  if constexpr (OUT == 1) {
    ((u16*)p.C)[cidx] = f2bf(v);
  } else if constexpr (OUT == 2) {
    u16 h = f2bf(v);
    ((u16*)p.C)[cidx] = h;
    ((u16*)p.C2)[cidx] = f2bf(v - bf2f(h));
  } else {
    float* C = (float*)p.C;
    if (p.beta != 0.0f) v += p.beta * C[cidx];
    C[cidx] = v;
  }
}

template<int MODE, int OUT>
__global__ __launch_bounds__(256) void gemm_nt(GArgs a) {
  constexpr bool X2 = (MODE != 0);
  constexpr int BK  = X2 ? 32 : 64;
  constexpr int BUFS = 16384;
  __shared__ __align__(16) u16 smem[2 * BUFS];
  const ZP p = a.z[blockIdx.z];
  const int tid  = threadIdx.x;
  const int lane = tid & 63, wv = tid >> 6;

  int bx = blockIdx.x, by = blockIdx.y;          // T1 XCD-chunked swizzle
  {
    const int gx = gridDim.x;
    const int nwg = gx * gridDim.y;
    if ((nwg & 7) == 0 && nwg >= 16) {
      const int flat = by * gx + bx;
      const int ch = nwg >> 3;
      const int nf = (flat & 7) * ch + (flat >> 3);
      bx = nf % gx; by = nf / gx;
    }
  }

  const long brow = (long)by * 128, bcol = (long)bx * 128;
  const int wm = (wv & 1) * 64, wn = (wv >> 1) * 64;
  const int srow = wv * 8 + (lane >> 3);
  const int sgc64 = ((lane & 7) ^ (lane >> 3)) * 8;
  const int sgc32 = ((tid & 3) ^ ((tid >> 3) & 3)) * 8;

  f32x4 acc[4][4];
#pragma unroll
  for (int i = 0; i < 4; ++i)
#pragma unroll
    for (int j = 0; j < 4; ++j) { f32x4 zv = {0.f, 0.f, 0.f, 0.f}; acc[i][j] = zv; }

  auto STAGE = [&](int kt, int buf) {
    u16* base = smem + buf * BUFS;
    if constexpr (!X2) {
      u16* As = base;
      u16* Bs = base + 8192;
#pragma unroll
      for (int i = 0; i < 4; ++i) {
        const int rr = i * 32 + srow;
        const int lb = (i * 32 + wv * 8) * 64;
        const u16* ga = p.Ah + (brow + rr) * (long)a.lda + kt + sgc64;
        const u16* gb = p.Bh + (bcol + rr) * (long)a.ldb + kt + sgc64;
        __builtin_amdgcn_global_load_lds((const __attribute__((address_space(1))) void*)ga,
                                         (__attribute__((address_space(3))) void*)(As + lb), 16, 0, 0);
        __builtin_amdgcn_global_load_lds((const __attribute__((address_space(1))) void*)gb,
                                         (__attribute__((address_space(3))) void*)(Bs + lb), 16, 0, 0);
      }
    } else {
#pragma unroll
      for (int pass = 0; pass < 2; ++pass) {
        const int row = pass * 64 + (tid >> 2);
        const int lb = pass * 2048 + tid * 8;
        const u16* ga = p.Ah + (brow + row) * (long)a.lda + kt + sgc32;
        const u16* gb = p.Bh + (bcol + row) * (long)a.ldb + kt + sgc32;
        const u16* ga2 = p.Al + (brow + row) * (long)a.lda + kt + sgc32;
        const u16* gb2 = p.Bl + (bcol + row) * (long)a.ldb + kt + sgc32;
        __builtin_amdgcn_global_load_lds((const __attribute__((address_space(1))) void*)ga,
                                         (__attribute__((address_space(3))) void*)(base + lb), 16, 0, 0);
        __builtin_amdgcn_global_load_lds((const __attribute__((address_space(1))) void*)gb,
                                         (__attribute__((address_space(3))) void*)(base + 4096 + lb), 16, 0, 0);
        __builtin_amdgcn_global_load_lds((const __attribute__((address_space(1))) void*)ga2,
                                         (__attribute__((address_space(3))) void*)(base + 8192 + lb), 16, 0, 0);
        __builtin_amdgcn_global_load_lds((const __attribute__((address_space(1))) void*)gb2,
                                         (__attribute__((address_space(3))) void*)(base + 12288 + lb), 16, 0, 0);
      }
    }
  };

  auto COMPUTE = [&](int buf) {
    u16* base = smem + buf * BUFS;
    if constexpr (!X2) {
      u16* As = base;
      u16* Bs = base + 8192;
#pragma unroll
      for (int kk = 0; kk < 64; kk += 32) {
        const int jf = (kk >> 3) + (lane >> 4);
        const int cs = ((jf ^ (lane & 7)) << 3);
        short8 af[4], bfv[4];
#pragma unroll
        for (int i = 0; i < 4; ++i) {
          af[i]  = *(const short8*)(As + (wm + i * 16 + (lane & 15)) * 64 + cs);
          bfv[i] = *(const short8*)(Bs + (wn + i * 16 + (lane & 15)) * 64 + cs);
        }
#pragma unroll
        for (int i = 0; i < 4; ++i)
#pragma unroll
          for (int j = 0; j < 4; ++j)
            acc[i][j] = __builtin_amdgcn_mfma_f32_16x16x32_bf16(af[i], bfv[j], acc[i][j], 0, 0, 0);
      }
    } else {
      const int jf = lane >> 4;
      const int cs = ((jf ^ ((lane >> 1) & 3)) << 3);
      short8 af[4], bfv[4], al[4], bl[4];
#pragma unroll
      for (int i = 0; i < 4; ++i) {
        const int ra = (wm + i * 16 + (lane & 15)) * 32 + cs;
        const int rb = (wn + i * 16 + (lane & 15)) * 32 + cs;
        af[i]  = *(const short8*)(base + ra);
        bfv[i] = *(const short8*)(base + 4096 + rb);
        al[i]  = *(const short8*)(base + 8192 + ra);
        bl[i]  = *(const short8*)(base + 12288 + rb);
      }
#pragma unroll
      for (int i = 0; i < 4; ++i)
#pragma unroll
        for (int j = 0; j < 4; ++j) {
          acc[i][j] = __builtin_amdgcn_mfma_f32_16x16x32_bf16(af[i], bfv[j], acc[i][j], 0, 0, 0);
          acc[i][j] = __builtin_amdgcn_mfma_f32_16x16x32_bf16(al[i], bfv[j], acc[i][j], 0, 0, 0);
          acc[i][j] = __builtin_amdgcn_mfma_f32_16x16x32_bf16(af[i], bl[j], acc[i][j], 0, 0, 0);
        }
    }
  };

  const int nkt = a.K / BK;
  STAGE(0, 0);
  __syncthreads();
  int cur = 0;
  for (int t = 0; t < nkt - 1; ++t) {
    STAGE((t + 1) * BK, cur ^ 1);
    COMPUTE(cur);
    __syncthreads();
    cur ^= 1;
  }
  COMPUTE(cur);

  const long crow = brow + wm + ((lane >> 4) * 4);
  const long ccol = bcol + wn + (lane & 15);
#pragma unroll
  for (int i = 0; i < 4; ++i)
#pragma unroll
    for (int j = 0; j < 4; ++j)
#pragma unroll
      for (int r = 0; r < 4; ++r) {
        const long cidx = (crow + i * 16 + r) * a.ldc + (ccol + j * 16) * (long)a.cstride;
        c_store<OUT>(p, cidx, acc[i][j][r]);
      }
}

// ---- 256x256-tile MODE0 GEMM (8 waves / 512 thr) ----
template<int OUT>
__global__ __launch_bounds__(512, 1) void gemm_nt256(GArgs a) {
  constexpr int BUFS = 32768;
  __shared__ __align__(16) u16 smem[2 * BUFS];
  const ZP p = a.z[blockIdx.z];
  const int tid  = threadIdx.x;
  const int lane = tid & 63, wv = tid >> 6;
  const int wr = wv >> 2, wc = wv & 3;

  int bx = blockIdx.x, by = blockIdx.y;
  {
    const int gx = gridDim.x;
    const int nwg = gx * gridDim.y;
    if ((nwg & 7) == 0 && nwg >= 16) {
      const int flat = by * gx + bx;
      const int ch = nwg >> 3;
      const int nf = (flat & 7) * ch + (flat >> 3);
      bx = nf % gx; by = nf / gx;
    }
  }

  const long brow = (long)by * 256, bcol = (long)bx * 256;
  const int sgc = ((tid & 7) ^ ((tid >> 3) & 7)) * 8;

  f32x4 acc[8][4];
#pragma unroll
  for (int i = 0; i < 8; ++i)
#pragma unroll
    for (int j = 0; j < 4; ++j) { f32x4 zv = {0.f, 0.f, 0.f, 0.f}; acc[i][j] = zv; }

  auto STAGE = [&](int kt, int buf) {
    u16* As = smem + buf * BUFS;
    u16* Bs = As + 16384;
#pragma unroll
    for (int i = 0; i < 4; ++i) {
      const int rr = i * 64 + (tid >> 3);
      const int lb = i * 4096 + tid * 8;
      const u16* ga = p.Ah + (brow + rr) * (long)a.lda + kt + sgc;
      const u16* gb = p.Bh + (bcol + rr) * (long)a.ldb + kt + sgc;
      __builtin_amdgcn_global_load_lds((const __attribute__((address_space(1))) void*)ga,
                                       (__attribute__((address_space(3))) void*)(As + lb), 16, 0, 0);
      __builtin_amdgcn_global_load_lds((const __attribute__((address_space(1))) void*)gb,
                                       (__attribute__((address_space(3))) void*)(Bs + lb), 16, 0, 0);
    }
  };

  auto COMPUTE = [&](int buf) {
    u16* As = smem + buf * BUFS;
    u16* Bs = As + 16384;
#pragma unroll
    for (int kk = 0; kk < 64; kk += 32) {
      const int jf = (kk >> 3) + (lane >> 4);
      const int cs = ((jf ^ (lane & 7)) << 3);
      short8 af[8], bfv[4];
#pragma unroll
      for (int i = 0; i < 8; ++i)
        af[i] = *(const short8*)(As + (wr * 128 + i * 16 + (lane & 15)) * 64 + cs);
#pragma unroll
      for (int j = 0; j < 4; ++j)
        bfv[j] = *(const short8*)(Bs + (wc * 64 + j * 16 + (lane & 15)) * 64 + cs);
#pragma unroll
      for (int i = 0; i < 8; ++i)
#pragma unroll
        for (int j = 0; j < 4; ++j)
          acc[i][j] = __builtin_amdgcn_mfma_f32_16x16x32_bf16(af[i], bfv[j], acc[i][j], 0, 0, 0);
    }
  };

  const int nkt = a.K >> 6;
  STAGE(0, 0);
  __syncthreads();
  int cur = 0;
  for (int t = 0; t < nkt - 1; ++t) {
    STAGE((t + 1) * 64, cur ^ 1);
    COMPUTE(cur);
    __syncthreads();
    cur ^= 1;
  }
  COMPUTE(cur);

  const long crow = brow + wr * 128 + ((lane >> 4) * 4);
  const long ccol = bcol + wc * 64 + (lane & 15);
#pragma unroll
  for (int i = 0; i < 8; ++i)
#pragma unroll
    for (int j = 0; j < 4; ++j)
#pragma unroll
      for (int r = 0; r < 4; ++r) {
        const long cidx = (crow + i * 16 + r) * a.ldc + (ccol + j * 16) * (long)a.cstride;
        c_store<OUT>(p, cidx, acc[i][j][r]);
      }
}

// ---------------- elementwise kernels (64x64 LDS-tile, coalesced) ----------------
#define TLOAD(ldsbuf, srcp) do { \
  _Pragma("unroll") \
  for (int i_ = 0; i_ < 4; ++i_) { \
    int row_ = ty + i_ * 16; \
    float4v v_ = *(const float4v*)((srcp) + (size_t)row_ * Dd + tx * 4); \
    ldsbuf[row_][tx * 4 + 0] = v_[0]; ldsbuf[row_][tx * 4 + 1] = v_[1]; \
    ldsbuf[row_][tx * 4 + 2] = v_[2]; ldsbuf[row_][tx * 4 + 3] = v_[3]; \
  } } while (0)

__global__ void k_buildA(const float* ur, const float* ui, const float* vr, const float* vi,
                         float* Af32, u16* Ahi, u16* Alo, u16* AsumH, u16* AsumL) {
  __shared__ float ldsA[64][65], ldsB[64][65];
  const int y = blockIdx.z;
  const int tx = threadIdx.x & 15, ty = threadIdx.x >> 4;
  const int R0 = blockIdx.y * 64, C0 = blockIdx.x * 64;
  const float* re = y ? vr : ur; const float* im = y ? vi : ui;
  TLOAD(ldsA, re + (size_t)C0 * Dd + R0);
  TLOAD(ldsB, im + (size_t)C0 * Dd + R0);
  __syncthreads();
#pragma unroll
  for (int i = 0; i < 4; ++i) {
    const int r = R0 + ty + i * 16;
    const size_t base = (size_t)r * Dd + C0 + tx * 4;
    float4v vre = *(const float4v*)(re + base);
    float4v vim = *(const float4v*)(im + base);
    float4v oar, oai;
    U64 ph, pl, pih, pil, sh, sl;
#pragma unroll
    for (int j = 0; j < 4; ++j) {
      float are = 0.5f * (vre[j] - ldsA[tx * 4 + j][ty + i * 16]);
      float aim = 0.5f * (vim[j] + ldsB[tx * 4 + j][ty + i * 16]);
      oar[j] = are; oai[j] = aim;
      u16 h = f2bf(are); ph.u[j] = h; pl.u[j] = f2bf(are - bf2f(h));
      h = f2bf(aim); pih.u[j] = h; pil.u[j] = f2bf(aim - bf2f(h));
      float s = are + aim; h = f2bf(s); sh.u[j] = h; sl.u[j] = f2bf(s - bf2f(h));
    }
    const size_t pr = (size_t)y * 2 * DD + base, pi = pr + DD;
    *(float4v*)(Af32 + pr) = oar; *(float4v*)(Af32 + pi) = oai;
    *(unsigned long long*)(Ahi + pr) = ph.v; *(unsigned long long*)(Alo + pr) = pl.v;
    *(unsigned long long*)(Ahi + pi) = pih.v; *(unsigned long long*)(Alo + pi) = pil.v;
    const size_t ps = (size_t)y * DD + base;
    *(unsigned long long*)(AsumH + ps) = sh.v; *(unsigned long long*)(AsumL + ps) = sl.v;
  }
}

// A^2 combine from T products {are@are, aim@aim, are@aim}:
// a2re = -T0-T1 ; a2im = T2 - T2^T. Emits A2 f32 (row, per-y ptr) + A2T/A2Tsum (transposed bf16).
__global__ void k_sq(const float* T, float* A2u, float* A2v, u16* A2T, u16* A2Tsum) {
  __shared__ float ldsA[64][65], ldsB[64][65];
  const int y = blockIdx.z;
  const int tx = threadIdx.x & 15, ty = threadIdx.x >> 4;
  const int R0 = blockIdx.y * 64, C0 = blockIdx.x * 64;
  const float* t0p = T + (size_t)y * 3 * DD;
  const float* t2p = t0p + 2 * DD;
  TLOAD(ldsA, t2p + (size_t)C0 * Dd + R0);  // (are@aim)^T block
  __syncthreads();
  float* A2 = y ? A2v : A2u;
  float xr[4][4], xi[4][4];
#pragma unroll
  for (int i = 0; i < 4; ++i) {
    const size_t base = (size_t)(R0 + ty + i * 16) * Dd + C0 + tx * 4;
    float4v v0 = *(const float4v*)(t0p + base);
    float4v v1 = *(const float4v*)(t0p + DD + base);
    float4v v2 = *(const float4v*)(t2p + base);
    float4v oar, oai;
#pragma unroll
    for (int j = 0; j < 4; ++j) {
      float a2re = -v0[j] - v1[j];
      float a2im = v2[j] - ldsA[tx * 4 + j][ty + i * 16];
      xr[i][j] = a2re; xi[i][j] = a2im;
      oar[j] = a2re; oai[j] = a2im;
    }
    *(float4v*)(A2 + base) = oar;
    *(float4v*)(A2 + DD + base) = oai;
  }
  __syncthreads();
#pragma unroll
  for (int i = 0; i < 4; ++i)
#pragma unroll
    for (int j = 0; j < 4; ++j) {
      ldsA[ty + i * 16][tx * 4 + j] = xr[i][j];
      ldsB[ty + i * 16][tx * 4 + j] = xi[i][j];
    }
  __syncthreads();
#pragma unroll
  for (int i = 0; i < 4; ++i) {
    const int cc = C0 + ty + i * 16;
    const size_t tb = (size_t)cc * Dd + R0 + tx * 4;
    U64 ph, pih, sh;
#pragma unroll
    for (int j = 0; j < 4; ++j) {
      float a2re = ldsA[tx * 4 + j][ty + i * 16];
      float a2im = ldsB[tx * 4 + j][ty + i * 16];
      ph.u[j] = f2bf(a2re); pih.u[j] = f2bf(a2im);
      sh.u[j] = f2bf(a2re + a2im);
    }
    const size_t qr = (size_t)y * 2 * DD + tb;
    *(unsigned long long*)(A2T + qr) = ph.v;
    *(unsigned long long*)(A2T + qr + DD) = pih.v;
    *(unsigned long long*)(A2Tsum + (size_t)y * DD + tb) = sh.v;
  }
}

// X0 = I + A + A^2 + A^3 ; A^3 Kara: re = T0-T1, im = T2-T0-T1. Emits X planes + XT planes.
__global__ void k_x0n(const float* Af32, const float* A2u, const float* A2v, const float* T,
                      float* Xf32, u16* Xhi, u16* XThi, u16* XsumH, u16* XTsumH) {
  __shared__ float ldsA[64][65], ldsB[64][65];
  const int y = blockIdx.z;
  const int tx = threadIdx.x & 15, ty = threadIdx.x >> 4;
  const int R0 = blockIdx.y * 64, C0 = blockIdx.x * 64;
  const float* t0p = T + (size_t)y * 3 * DD;
  const float* A2 = y ? A2v : A2u;
  float xr[4][4], xi[4][4];
#pragma unroll
  for (int i = 0; i < 4; ++i) {
    const int r = R0 + ty + i * 16;
    const size_t base = (size_t)r * Dd + C0 + tx * 4;
    float4v v0 = *(const float4v*)(t0p + base);
    float4v v1 = *(const float4v*)(t0p + DD + base);
    float4v v2 = *(const float4v*)(t0p + 2 * DD + base);
    const size_t pr = (size_t)y * 2 * DD + base, pi = pr + DD;
    float4v ar = *(const float4v*)(Af32 + pr);
    float4v ai = *(const float4v*)(Af32 + pi);
    float4v a2r = *(const float4v*)(A2 + base);
    float4v a2i = *(const float4v*)(A2 + DD + base);
    float4v oxr, oxi;
    U64 ph, pih, sh;
#pragma unroll
    for (int j = 0; j < 4; ++j) {
      const int c = C0 + tx * 4 + j;
      float xre = ar[j] + a2r[j] + (v0[j] - v1[j]) + (r == c ? 1.0f : 0.0f);
      float xim = ai[j] + a2i[j] + (v2[j] - v0[j] - v1[j]);
      xr[i][j] = xre; xi[i][j] = xim;
      oxr[j] = xre; oxi[j] = xim;
      ph.u[j] = f2bf(xre); pih.u[j] = f2bf(xim);
      sh.u[j] = f2bf(xre + xim);
    }
    *(float4v*)(Xf32 + pr) = oxr; *(float4v*)(Xf32 + pi) = oxi;
    *(unsigned long long*)(Xhi + pr) = ph.v; *(unsigned long long*)(Xhi + pi) = pih.v;
    *(unsigned long long*)(XsumH + (size_t)y * DD + base) = sh.v;
  }
  __syncthreads();
#pragma unroll
  for (int i = 0; i < 4; ++i)
#pragma unroll
    for (int j = 0; j < 4; ++j) {
      ldsA[ty + i * 16][tx * 4 + j] = xr[i][j];
      ldsB[ty + i * 16][tx * 4 + j] = xi[i][j];
    }
  __syncthreads();
#pragma unroll
  for (int i = 0; i < 4; ++i) {
    const int cc = C0 + ty + i * 16;
    const size_t tb = (size_t)cc * Dd + R0 + tx * 4;
    U64 ph, pih, sh;
#pragma unroll
    for (int j = 0; j < 4; ++j) {
      float xre = ldsA[tx * 4 + j][ty + i * 16];
      float xim = ldsB[tx * 4 + j][ty + i * 16];
      ph.u[j] = f2bf(xre); pih.u[j] = f2bf(xim);
      sh.u[j] = f2bf(xre + xim);
    }
    const size_t qr = (size_t)y * 2 * DD + tb;
    *(unsigned long long*)(XThi + qr) = ph.v;
    *(unsigned long long*)(XThi + qr + DD) = pih.v;
    *(unsigned long long*)(XTsumH + (size_t)y * DD + tb) = sh.v;
  }
}

__global__ void k_wt(const float* Xf32, const float* T, u16* WThi, u16* WTsumH, float idc) {
  __shared__ float lds[64][65];
  const int y = blockIdx.z;
  const int tx = threadIdx.x & 15, ty = threadIdx.x >> 4;
  const int N0 = blockIdx.y * 64, K0 = blockIdx.x * 64;
  const float* t1p = T + (size_t)y * 3 * DD;
  const float* xrp = Xf32 + (size_t)y * 2 * DD;
  float wre[4][4], wim[4][4];
#pragma unroll
  for (int i = 0; i < 4; ++i)
#pragma unroll
    for (int j = 0; j < 4; ++j) {
      wre[i][j] = ((N0 + ty + i * 16) == (K0 + tx * 4 + j)) ? idc : 0.0f;
      wim[i][j] = 0.0f;
    }
  const float* planes[5] = {t1p, t1p + DD, t1p + 2 * DD, xrp, xrp + DD};
#pragma unroll
  for (int p = 0; p < 5; ++p) {
    TLOAD(lds, planes[p] + (size_t)K0 * Dd + N0);
    __syncthreads();
#pragma unroll
    for (int i = 0; i < 4; ++i)
#pragma unroll
      for (int j = 0; j < 4; ++j) {
        float v = lds[tx * 4 + j][ty + i * 16];
        if (p == 0) { wre[i][j] += v; wim[i][j] -= v; }
        else if (p == 1) { wre[i][j] -= v; wim[i][j] -= v; }
        else if (p == 2) { wim[i][j] += v; }
        else if (p == 3) { wre[i][j] -= v; }
        else { wim[i][j] -= v; }
      }
    __syncthreads();
  }
#pragma unroll
  for (int i = 0; i < 4; ++i) {
    const size_t base = (size_t)(N0 + ty + i * 16) * Dd + K0 + tx * 4;
    U64 ph, pih, sh;
#pragma unroll
    for (int j = 0; j < 4; ++j) {
      ph.u[j] = f2bf(wre[i][j]); pih.u[j] = f2bf(wim[i][j]);
      sh.u[j] = f2bf(wre[i][j] + wim[i][j]);
    }
    const size_t pr = (size_t)y * 2 * DD + base;
    *(unsigned long long*)(WThi + pr) = ph.v;
    *(unsigned long long*)(WThi + pr + DD) = pih.v;
    *(unsigned long long*)(WTsumH + (size_t)y * DD + base) = sh.v;
  }
}

__global__ void k_xn(const float* T, float* Xf32, u16* Xhi, u16* XThi, u16* XsumH, u16* XTsumH,
                     u16* Xlo, u16* XTlo, u16* XTsumL) {
  __shared__ float ldsA[64][65], ldsB[64][65];
  const int y = blockIdx.z;
  const int tx = threadIdx.x & 15, ty = threadIdx.x >> 4;
  const int R0 = blockIdx.y * 64, C0 = blockIdx.x * 64;
  const float* t1p = T + (size_t)y * 3 * DD;
  float xr[4][4], xi[4][4];
#pragma unroll
  for (int i = 0; i < 4; ++i) {
    const size_t base = (size_t)(R0 + ty + i * 16) * Dd + C0 + tx * 4;
    float4v v1 = *(const float4v*)(t1p + base);
    float4v v2 = *(const float4v*)(t1p + DD + base);
    float4v v3 = *(const float4v*)(t1p + 2 * DD + base);
    float4v oxr, oxi;
    U64 ph, pih, sh, plr, pli;
#pragma unroll
    for (int j = 0; j < 4; ++j) {
      float xre = v1[j] - v2[j];
      float xim = v3[j] - v1[j] - v2[j];
      xr[i][j] = xre; xi[i][j] = xim;
      oxr[j] = xre; oxi[j] = xim;
      u16 hr = f2bf(xre), hi_ = f2bf(xim);
      ph.u[j] = hr; pih.u[j] = hi_;
      sh.u[j] = f2bf(xre + xim);
      plr.u[j] = f2bf(xre - bf2f(hr)); pli.u[j] = f2bf(xim - bf2f(hi_));
    }
    const size_t pr = (size_t)y * 2 * DD + base, pi = pr + DD;
    *(float4v*)(Xf32 + pr) = oxr; *(float4v*)(Xf32 + pi) = oxi;
    *(unsigned long long*)(Xhi + pr) = ph.v; *(unsigned long long*)(Xhi + pi) = pih.v;
    *(unsigned long long*)(XsumH + (size_t)y * DD + base) = sh.v;
    if (Xlo) {
      *(unsigned long long*)(Xlo + pr) = plr.v;
      *(unsigned long long*)(Xlo + pi) = pli.v;
    }
  }
  __syncthreads();
#pragma unroll
  for (int i = 0; i < 4; ++i)
#pragma unroll
    for (int j = 0; j < 4; ++j) {
      ldsA[ty + i * 16][tx * 4 + j] = xr[i][j];
      ldsB[ty + i * 16][tx * 4 + j] = xi[i][j];
    }
  __syncthreads();
#pragma unroll
  for (int i = 0; i < 4; ++i) {
    const int cc = C0 + ty + i * 16;
    const size_t tb = (size_t)cc * Dd + R0 + tx * 4;
    U64 ph, pih, sh, plr, pli, sl;
#pragma unroll
    for (int j = 0; j < 4; ++j) {
      float xre = ldsA[tx * 4 + j][ty + i * 16];
      float xim = ldsB[tx * 4 + j][ty + i * 16];
      u16 hr = f2bf(xre), hi_ = f2bf(xim);
      ph.u[j] = hr; pih.u[j] = hi_;
      float s = xre + xim; u16 hs = f2bf(s);
      sh.u[j] = hs;
      plr.u[j] = f2bf(xre - bf2f(hr)); pli.u[j] = f2bf(xim - bf2f(hi_));
      sl.u[j] = f2bf(s - bf2f(hs));
    }
    const size_t qr = (size_t)y * 2 * DD + tb;
    *(unsigned long long*)(XThi + qr) = ph.v;
    *(unsigned long long*)(XThi + qr + DD) = pih.v;
    *(unsigned long long*)(XTsumH + (size_t)y * DD + tb) = sh.v;
    if (Xlo) {
      *(unsigned long long*)(XTlo + qr) = plr.v;
      *(unsigned long long*)(XTlo + qr + DD) = pli.v;
      *(unsigned long long*)(XTsumL + (size_t)y * DD + tb) = sl.v;
    }
  }
}

__global__ void k_finalUV(const float* Xf32, const float* T, const float* logsig,
                          u16* VsHi, u16* VsLo, u16* UHi, u16* ULo, u16* UsHi, u16* VHi,
                          u16* UdifH, u16* UdifL, u16* UssumH, u16* VssumH, u16* VssumL, u16* VdifH) {
  const int y = blockIdx.y;
  const size_t idx = (size_t)blockIdx.x * 256 + threadIdx.x;
  const size_t r = idx >> 10, c = idx & 1023;
  const size_t t0 = (size_t)y * 3 * DD;
  float t1 = T[t0 + idx], t2 = T[t0 + DD + idx], t3 = T[t0 + 2 * DD + idx];
  const size_t pr = (size_t)y * 2 * DD + idx, pi = pr + DD;
  float cre = 2.0f * (Xf32[pr] + (t1 - t2)) - (r == c ? 1.0f : 0.0f);
  float cim = 2.0f * (Xf32[pi] + (t3 - t1 - t2));
  if (y == 0) {
    u16 h = f2bf(cre); UHi[idx] = h; ULo[idx] = f2bf(cre - bf2f(h));
    h = f2bf(cim); UHi[DD + idx] = h; ULo[DD + idx] = f2bf(cim - bf2f(h));
    float d = cre - cim; h = f2bf(d); UdifH[idx] = h; UdifL[idx] = f2bf(d - bf2f(h));
    float s = expf(logsig[c]);
    UsHi[idx] = f2bf(cre * s); UsHi[DD + idx] = f2bf(cim * s);
    UssumH[idx] = f2bf((cre + cim) * s);
  } else {
    VHi[idx] = f2bf(cre); VHi[DD + idx] = f2bf(cim);
    VdifH[idx] = f2bf(cre - cim);
    float si = expf(-logsig[c]);
    float a = cre * si, b = cim * si;
    u16 h = f2bf(a); VsHi[idx] = h; VsLo[idx] = f2bf(a - bf2f(h));
    h = f2bf(b); VsHi[DD + idx] = h; VsLo[DD + idx] = f2bf(b - bf2f(h));
    float ss = (cre + cim) * si; h = f2bf(ss); VssumH[idx] = h; VssumL[idx] = f2bf(ss - bf2f(h));
  }
}

__global__ void k_cmb_M(const float* T, u16* MiRe, u16* MiIm, u16* MiTcH, u16* MiTcL,
                        u16* Mcat) {
  __shared__ float ldsA[64][65], ldsB[64][65];
  const int tx = threadIdx.x & 15, ty = threadIdx.x >> 4;
  const int R0 = blockIdx.y * 64, C0 = blockIdx.x * 64;
#pragma unroll
  for (int i = 0; i < 4; ++i) {
    const size_t base = (size_t)(R0 + ty + i * 16) * Dd + C0 + tx * 4;
    const size_t r = R0 + ty + i * 16;
    float4v g1 = *(const float4v*)(T + base);
    float4v g2 = *(const float4v*)(T + DD + base);
    float4v g3 = *(const float4v*)(T + 2 * DD + base);
    float4v h1 = *(const float4v*)(T + 3 * DD + base);
    float4v h2 = *(const float4v*)(T + 4 * DD + base);
    float4v h3 = *(const float4v*)(T + 5 * DD + base);
    U64 pir, pii, pmr, pmi;
#pragma unroll
    for (int j = 0; j < 4; ++j) {
      float mire = g1[j] + g2[j];
      float miim = g3[j] - g1[j] + g2[j];
      float mre  = h1[j] + h2[j];
      float mim  = h3[j] - h1[j] + h2[j];
      pir.u[j] = f2bf(mire); pii.u[j] = f2bf(miim);
      pmr.u[j] = f2bf(mre);  pmi.u[j] = f2bf(mim);
      ldsA[ty + i * 16][tx * 4 + j] = mire;
      ldsB[ty + i * 16][tx * 4 + j] = miim;
    }
    *(unsigned long long*)(MiRe + base) = pir.v;
    *(unsigned long long*)(MiIm + base) = pii.v;
    const size_t mb = r * 2048 + C0 + tx * 4;
    *(unsigned long long*)(Mcat + mb) = pmr.v;
    *(unsigned long long*)(Mcat + mb + 1024) = pmi.v;
  }
  __syncthreads();
#pragma unroll
  for (int i = 0; i < 4; ++i) {
    const int cc = C0 + ty + i * 16;
    const size_t o = (size_t)cc * 2048 + R0 + tx * 4;
    U64 rh, rl, ih, il;
#pragma unroll
    for (int j = 0; j < 4; ++j) {
      float mire = ldsA[tx * 4 + j][ty + i * 16];
      float miim = ldsB[tx * 4 + j][ty + i * 16];
      u16 h = f2bf(mire); rh.u[j] = h; rl.u[j] = f2bf(mire - bf2f(h));
      h = f2bf(miim); ih.u[j] = h; il.u[j] = f2bf(miim - bf2f(h));
    }
    *(unsigned long long*)(MiTcH + o) = rh.v;
    *(unsigned long long*)(MiTcL + o) = rl.v;
    *(unsigned long long*)(MiTcH + o + 1024) = ih.v;
    *(unsigned long long*)(MiTcL + o + 1024) = il.v;
  }
}

// vectorized x4 split (n multiple of 1024)
__global__ void k_split4(const float* src, u16* hi, u16* lo) {
  const size_t i4 = (size_t)blockIdx.x * 256 + threadIdx.x;
  float4v v = ((const float4v*)src)[i4];
  U64 oh, ol;
#pragma unroll
  for (int j = 0; j < 4; ++j) {
    u16 h = f2bf(v[j]);
    oh.u[j] = h; ol.u[j] = f2bf(v[j] - bf2f(h));
  }
  ((unsigned long long*)hi)[i4] = oh.v;
  ((unsigned long long*)lo)[i4] = ol.v;
}

__global__ void k_splitB(const float* x, const float* hsrc, u16* xh, u16* xl, u16* hb) {
  const size_t i4 = (size_t)blockIdx.x * 256 + threadIdx.x;
  float4v xv = ((const float4v*)x)[i4];
  float4v hv = ((const float4v*)hsrc)[i4];
  U64 oh, ol, ob;
#pragma unroll
  for (int j = 0; j < 4; ++j) {
    u16 h = f2bf(xv[j]);
    oh.u[j] = h;
    ol.u[j] = f2bf(xv[j] - bf2f(h));
    ob.u[j] = f2bf(hv[j]);
  }
  ((unsigned long long*)xh)[i4] = oh.v;
  ((unsigned long long*)xl)[i4] = ol.v;
  ((unsigned long long*)hb)[i4] = ob.v;
}

// vectorized x4: one block per batch row b (256 thr x 4 c)
__global__ void k_pointwise(const u16* HtCat, const u16* XtCat,
                            const float* delta, const float* dt, const float* ld, const float* lf,
                            const float* dts, const float* sre, const float* sim,
                            const float* lwre, const float* lwim, const float* selb,
                            u16* Hncat, float imSign) {
  const int b = blockIdx.x;
  const int c0 = threadIdx.x * 4;
  const size_t ro = (size_t)b * 2048 + c0;
  const float dtv = dt[b];
  float4v dre4 = *(const float4v*)(delta + ro);
  float4v dim4 = *(const float4v*)(delta + ro + 1024);
  float4v sbR = *(const float4v*)(selb + c0);
  float4v sbI = *(const float4v*)(selb + 1024 + c0);
  float4v ld4 = *(const float4v*)(ld + c0);
  float4v lf4 = *(const float4v*)(lf + c0);
  float4v dts4 = *(const float4v*)(dts + c0);
  float4v sre4 = *(const float4v*)(sre + c0);
  float4v sim4 = *(const float4v*)(sim + c0);
  float4v lwr4 = *(const float4v*)(lwre + c0);
  float4v lwi4 = *(const float4v*)(lwim + c0);
  U64 htR, htI, xtR, xtI;
  htR.v = *(const unsigned long long*)(HtCat + ro);
  htI.v = *(const unsigned long long*)(HtCat + ro + 1024);
  xtR.v = *(const unsigned long long*)(XtCat + ro);
  xtI.v = *(const unsigned long long*)(XtCat + ro + 1024);
  U64 oR, oI;
#pragma unroll
  for (int j = 0; j < 4; ++j) {
    float lamre = -expf(ld4[j]) + lwr4[j] + dre4[j] + sbR[j];
    float lamim = lf4[j] + lwi4[j] + dim4[j] + sbI[j];
    float dtn = dtv / dts4[j];
    float zre = lamre * dtn, zim = lamim * dtn;
    float r2 = zre * zre + zim * zim;
    float er = expf(zre); float sn, cs; __sincosf(zim, &sn, &cs);
    float dcre = er * cs, dcim = er * sn;
    float p1re, p1im;
    if (r2 < 1e-8f) {
      p1re = 1.0f + 0.5f * zre + (zre * zre - zim * zim) * (1.0f / 6.0f);
      p1im = 0.5f * zim + (zre * zim) * (1.0f / 3.0f);
    } else {
      float inv = 1.0f / r2;
      float nre = dcre - 1.0f, nim = dcim;
      p1re = (nre * zre + nim * zim) * inv;
      p1im = (nim * zre - nre * zim) * inv;
    }
    float fre = p1re * dtv, fim = p1im * dtv;
    float hre = bf2f(htR.u[j]), him = bf2f(htI.u[j]);
    float xre = bf2f(xtR.u[j]) + sre4[j], xim = bf2f(xtI.u[j]) + sim4[j];
    float ore = hre * dcre - him * dcim + xre * fre - xim * fim;
    float oim = hre * dcim + him * dcre + xre * fim + xim * fre;
    oR.u[j] = f2bf(ore); oI.u[j] = f2bf(imSign * oim);
  }
  *(unsigned long long*)(Hncat + ro) = oR.v;
  *(unsigned long long*)(Hncat + ro + 1024) = oI.v;
}

__global__ void k_fill(float* p, size_t n, float v) {
  const size_t idx = (size_t)blockIdx.x * 256 + threadIdx.x;
  if (idx < n) p[idx] = v;
}

// ---------------- host ----------------
static void launch_gemm(int mode, int out, int M, int N, int K, int lda, int ldb,
                        long ldc, int cstride, int nz, const ZP* z, hipStream_t s) {
  GArgs a; a.K = K; a.lda = lda; a.ldb = ldb; a.ldc = ldc; a.cstride = cstride;
  for (int i = 0; i < 8; ++i) a.z[i] = z[i < nz ? i : 0];
  dim3 g(N / 128, M / 128, nz), blk(256);
  if (mode == 1 && out == 0)      gemm_nt<1, 0><<<g, blk, 0, s>>>(a);
  else if (mode == 1 && out == 2) gemm_nt<1, 2><<<g, blk, 0, s>>>(a);
  else if (out == 1)              gemm_nt<0, 1><<<g, blk, 0, s>>>(a);
  else                            gemm_nt<0, 0><<<g, blk, 0, s>>>(a);
}

static void launch_gemm256(int out, int M, int N, int K, int lda, int ldb,
                           long ldc, int cstride, int nz, const ZP* z, hipStream_t s) {
  GArgs a; a.K = K; a.lda = lda; a.ldb = ldb; a.ldc = ldc; a.cstride = cstride;
  for (int i = 0; i < 8; ++i) a.z[i] = z[i < nz ? i : 0];
  dim3 g(N / 256, M / 256, nz), blk(512);
  if (out == 1) gemm_nt256<1><<<g, blk, 0, s>>>(a);
  else          gemm_nt256<0><<<g, blk, 0, s>>>(a);
}

extern "C" void kernel_launch(void* const* d_in, const int* in_sizes, int n_in,
                              void* d_out, int out_size, void* d_ws, size_t ws_size,
                              hipStream_t stream) {
  const float* h_prev  = (const float*)d_in[0];
  const float* x_input = (const float*)d_in[1];
  const float* dt      = (const float*)d_in[2];
  const float* ur      = (const float*)d_in[3];
  const float* ui      = (const float*)d_in[4];
  const float* vr      = (const float*)d_in[5];
  const float* vi      = (const float*)d_in[6];
  const float* logsig  = (const float*)d_in[7];
  const float* ld      = (const float*)d_in[8];
  const float* lf      = (const float*)d_in[9];
  const float* dts     = (const float*)d_in[10];
  const float* sre     = (const float*)d_in[11];
  const float* sim     = (const float*)d_in[12];
  const float* lwre    = (const float*)d_in[13];
  const float* lwim    = (const float*)d_in[14];
  const float* sel_w   = (const float*)d_in[15];
  const float* sel_b   = (const float*)d_in[16];
  float* out = (float*)d_out;
  char* ws = (char*)d_ws;

  const bool realOnly = ((size_t)out_size == BD);
  const bool interleaved = ((size_t)out_size == 2 * BD);
  if ((!realOnly && !interleaved) || ws_size < 224 * MBy) {
    k_fill<<<dim3(((size_t)out_size + 255) / 256), dim3(256), 0, stream>>>(out, (size_t)out_size, 1e9f);
    return;
  }

  // persistent region [0,16MB)
  u16* MiRe_b = (u16*)(ws + 0 * MBy);   // MiRe+MiIm adjacent (N-stacked encode Bt)
  u16* MiIm_b = (u16*)(ws + 2 * MBy);
  u16* Mcat   = (u16*)(ws + 4 * MBy);   // [1024][2048] = [MRe | MIm]
  u16* G_hi   = (u16*)(ws + 8 * MBy);
  u16* G_lo   = (u16*)(ws + 12 * MBy);
  char* AR = ws + 16 * MBy;  // arena
  // phase A
  float* Af32   = (float*)(AR + 0);
  u16* Ahi      = (u16*)(AR + 16 * MBy);
  u16* Alo      = (u16*)(AR + 24 * MBy);
  u16* AsumH    = (u16*)(AR + 32 * MBy);
  u16* AsumL    = (u16*)(AR + 36 * MBy);
  float* Xf32   = (float*)(AR + 40 * MBy);
  u16* Xhi      = (u16*)(AR + 56 * MBy);
  u16* Xlo      = (u16*)(AR + 64 * MBy);   // late (k_xn) ; early: A2u f32 [64,72)
  u16* XThi     = (u16*)(AR + 72 * MBy);
  u16* XTlo     = (u16*)(AR + 80 * MBy);   // late (k_xn) ; early: A2v f32 [80,88)
  u16* XsumH    = (u16*)(AR + 88 * MBy);
  u16* XTsumH   = (u16*)(AR + 92 * MBy);
  u16* XTsumL   = (u16*)(AR + 96 * MBy);
  u16* WThi     = (u16*)(AR + 100 * MBy);  // late (k_wt) ; early: A2T bf16 [100,108)
  u16* WTsumH   = (u16*)(AR + 108 * MBy);  // late ; early: A2Tsum [108,112)
  float* T      = (float*)(AR + 112 * MBy);
  u16* VsHi     = (u16*)(AR + 136 * MBy);
  u16* VsLo     = (u16*)(AR + 140 * MBy);
  u16* UHi      = (u16*)(AR + 144 * MBy);
  u16* ULo      = (u16*)(AR + 148 * MBy);
  u16* UsHi     = (u16*)(AR + 152 * MBy);
  u16* VHi      = (u16*)(AR + 156 * MBy);
  u16* UdifH    = (u16*)(AR + 160 * MBy);
  u16* UdifL    = (u16*)(AR + 162 * MBy);
  u16* UssumH   = (u16*)(AR + 164 * MBy);
  u16* VssumH   = (u16*)(AR + 166 * MBy);
  u16* VssumL   = (u16*)(AR + 168 * MBy);
  u16* VdifH    = (u16*)(AR + 170 * MBy);
  u16* MiTcH    = (u16*)(AR + 172 * MBy);
  u16* MiTcL    = (u16*)(AR + 176 * MBy);
  u16* W_hi     = (u16*)(AR + 180 * MBy);
  u16* W_lo     = (u16*)(AR + 188 * MBy);
  float* A2u    = (float*)(AR + 64 * MBy); // aliases Xlo (dead until k_xn)
  float* A2v    = (float*)(AR + 80 * MBy); // aliases XTlo
  u16* A2T      = (u16*)(AR + 100 * MBy);  // aliases WThi (dead until k_wt)
  u16* A2Tsum   = (u16*)(AR + 108 * MBy);  // aliases WTsumH
  // phase B (reuses arena)
  u16* Hb     = (u16*)(AR + 0);
  u16* XbHi   = (u16*)(AR + 16 * MBy);
  u16* XbLo   = (u16*)(AR + 32 * MBy);
  u16* HtCat  = (u16*)(AR + 48 * MBy);
  u16* XtCat  = (u16*)(AR + 80 * MBy);
  float* delta= (float*)(AR + 112 * MBy);
  u16* Hncat  = (u16*)(AR + 176 * MBy);

  dim3 b256(256);
  const dim3 tdd(16, 16, 2);

  // ---- Phase A ----
  k_buildA<<<tdd, b256, 0, stream>>>(ur, ui, vr, vi, Af32, Ahi, Alo, AsumH, AsumL);

  {  // A^2 products: {are@are, aim@aim, are@aim} per y
    ZP z[6];
    for (int y = 0; y < 2; ++y) {
      const u16* are = Ahi + (size_t)y * 2 * DD; const u16* aim = are + DD;
      float* t = T + (size_t)y * 3 * DD;
      z[y*3+0] = {are, nullptr, are, nullptr, t,          nullptr, 1.f, 0.f};
      z[y*3+1] = {aim, nullptr, aim, nullptr, t + DD,     nullptr, 1.f, 0.f};
      z[y*3+2] = {are, nullptr, aim, nullptr, t + 2*DD,   nullptr, 1.f, 0.f};
    }
    launch_gemm(0, 0, 1024, 1024, 1024, 1024, 1024, 1024, 1, 6, z, stream);
  }
  k_sq<<<tdd, b256, 0, stream>>>(T, A2u, A2v, A2T, A2Tsum);
  {  // A^3 = A @ A^2 (Kara, z=6)
    ZP z[6];
    for (int y = 0; y < 2; ++y) {
      const u16* are = Ahi + (size_t)y*2*DD; const u16* aim = are + DD;
      const u16* a2r = A2T + (size_t)y*2*DD; const u16* a2i = a2r + DD;
      float* t = T + (size_t)y*3*DD;
      z[y*3+0] = {are, nullptr, a2r, nullptr, t,        nullptr, 1.f, 0.f};
      z[y*3+1] = {aim, nullptr, a2i, nullptr, t + DD,   nullptr, 1.f, 0.f};
      z[y*3+2] = {AsumH + (size_t)y*DD, nullptr, A2Tsum + (size_t)y*DD, nullptr, t + 2*DD, nullptr, 1.f, 0.f};
    }
    launch_gemm(0, 0, 1024, 1024, 1024, 1024, 1024, 1024, 1, 6, z, stream);
  }
  k_x0n<<<tdd, b256, 0, stream>>>(Af32, A2u, A2v, T, Xf32, Xhi, XThi, XsumH, XTsumH);

  {  // single Newton: Q = A@X0
    ZP z[6];
    for (int y = 0; y < 2; ++y) {
      const u16* are = Ahi + (size_t)y*2*DD; const u16* aim = are + DD;
      const u16* xtr = XThi + (size_t)y*2*DD; const u16* xti = xtr + DD;
      float* t = T + (size_t)y*3*DD;
      z[y*3+0] = {are, nullptr, xtr, nullptr, t,        nullptr, 1.f, 0.f};
      z[y*3+1] = {aim, nullptr, xti, nullptr, t + DD,   nullptr, 1.f, 0.f};
      z[y*3+2] = {AsumH + (size_t)y*DD, nullptr, XTsumH + (size_t)y*DD, nullptr, t + 2*DD, nullptr, 1.f, 0.f};
    }
    launch_gemm(0, 0, 1024, 1024, 1024, 1024, 1024, 1024, 1, 6, z, stream);
  }
  k_wt<<<tdd, b256, 0, stream>>>(Xf32, T, WThi, WTsumH, 2.0f);
  {  // X1 = X0@W
    ZP z[6];
    for (int y = 0; y < 2; ++y) {
      const u16* xre = Xhi + (size_t)y*2*DD; const u16* xim = xre + DD;
      const u16* wtr = WThi + (size_t)y*2*DD; const u16* wti = wtr + DD;
      float* t = T + (size_t)y*3*DD;
      z[y*3+0] = {xre, nullptr, wtr, nullptr, t,        nullptr, 1.f, 0.f};
      z[y*3+1] = {xim, nullptr, wti, nullptr, t + DD,   nullptr, 1.f, 0.f};
      z[y*3+2] = {XsumH + (size_t)y*DD, nullptr, WTsumH + (size_t)y*DD, nullptr, t + 2*DD, nullptr, 1.f, 0.f};
    }
    launch_gemm(0, 0, 1024, 1024, 1024, 1024, 1024, 1024, 1, 6, z, stream);
  }
  k_xn<<<tdd, b256, 0, stream>>>(T, Xf32, Xhi, XThi, XsumH, XTsumH, Xlo, XTlo, XTsumL);

  {  // refine: Q = A@X split precision (Kara)
    ZP z[6];
    for (int y = 0; y < 2; ++y) {
      const u16* areh = Ahi + (size_t)y*2*DD; const u16* aimh = areh + DD;
      const u16* arel = Alo + (size_t)y*2*DD; const u16* aiml = arel + DD;
      const u16* xtrh = XThi + (size_t)y*2*DD; const u16* xtih = xtrh + DD;
      const u16* xtrl = XTlo + (size_t)y*2*DD; const u16* xtil = xtrl + DD;
      float* t = T + (size_t)y*3*DD;
      z[y*3+0] = {areh, arel, xtrh, xtrl, t,        nullptr, 1.f, 0.f};
      z[y*3+1] = {aimh, aiml, xtih, xtil, t + DD,   nullptr, 1.f, 0.f};
      z[y*3+2] = {AsumH + (size_t)y*DD, AsumL + (size_t)y*DD,
                  XTsumH + (size_t)y*DD, XTsumL + (size_t)y*DD, t + 2*DD, nullptr, 1.f, 0.f};
    }
    launch_gemm(1, 0, 1024, 1024, 1024, 1024, 1024, 1024, 1, 6, z, stream);
  }
  k_wt<<<tdd, b256, 0, stream>>>(Xf32, T, WThi, WTsumH, 1.0f);
  {  // XR = X@R (plain, Kara)
    ZP z[6];
    for (int y = 0; y < 2; ++y) {
      const u16* xre = Xhi + (size_t)y*2*DD; const u16* xim = xre + DD;
      const u16* rtr = WThi + (size_t)y*2*DD; const u16* rti = rtr + DD;
      float* t = T + (size_t)y*3*DD;
      z[y*3+0] = {xre, nullptr, rtr, nullptr, t,        nullptr, 1.f, 0.f};
      z[y*3+1] = {xim, nullptr, rti, nullptr, t + DD,   nullptr, 1.f, 0.f};
      z[y*3+2] = {XsumH + (size_t)y*DD, nullptr, WTsumH + (size_t)y*DD, nullptr, t + 2*DD, nullptr, 1.f, 0.f};
    }
    launch_gemm(0, 0, 1024, 1024, 1024, 1024, 1024, 1024, 1, 6, z, stream);
  }
  k_finalUV<<<dim3(4096, 2), b256, 0, stream>>>(Xf32, T, logsig, VsHi, VsLo, UHi, ULo, UsHi, VHi,
                                                UdifH, UdifL, UssumH, VssumH, VssumL, VdifH);

  {  // Minv = (V s_inv) @ U^H : conj-Kara, split
    ZP z[3] = {
      {VsHi,      VsLo,      UHi,      ULo,      T,        nullptr, 1.f, 0.f},
      {VsHi + DD, VsLo + DD, UHi + DD, ULo + DD, T + DD,   nullptr, 1.f, 0.f},
      {VssumH,    VssumL,    UdifH,    UdifL,    T + 2*DD, nullptr, 1.f, 0.f}};
    launch_gemm(1, 0, 1024, 1024, 1024, 1024, 1024, 1024, 1, 3, z, stream);
  }
  {  // M = (U s) @ V^H : conj-Kara, plain
    ZP z[3] = {
      {UsHi,      nullptr, VHi,      nullptr, T + 3*DD, nullptr, 1.f, 0.f},
      {UsHi + DD, nullptr, VHi + DD, nullptr, T + 4*DD, nullptr, 1.f, 0.f},
      {UssumH,    nullptr, VdifH,    nullptr, T + 5*DD, nullptr, 1.f, 0.f}};
    launch_gemm(0, 0, 1024, 1024, 1024, 1024, 1024, 1024, 1, 3, z, stream);
  }
  k_cmb_M<<<dim3(16, 16), b256, 0, stream>>>(T, MiRe_b, MiIm_b, MiTcH, MiTcL, Mcat);

  // G = [W1|W2] @ [MiRe^T | MiIm^T]  (K=2048 split GEMM, split-pair output)
  k_split4<<<dim3(4096), b256, 0, stream>>>(sel_w, W_hi, W_lo);
  {
    ZP z1[1] = {{W_hi, W_lo, MiTcH, MiTcL, G_hi, G_lo, 1.f, 0.f}};
    launch_gemm(1, 2, 2048, 1024, 2048, 2048, 2048, 1024, 1, 1, z1, stream);
  }

  // ---- Phase B ----
  k_splitB<<<dim3(8192), b256, 0, stream>>>(x_input, h_prev, XbHi, XbLo, Hb);
  {  // encode: N-stacked Bt (MiRe|MiIm adjacent) -> HtCat/XtCat, z=2, 256^2 tile
    ZP z[2] = {
      {Hb,   nullptr, MiRe_b, nullptr, HtCat, nullptr, 1.f, 0.f},
      {XbHi, nullptr, MiRe_b, nullptr, XtCat, nullptr, 1.f, 0.f}};
    launch_gemm256(1, 8192, 2048, 1024, 1024, 1024, 2048, 1, 2, z, stream);
  }
  // delta = x @ G^T: split only for dt_n-large cols ([0,512) and [1024,1536))
  {  // split half (MODE1 BK=32)
    ZP z[2] = {
      {XbHi, XbLo, G_hi,                     G_lo,                     delta,        nullptr, 1.f, 0.f},
      {XbHi, XbLo, G_hi + 1024 * (size_t)Dd, G_lo + 1024 * (size_t)Dd, delta + 1024, nullptr, 1.f, 0.f}};
    launch_gemm(1, 0, 8192, 512, 1024, 1024, 1024, 2048, 1, 2, z, stream);
  }
  {  // plain half
    ZP z[2] = {
      {XbHi, nullptr, G_hi + 512 * (size_t)Dd,  nullptr, delta + 512,  nullptr, 1.f, 0.f},
      {XbHi, nullptr, G_hi + 1536 * (size_t)Dd, nullptr, delta + 1536, nullptr, 1.f, 0.f}};
    launch_gemm(0, 0, 8192, 512, 1024, 1024, 1024, 2048, 1, 2, z, stream);
  }

  if (realOnly) {
    k_pointwise<<<dim3(8192), b256, 0, stream>>>(HtCat, XtCat, delta, dt, ld, lf, dts,
                                                 sre, sim, lwre, lwim, sel_b, Hncat, -1.0f);
    ZP z1[1] = {{Hncat, nullptr, Mcat, nullptr, out, nullptr, 1.f, 0.f}};
    launch_gemm(0, 0, 8192, 1024, 2048, 2048, 2048, 1024, 1, 1, z1, stream);
  } else {
    k_pointwise<<<dim3(8192), b256, 0, stream>>>(HtCat, XtCat, delta, dt, ld, lf, dts,
                                                 sre, sim, lwre, lwim, sel_b, Hncat, -1.0f);
    {
      ZP z1[1] = {{Hncat, nullptr, Mcat, nullptr, out, nullptr, 1.f, 0.f}};
      launch_gemm(0, 0, 8192, 1024, 2048, 2048, 2048, 2048, 2, 1, z1, stream);
    }
    {
      ZP z1[1] = {{Hncat, nullptr, Mcat + 1024, nullptr, out + 1, nullptr, 1.f, 0.f}};
      launch_gemm(0, 0, 8192, 1024, 1024, 2048, 2048, 2048, 2, 1, z1, stream);
    }
    {
      ZP z1[1] = {{Hncat + 1024, nullptr, Mcat, nullptr, out + 1, nullptr, -1.f, 1.f}};
      launch_gemm(0, 0, 8192, 1024, 1024, 2048, 2048, 2048, 2, 1, z1, stream);
    }
  }
}